// Round 8
// baseline (20394.110 us; speedup 1.0000x reference)
//
#include <hip/hip_runtime.h>
#include <math.h>

#define BB 128
#define NN 256
#define NP1 257
#define HH 1024

typedef unsigned short u16;
typedef unsigned int u32;
typedef __attribute__((ext_vector_type(8))) short short8v;
typedef __attribute__((ext_vector_type(4))) short short4v;
typedef __attribute__((ext_vector_type(4))) float float4v;

__device__ __forceinline__ u16 f2b(float x) {            // f32 -> bf16 (RNE)
    union { float f; u32 u; } c; c.f = x;
    u32 r = (c.u + 0x7fffu + ((c.u >> 16) & 1u)) >> 16;
    return (u16)r;
}
__device__ __forceinline__ float b2f(u16 s) {            // bf16 -> f32
    union { u32 u; float f; } c; c.u = ((u32)s) << 16;
    return c.f;
}
__device__ __forceinline__ float ftanh(float x) {        // exact at +-inf
    float e = __builtin_amdgcn_exp2f(x * 2.8853900817779268f);   // e^(2x)
    return 1.f - 2.f * __builtin_amdgcn_rcpf(e + 1.f);
}
__device__ __forceinline__ float fsig(float x) {
    return __builtin_amdgcn_rcpf(1.f + __builtin_amdgcn_exp2f(x * -1.4426950408889634f));
}

#define CPHI(m) ((m) + (((m) >> 5) << 2))
#define KS2 72    // u16 LDS row stride for 64-wide bf16 k-chunks

// ---------------------------------------------------------------------------
// Grid barrier, contention-free arrival:
//  - each block release-stores generation to its OWN slot (64B stride)
//  - block 0 threads 1..255 gather slots in parallel, then release-store go
//  - spinners poll go relaxed, one final acquire
// Round-5's failure was 512 serialized RMWs on ONE line (~130us); slots fix it.
__device__ __forceinline__ void pbar(int* slots, int* go, int gen) {
    __syncthreads();
    const int t = threadIdx.x;
    if (blockIdx.x == 0) {
        if (t >= 1 && t < 256) {
            while (__hip_atomic_load(&slots[t << 4], __ATOMIC_RELAXED,
                                     __HIP_MEMORY_SCOPE_AGENT) < gen)
                __builtin_amdgcn_s_sleep(1);
            (void)__hip_atomic_load(&slots[t << 4], __ATOMIC_ACQUIRE,
                                    __HIP_MEMORY_SCOPE_AGENT);
        }
        __syncthreads();
        if (t == 0)
            __hip_atomic_store(go, gen, __ATOMIC_RELEASE, __HIP_MEMORY_SCOPE_AGENT);
    } else {
        if (t == 0) {
            __hip_atomic_store(&slots[blockIdx.x << 4], gen, __ATOMIC_RELEASE,
                               __HIP_MEMORY_SCOPE_AGENT);
            while (__hip_atomic_load(go, __ATOMIC_RELAXED,
                                     __HIP_MEMORY_SCOPE_AGENT) < gen)
                __builtin_amdgcn_s_sleep(1);
            (void)__hip_atomic_load(go, __ATOMIC_ACQUIRE, __HIP_MEMORY_SCOPE_AGENT);
        }
        __syncthreads();
    }
}

// ---------------------------------------------------------------------------
// init per call: cx=0, hxbA=0, mask=0, cur=-1, barrier slots/go=0
__global__ __launch_bounds__(256) void k_binit(float* cx, u16* hxbA, int* mask,
                                               int* cur, int* slots, int* go) {
    int i = blockIdx.x * 256 + threadIdx.x;
    if (i < BB * HH) cx[i] = 0.f;
    if (i < BB * HH / 2) ((u32*)hxbA)[i] = 0u;
    if (i < BB * NP1) mask[i] = 0;
    if (i < BB) cur[i] = -1;
    if (i < 256 * 16) slots[i] = 0;
    if (i == 0) *go = 0;
}

// ---------------------------------------------------------------------------
// Pack W = [Wih | Whh] bf16, row order j' = nt*64 + g*16 + c; bpk = bih+bhh.
__global__ __launch_bounds__(256) void k_pack(const float* __restrict__ Wih,
                                              const float* __restrict__ Whh,
                                              const float* __restrict__ bih,
                                              const float* __restrict__ bhh,
                                              u16* __restrict__ Wpk,
                                              float* __restrict__ bpk) {
    const int jp = blockIdx.x;
    const int nt = jp >> 6, r = jp & 63, g = r >> 4, c = r & 15;
    const int j = g * HH + nt * 16 + c;
    const int t = threadIdx.x;
    const int k = t * 8;
    const float* s = (k < HH) ? (Wih + (size_t)j * HH + k)
                              : (Whh + (size_t)j * HH + (k - HH));
    float4 v0 = *(const float4*)(s);
    float4 v1 = *(const float4*)(s + 4);
    short8v o;
    o[0]=(short)f2b(v0.x); o[1]=(short)f2b(v0.y); o[2]=(short)f2b(v0.z); o[3]=(short)f2b(v0.w);
    o[4]=(short)f2b(v1.x); o[5]=(short)f2b(v1.y); o[6]=(short)f2b(v1.z); o[7]=(short)f2b(v1.w);
    *(short8v*)(Wpk + (size_t)jp * 2048 + k) = o;
    if (t == 0) bpk[jp] = bih[j] + bhh[j];
}

// ---------------------------------------------------------------------------
__global__ __launch_bounds__(256) void k_cvte(const float* __restrict__ enc,
                                              const float* __restrict__ etok,
                                              const float* __restrict__ stok,
                                              u16* __restrict__ encB) {
    const int row = blockIdx.x;
    const float* src = (row < BB * NN) ? enc + (size_t)row * HH
                      : (row == BB * NN ? etok : stok);
    const int t = threadIdx.x;
    float4 v = *(const float4*)(src + t * 4);
    short4v o;
    o[0]=(short)f2b(v.x); o[1]=(short)f2b(v.y); o[2]=(short)f2b(v.z); o[3]=(short)f2b(v.w);
    *(short4v*)(encB + (size_t)row * HH + t * 4) = o;
}

__global__ __launch_bounds__(256) void k_cvtu(const float* __restrict__ Ua,
                                              u16* __restrict__ Uab) {
    const int row = blockIdx.x;
    const int t = threadIdx.x;
    float4 v = *(const float4*)(Ua + (size_t)row * HH + t * 4);
    short4v o;
    o[0]=(short)f2b(v.x); o[1]=(short)f2b(v.y); o[2]=(short)f2b(v.z); o[3]=(short)f2b(v.w);
    *(short4v*)(Uab + (size_t)row * HH + t * 4) = o;
}

// ---------------------------------------------------------------------------
// encWaB[r, n] (bf16) = sum_k ext[r,k] * Wa[n,k];  f32 math, bf16 store.
__global__ __launch_bounds__(256, 2) void k_encWa2b(const float* __restrict__ enc,
                                                    const float* __restrict__ etok,
                                                    const float* __restrict__ Wa,
                                                    u16* __restrict__ out) {
    __shared__ float As[32][140];
    __shared__ float Ws[32][140];
    const int mt = blockIdx.x, ntl = blockIdx.y;
    const int tid = threadIdx.x;
    const int lr = tid >> 2, lc = tid & 3;
    const int tr = tid & 15, tc = tid >> 4;

    const int r0 = mt * 128 + lr, r1 = r0 + 64;
    const int bb0 = r0 / NP1, nn0 = r0 - bb0 * NP1;
    const int bb1 = r1 / NP1, nn1 = r1 - bb1 * NP1;
    const float* a0 = (nn0 == NN) ? etok : enc + ((size_t)(bb0 * NN + nn0)) * HH;
    const float* a1 = (nn1 == NN) ? etok : enc + ((size_t)(bb1 * NN + nn1)) * HH;
    const float* w0 = Wa + (size_t)(ntl * 128 + lr) * HH;
    const float* w1 = w0 + (size_t)64 * HH;
    const int ca = CPHI(lr), cb = CPHI(lr + 64);
    const int colA = tr * 8 + ((tr >> 2) << 2);
    const int colB = tc * 8 + ((tc >> 2) << 2);

    float acc[8][8] = {};
    for (int k0 = 0; k0 < HH; k0 += 32) {
        float4 va0 = *(const float4*)(a0 + k0 + lc * 4);
        float4 va1 = *(const float4*)(a0 + k0 + lc * 4 + 16);
        float4 va2 = *(const float4*)(a1 + k0 + lc * 4);
        float4 va3 = *(const float4*)(a1 + k0 + lc * 4 + 16);
        float4 vb0 = *(const float4*)(w0 + k0 + lc * 4);
        float4 vb1 = *(const float4*)(w0 + k0 + lc * 4 + 16);
        float4 vb2 = *(const float4*)(w1 + k0 + lc * 4);
        float4 vb3 = *(const float4*)(w1 + k0 + lc * 4 + 16);
        __syncthreads();
        #pragma unroll
        for (int e = 0; e < 4; e++) {
            As[lc*4+e][ca]      = ((const float*)&va0)[e];
            As[lc*4+16+e][ca]   = ((const float*)&va1)[e];
            As[lc*4+e][cb]      = ((const float*)&va2)[e];
            As[lc*4+16+e][cb]   = ((const float*)&va3)[e];
            Ws[lc*4+e][ca]      = ((const float*)&vb0)[e];
            Ws[lc*4+16+e][ca]   = ((const float*)&vb1)[e];
            Ws[lc*4+e][cb]      = ((const float*)&vb2)[e];
            Ws[lc*4+16+e][cb]   = ((const float*)&vb3)[e];
        }
        __syncthreads();
        #pragma unroll
        for (int kk = 0; kk < 32; kk++) {
            float4 A0 = *(const float4*)&As[kk][colA];
            float4 A1 = *(const float4*)&As[kk][colA + 4];
            float4 B0 = *(const float4*)&Ws[kk][colB];
            float4 B1 = *(const float4*)&Ws[kk][colB + 4];
            float av[8] = {A0.x,A0.y,A0.z,A0.w,A1.x,A1.y,A1.z,A1.w};
            float bv[8] = {B0.x,B0.y,B0.z,B0.w,B1.x,B1.y,B1.z,B1.w};
            #pragma unroll
            for (int i = 0; i < 8; i++)
                #pragma unroll
                for (int j = 0; j < 8; j++) acc[i][j] += av[i] * bv[j];
        }
        __syncthreads();
    }
    #pragma unroll
    for (int i = 0; i < 8; i++) {
        short8v o;
        #pragma unroll
        for (int j = 0; j < 8; j++) o[j] = (short)f2b(acc[i][j]);
        *(short8v*)(out + (size_t)(mt * 128 + tr * 8 + i) * HH + ntl * 128 + tc * 8) = o;
    }
}

// ---------------------------------------------------------------------------
// Persistent decode kernel: 256 blocks x 512 threads, 3 custom barriers/step.
// Phase bodies are the round-7 kernels verbatim (A/B on waves 0-3; C on all 8
// waves of blocks 0..127).
__global__ __launch_bounds__(512, 1) void k_persist(
    const u16* __restrict__ encB, const u16* __restrict__ Wpk,
    const float* __restrict__ bpk, const u16* __restrict__ Uab,
    const u16* __restrict__ encWaB, const float* __restrict__ vvec,
    int* __restrict__ cur, int* __restrict__ mask,
    u16* __restrict__ hxbA, u16* __restrict__ hxbB,
    float* __restrict__ cx, float* __restrict__ hup,
    float* __restrict__ out_lp, float* __restrict__ out_idx,
    int* __restrict__ slots, int* __restrict__ go)
{
    __shared__ __align__(16) char arena[14336];
    u16* AsU = (u16*)arena;                               // 32*KS2 = 4608B
    u16* BsU = (u16*)(arena + 4608);                      // 64*KS2 = 9216B
    float (*Gs)[32][17] = (float (*)[32][17])arena;       // 4*32*17*4 = 8704B
    float* huS = (float*)arena;                           // 4096B
    float* vvS = (float*)(arena + 4096);                  // 4096B
    float* scS = (float*)(arena + 8192);                  // 1028B
    float* rv  = (float*)(arena + 9248);                  // 2048B
    int*   ri  = (int*)  (arena + 11296);                 // 2048B

    const int bid = blockIdx.x;
    const int t = threadIdx.x;
    const int w = t >> 6, lane = t & 63;
    int gen = 1;

    for (int step = 0; step < NP1; step++) {
        const u16* hin = (step & 1) ? hxbB : hxbA;
        u16* hout = (step & 1) ? hxbA : hxbB;

        // ============ phase A: gates GEMM + LSTM cell (waves 0-3) ==========
        {
            const int nt = bid & 63, mt = bid >> 6;
            short8v a_r, b_r0, b_r1;
            const u16 *xrow = nullptr, *hrow = nullptr, *brow = nullptr;
            int rA = 0, koA = 0, rB = 0, koB = 0;
            if (t < 256) {
                rA = t >> 3; koA = (t & 7) * 8;
                const int mg = mt * 32 + rA;
                const int sel = cur[mg];
                xrow = encB + (size_t)((sel < 0) ? (BB * NN + 1)
                             : (sel == NN ? BB * NN : (mg * NN + sel))) * HH;
                hrow = hin + (size_t)mg * HH;
                rB = t >> 2; koB = (t & 3) * 16;
                brow = Wpk + (size_t)(nt * 64 + rB) * 2048;
                a_r  = *(const short8v*)(xrow + koA);
                b_r0 = *(const short8v*)(brow + koB);
                b_r1 = *(const short8v*)(brow + koB + 8);
            }
            float4v acc0 = {}, acc1 = {};
            for (int it = 0; it < 32; ++it) {
                __syncthreads();
                if (t < 256) {
                    *(short8v*)&AsU[rA * KS2 + koA] = a_r;
                    *(short8v*)&BsU[rB * KS2 + koB] = b_r0;
                    *(short8v*)&BsU[rB * KS2 + koB + 8] = b_r1;
                }
                __syncthreads();
                if (t < 256) {
                    if (it < 31) {
                        const int k0 = (it + 1) * 64;
                        const u16* asrc = (k0 < HH) ? (xrow + k0) : (hrow + (k0 - HH));
                        a_r  = *(const short8v*)(asrc + koA);
                        b_r0 = *(const short8v*)(brow + k0 + koB);
                        b_r1 = *(const short8v*)(brow + k0 + koB + 8);
                    }
                    #pragma unroll
                    for (int kf = 0; kf < 2; ++kf) {
                        short8v bf = *(const short8v*)&BsU[(w * 16 + (lane & 15)) * KS2 + kf * 32 + (lane >> 4) * 8];
                        short8v a0 = *(const short8v*)&AsU[(lane & 15) * KS2 + kf * 32 + (lane >> 4) * 8];
                        short8v a1 = *(const short8v*)&AsU[(16 + (lane & 15)) * KS2 + kf * 32 + (lane >> 4) * 8];
                        acc0 = __builtin_amdgcn_mfma_f32_16x16x32_bf16(a0, bf, acc0, 0, 0, 0);
                        acc1 = __builtin_amdgcn_mfma_f32_16x16x32_bf16(a1, bf, acc1, 0, 0, 0);
                    }
                }
            }
            __syncthreads();
            if (t < 256) {
                #pragma unroll
                for (int r = 0; r < 4; r++) {
                    Gs[w][(lane >> 4) * 4 + r][lane & 15]      = acc0[r];
                    Gs[w][16 + (lane >> 4) * 4 + r][lane & 15] = acc1[r];
                }
            }
            __syncthreads();
            if (t < 256) {
                #pragma unroll
                for (int p = t; p < 512; p += 256) {
                    const int c = p & 15, m = p >> 4;
                    const int mg2 = mt * 32 + m, cg = nt * 16 + c;
                    float gi = Gs[0][m][c] + bpk[nt * 64 + c];
                    float gf = Gs[1][m][c] + bpk[nt * 64 + 16 + c];
                    float gg = Gs[2][m][c] + bpk[nt * 64 + 32 + c];
                    float go2 = Gs[3][m][c] + bpk[nt * 64 + 48 + c];
                    float cold = cx[(size_t)mg2 * HH + cg];
                    float cn = fsig(gf) * cold + fsig(gi) * ftanh(gg);
                    float hn = fsig(go2) * ftanh(cn);
                    cx[(size_t)mg2 * HH + cg] = cn;
                    hout[(size_t)mg2 * HH + cg] = f2b(hn);
                }
            }
        }
        pbar(slots, go, gen++);

        // ============ phase B: hUa partials (waves 0-3) ====================
        {
            const int nt = bid & 15, mt = (bid >> 4) & 3, ks = bid >> 6;
            short8v a_r, b_r0, b_r1;
            const u16 *arow = nullptr, *brow = nullptr;
            int rA = 0, koA = 0, rB = 0, koB = 0;
            if (t < 256) {
                rA = t >> 3; koA = (t & 7) * 8;
                arow = hout + (size_t)(mt * 32 + rA) * HH + ks * 256;
                rB = t >> 2; koB = (t & 3) * 16;
                brow = Uab + (size_t)(nt * 64 + rB) * HH + ks * 256;
                a_r  = *(const short8v*)(arow + koA);
                b_r0 = *(const short8v*)(brow + koB);
                b_r1 = *(const short8v*)(brow + koB + 8);
            }
            float4v acc0 = {}, acc1 = {};
            for (int it = 0; it < 4; ++it) {
                __syncthreads();
                if (t < 256) {
                    *(short8v*)&AsU[rA * KS2 + koA] = a_r;
                    *(short8v*)&BsU[rB * KS2 + koB] = b_r0;
                    *(short8v*)&BsU[rB * KS2 + koB + 8] = b_r1;
                }
                __syncthreads();
                if (t < 256) {
                    if (it < 3) {
                        const int k0 = (it + 1) * 64;
                        a_r  = *(const short8v*)(arow + k0 + koA);
                        b_r0 = *(const short8v*)(brow + k0 + koB);
                        b_r1 = *(const short8v*)(brow + k0 + koB + 8);
                    }
                    #pragma unroll
                    for (int kf = 0; kf < 2; ++kf) {
                        short8v bf = *(const short8v*)&BsU[(w * 16 + (lane & 15)) * KS2 + kf * 32 + (lane >> 4) * 8];
                        short8v a0 = *(const short8v*)&AsU[(lane & 15) * KS2 + kf * 32 + (lane >> 4) * 8];
                        short8v a1 = *(const short8v*)&AsU[(16 + (lane & 15)) * KS2 + kf * 32 + (lane >> 4) * 8];
                        acc0 = __builtin_amdgcn_mfma_f32_16x16x32_bf16(a0, bf, acc0, 0, 0, 0);
                        acc1 = __builtin_amdgcn_mfma_f32_16x16x32_bf16(a1, bf, acc1, 0, 0, 0);
                    }
                }
            }
            if (t < 256) {
                const int n = nt * 64 + w * 16 + (lane & 15);
                #pragma unroll
                for (int r = 0; r < 4; r++) {
                    const int m0 = mt * 32 + (lane >> 4) * 4 + r;
                    hup[((size_t)ks * BB + m0) * HH + n]      = acc0[r];
                    hup[((size_t)ks * BB + m0 + 16) * HH + n] = acc1[r];
                }
            }
        }
        pbar(slots, go, gen++);

        // ============ phase C: scores + finalize (blocks 0..127) ===========
        if (bid < 128) {
            const int b = bid;
            for (int c = t; c < HH; c += 512) {
                float s = 0.f;
                #pragma unroll
                for (int ks = 0; ks < 4; ks++) s += hup[((size_t)ks * BB + b) * HH + c];
                huS[c] = s;
                vvS[c] = vvec[c];
            }
            __syncthreads();

            const int c0 = lane * 16;
            {
                int n = w;
                const u16* rp = encWaB + ((size_t)b * NP1 + n) * HH + c0;
                short8v e0 = *(const short8v*)(rp);
                short8v e1 = *(const short8v*)(rp + 8);
                while (n < NP1) {
                    const int n2 = n + 8;
                    short8v f0 = e0, f1 = e1;
                    if (n2 < NP1) {
                        const u16* rp2 = encWaB + ((size_t)b * NP1 + n2) * HH + c0;
                        f0 = *(const short8v*)(rp2);
                        f1 = *(const short8v*)(rp2 + 8);
                    }
                    float s = 0.f;
                    #pragma unroll
                    for (int j = 0; j < 8; j++)
                        s += vvS[c0 + j] * ftanh(b2f((u16)e0[j]) + huS[c0 + j]);
                    #pragma unroll
                    for (int j = 0; j < 8; j++)
                        s += vvS[c0 + 8 + j] * ftanh(b2f((u16)e1[j]) + huS[c0 + 8 + j]);
                    #pragma unroll
                    for (int off = 32; off; off >>= 1) s += __shfl_down(s, off);
                    if (lane == 0) scS[n] = s;
                    e0 = f0; e1 = f1; n = n2;
                }
            }
            __syncthreads();

            float va = -INFINITY;
            if (t < NP1) va = (mask[b * NP1 + t] != 0) ? -INFINITY : scS[t];
            rv[t] = va; ri[t] = t;
            __syncthreads();
            for (int s = 256; s; s >>= 1) {
                if (t < s) {
                    float ov = rv[t + s]; int oi = ri[t + s];
                    if (ov > rv[t] || (ov == rv[t] && oi < ri[t])) { rv[t] = ov; ri[t] = oi; }
                }
                __syncthreads();
            }
            const float vmax = rv[0]; const int amax = ri[0];
            __syncthreads();

            float es = (t < NP1) ? expf(va - vmax) : 0.f;
            rv[t] = es;
            __syncthreads();
            for (int s = 256; s; s >>= 1) {
                if (t < s) rv[t] += rv[t + s];
                __syncthreads();
            }
            const float lse = vmax + logf(rv[0]);

            if (t < NP1)
                out_lp[((size_t)b * NP1 + step) * NP1 + t] = fmaxf(va - lse, -1e30f);
            if (t == 0) {
                out_idx[(size_t)b * NP1 + step] = (float)amax;
                cur[b] = amax;
                if (amax < NN) mask[b * NP1 + amax] = 1;
            }
        }
        pbar(slots, go, gen++);
    }
}

// ---------------------------------------------------------------------------
extern "C" void kernel_launch(void* const* d_in, const int* in_sizes, int n_in,
                              void* d_out, int out_size, void* d_ws, size_t ws_size,
                              hipStream_t stream) {
    const float* enc  = (const float*)d_in[0];
    const float* Wih  = (const float*)d_in[1];
    const float* Whh  = (const float*)d_in[2];
    const float* bih  = (const float*)d_in[3];
    const float* bhh  = (const float*)d_in[4];
    const float* Wa   = (const float*)d_in[5];
    const float* Ua   = (const float*)d_in[6];
    const float* v    = (const float*)d_in[7];
    const float* stok = (const float*)d_in[8];
    const float* etok = (const float*)d_in[9];
    float* out = (float*)d_out;
    float* out_idx = out + (size_t)BB * NP1 * NP1;

    size_t off = 0;
    char* base = (char*)d_ws;
    auto alloc = [&](size_t bytes) -> char* {
        char* p = base + off;
        off += (bytes + 255) & ~(size_t)255;
        return p;
    };
    u16*   encWaB = (u16*)  alloc((size_t)BB * NP1 * HH * 2);      // 67.4 MB
    u16*   encB   = (u16*)  alloc((size_t)(BB * NN + 2) * HH * 2); // 67.1 MB
    u16*   Wpk    = (u16*)  alloc((size_t)4096 * 2048 * 2);        // 16.8 MB
    u16*   Uab    = (u16*)  alloc((size_t)HH * HH * 2);            //  2.1 MB
    float* bpk    = (float*)alloc((size_t)4096 * 4);
    float* hup    = (float*)alloc((size_t)4 * BB * HH * 4);        //  2.1 MB
    float* cx     = (float*)alloc((size_t)BB * HH * 4);
    u16*   hxbA   = (u16*)  alloc((size_t)BB * HH * 2);
    u16*   hxbB   = (u16*)  alloc((size_t)BB * HH * 2);
    int*   mask   = (int*)  alloc((size_t)BB * NP1 * 4);
    int*   cur    = (int*)  alloc((size_t)BB * 4);
    int*   slots  = (int*)  alloc((size_t)256 * 16 * 4);
    int*   go     = (int*)  alloc((size_t)64);
    if (off > ws_size) return;   // distinctive failure: 0-node graph

    k_binit<<<512, 256, 0, stream>>>(cx, hxbA, mask, cur, slots, go);
    k_pack<<<4096, 256, 0, stream>>>(Wih, Whh, bih, bhh, Wpk, bpk);
    k_cvte<<<BB * NN + 2, 256, 0, stream>>>(enc, etok, stok, encB);
    k_cvtu<<<HH, 256, 0, stream>>>(Ua, Uab);
    k_encWa2b<<<dim3(257, 8), 256, 0, stream>>>(enc, etok, Wa, encWaB);

    void* args[] = { (void*)&encB, (void*)&Wpk, (void*)&bpk, (void*)&Uab,
                     (void*)&encWaB, (void*)&v, (void*)&cur, (void*)&mask,
                     (void*)&hxbA, (void*)&hxbB, (void*)&cx, (void*)&hup,
                     (void*)&out, (void*)&out_idx, (void*)&slots, (void*)&go };
    hipLaunchCooperativeKernel((const void*)k_persist, dim3(256), dim3(512),
                               args, 0, stream);
}

// Round 9
// 14089.784 us; speedup vs baseline: 1.4474x; 1.4474x over previous
//
#include <hip/hip_runtime.h>
#include <math.h>

#define BB 128
#define NN 256
#define NP1 257
#define HH 1024

typedef unsigned short u16;
typedef unsigned int u32;
typedef unsigned long long u64;
typedef __attribute__((ext_vector_type(8))) short short8v;
typedef __attribute__((ext_vector_type(4))) short short4v;
typedef __attribute__((ext_vector_type(4))) float float4v;

__device__ __forceinline__ u16 f2b(float x) {            // f32 -> bf16 (RNE)
    union { float f; u32 u; } c; c.f = x;
    u32 r = (c.u + 0x7fffu + ((c.u >> 16) & 1u)) >> 16;
    return (u16)r;
}
__device__ __forceinline__ float b2f(u16 s) {            // bf16 -> f32
    union { u32 u; float f; } c; c.u = ((u32)s) << 16;
    return c.f;
}
__device__ __forceinline__ float ftanh(float x) {        // exact at +-inf
    float e = __builtin_amdgcn_exp2f(x * 2.8853900817779268f);   // e^(2x)
    return 1.f - 2.f * __builtin_amdgcn_rcpf(e + 1.f);
}
__device__ __forceinline__ float fsig(float x) {
    return __builtin_amdgcn_rcpf(1.f + __builtin_amdgcn_exp2f(x * -1.4426950408889634f));
}

// LLC-coherent (sc1) access helpers: relaxed agent atomics -> no cache fences
__device__ __forceinline__ u64 gload64(const u16* p) {
    return __hip_atomic_load((u64*)p, __ATOMIC_RELAXED, __HIP_MEMORY_SCOPE_AGENT);
}
__device__ __forceinline__ short8v gload8h(const u16* p) {
    union { u64 q[2]; short8v v; } uq;
    uq.q[0] = gload64(p);
    uq.q[1] = gload64(p + 4);
    return uq.v;
}
__device__ __forceinline__ void gstore32(u32* p, u32 v) {
    __hip_atomic_store(p, v, __ATOMIC_RELAXED, __HIP_MEMORY_SCOPE_AGENT);
}
__device__ __forceinline__ u32 gload32(const u32* p) {
    return __hip_atomic_load((u32*)p, __ATOMIC_RELAXED, __HIP_MEMORY_SCOPE_AGENT);
}

#define CPHI(m) ((m) + (((m) >> 5) << 2))
#define KS2 72    // u16 LDS row stride for 64-wide bf16 k-chunks

// ---------------------------------------------------------------------------
// Fence-free grid barrier. Data visibility is carried by sc1 accesses to the
// mutable buffers themselves; __syncthreads() drains vmcnt(0) per wave before
// s_barrier [HIP-compiler], so arrival implies this block's stores hit LLC.
__device__ __forceinline__ void pbar(int* slots, int* go, int gen) {
    asm volatile("" ::: "memory");
    __syncthreads();                       // drains vmcnt for every wave
    const int t = threadIdx.x;
    if (blockIdx.x == 0) {
        if (t >= 1 && t < 256) {
            while ((int)gload32((u32*)&slots[t << 4]) < gen)
                __builtin_amdgcn_s_sleep(1);
        }
        __syncthreads();
        if (t == 0) gstore32((u32*)go, (u32)gen);
    } else {
        if (t == 0) {
            gstore32((u32*)&slots[blockIdx.x << 4], (u32)gen);
            while ((int)gload32((u32*)go) < gen)
                __builtin_amdgcn_s_sleep(1);
        }
        __syncthreads();
    }
    asm volatile("" ::: "memory");
}

// ---------------------------------------------------------------------------
// init per call: cx=0, hxbA=0, mask=0, cur=-1, slots/go=0
__global__ __launch_bounds__(256) void k_binit(float* cx, u16* hxbA, int* mask,
                                               int* cur, int* slots, int* go) {
    int i = blockIdx.x * 256 + threadIdx.x;
    if (i < BB * HH) cx[i] = 0.f;
    if (i < BB * HH / 2) ((u32*)hxbA)[i] = 0u;
    if (i < BB * NP1) mask[i] = 0;
    if (i < BB) cur[i] = -1;
    if (i < 256 * 16) slots[i] = 0;
    if (i == 0) *go = 0;
}

// ---------------------------------------------------------------------------
// Pack W = [Wih | Whh] bf16, row order j' = nt*64 + g*16 + c; bpk = bih+bhh.
__global__ __launch_bounds__(256) void k_pack(const float* __restrict__ Wih,
                                              const float* __restrict__ Whh,
                                              const float* __restrict__ bih,
                                              const float* __restrict__ bhh,
                                              u16* __restrict__ Wpk,
                                              float* __restrict__ bpk) {
    const int jp = blockIdx.x;
    const int nt = jp >> 6, r = jp & 63, g = r >> 4, c = r & 15;
    const int j = g * HH + nt * 16 + c;
    const int t = threadIdx.x;
    const int k = t * 8;
    const float* s = (k < HH) ? (Wih + (size_t)j * HH + k)
                              : (Whh + (size_t)j * HH + (k - HH));
    float4 v0 = *(const float4*)(s);
    float4 v1 = *(const float4*)(s + 4);
    short8v o;
    o[0]=(short)f2b(v0.x); o[1]=(short)f2b(v0.y); o[2]=(short)f2b(v0.z); o[3]=(short)f2b(v0.w);
    o[4]=(short)f2b(v1.x); o[5]=(short)f2b(v1.y); o[6]=(short)f2b(v1.z); o[7]=(short)f2b(v1.w);
    *(short8v*)(Wpk + (size_t)jp * 2048 + k) = o;
    if (t == 0) bpk[jp] = bih[j] + bhh[j];
}

// ---------------------------------------------------------------------------
__global__ __launch_bounds__(256) void k_cvte(const float* __restrict__ enc,
                                              const float* __restrict__ etok,
                                              const float* __restrict__ stok,
                                              u16* __restrict__ encB) {
    const int row = blockIdx.x;
    const float* src = (row < BB * NN) ? enc + (size_t)row * HH
                      : (row == BB * NN ? etok : stok);
    const int t = threadIdx.x;
    float4 v = *(const float4*)(src + t * 4);
    short4v o;
    o[0]=(short)f2b(v.x); o[1]=(short)f2b(v.y); o[2]=(short)f2b(v.z); o[3]=(short)f2b(v.w);
    *(short4v*)(encB + (size_t)row * HH + t * 4) = o;
}

__global__ __launch_bounds__(256) void k_cvtu(const float* __restrict__ Ua,
                                              u16* __restrict__ Uab) {
    const int row = blockIdx.x;
    const int t = threadIdx.x;
    float4 v = *(const float4*)(Ua + (size_t)row * HH + t * 4);
    short4v o;
    o[0]=(short)f2b(v.x); o[1]=(short)f2b(v.y); o[2]=(short)f2b(v.z); o[3]=(short)f2b(v.w);
    *(short4v*)(Uab + (size_t)row * HH + t * 4) = o;
}

// ---------------------------------------------------------------------------
// encWaB[r, n] (bf16) = sum_k ext[r,k] * Wa[n,k];  f32 math, bf16 store.
__global__ __launch_bounds__(256, 2) void k_encWa2b(const float* __restrict__ enc,
                                                    const float* __restrict__ etok,
                                                    const float* __restrict__ Wa,
                                                    u16* __restrict__ out) {
    __shared__ float As[32][140];
    __shared__ float Ws[32][140];
    const int mt = blockIdx.x, ntl = blockIdx.y;
    const int tid = threadIdx.x;
    const int lr = tid >> 2, lc = tid & 3;
    const int tr = tid & 15, tc = tid >> 4;

    const int r0 = mt * 128 + lr, r1 = r0 + 64;
    const int bb0 = r0 / NP1, nn0 = r0 - bb0 * NP1;
    const int bb1 = r1 / NP1, nn1 = r1 - bb1 * NP1;
    const float* a0 = (nn0 == NN) ? etok : enc + ((size_t)(bb0 * NN + nn0)) * HH;
    const float* a1 = (nn1 == NN) ? etok : enc + ((size_t)(bb1 * NN + nn1)) * HH;
    const float* w0 = Wa + (size_t)(ntl * 128 + lr) * HH;
    const float* w1 = w0 + (size_t)64 * HH;
    const int ca = CPHI(lr), cb = CPHI(lr + 64);
    const int colA = tr * 8 + ((tr >> 2) << 2);
    const int colB = tc * 8 + ((tc >> 2) << 2);

    float acc[8][8] = {};
    for (int k0 = 0; k0 < HH; k0 += 32) {
        float4 va0 = *(const float4*)(a0 + k0 + lc * 4);
        float4 va1 = *(const float4*)(a0 + k0 + lc * 4 + 16);
        float4 va2 = *(const float4*)(a1 + k0 + lc * 4);
        float4 va3 = *(const float4*)(a1 + k0 + lc * 4 + 16);
        float4 vb0 = *(const float4*)(w0 + k0 + lc * 4);
        float4 vb1 = *(const float4*)(w0 + k0 + lc * 4 + 16);
        float4 vb2 = *(const float4*)(w1 + k0 + lc * 4);
        float4 vb3 = *(const float4*)(w1 + k0 + lc * 4 + 16);
        __syncthreads();
        #pragma unroll
        for (int e = 0; e < 4; e++) {
            As[lc*4+e][ca]      = ((const float*)&va0)[e];
            As[lc*4+16+e][ca]   = ((const float*)&va1)[e];
            As[lc*4+e][cb]      = ((const float*)&va2)[e];
            As[lc*4+16+e][cb]   = ((const float*)&va3)[e];
            Ws[lc*4+e][ca]      = ((const float*)&vb0)[e];
            Ws[lc*4+16+e][ca]   = ((const float*)&vb1)[e];
            Ws[lc*4+e][cb]      = ((const float*)&vb2)[e];
            Ws[lc*4+16+e][cb]   = ((const float*)&vb3)[e];
        }
        __syncthreads();
        #pragma unroll
        for (int kk = 0; kk < 32; kk++) {
            float4 A0 = *(const float4*)&As[kk][colA];
            float4 A1 = *(const float4*)&As[kk][colA + 4];
            float4 B0 = *(const float4*)&Ws[kk][colB];
            float4 B1 = *(const float4*)&Ws[kk][colB + 4];
            float av[8] = {A0.x,A0.y,A0.z,A0.w,A1.x,A1.y,A1.z,A1.w};
            float bv[8] = {B0.x,B0.y,B0.z,B0.w,B1.x,B1.y,B1.z,B1.w};
            #pragma unroll
            for (int i = 0; i < 8; i++)
                #pragma unroll
                for (int j = 0; j < 8; j++) acc[i][j] += av[i] * bv[j];
        }
        __syncthreads();
    }
    #pragma unroll
    for (int i = 0; i < 8; i++) {
        short8v o;
        #pragma unroll
        for (int j = 0; j < 8; j++) o[j] = (short)f2b(acc[i][j]);
        *(short8v*)(out + (size_t)(mt * 128 + tr * 8 + i) * HH + ntl * 128 + tc * 8) = o;
    }
}

// ---------------------------------------------------------------------------
// Persistent decode: 256 blocks x 512 threads, 3 fence-free barriers/step.
// Cross-block mutable data (h, hup, cur) via sc1 atomics; constants stay in
// warm L2; cx/mask/out block-private normal.
__global__ __launch_bounds__(512, 1) void k_persist(
    const u16* __restrict__ encB, const u16* __restrict__ Wpk,
    const float* __restrict__ bpk, const u16* __restrict__ Uab,
    const u16* __restrict__ encWaB, const float* __restrict__ vvec,
    int* __restrict__ cur, int* __restrict__ mask,
    u16* __restrict__ hxbA, u16* __restrict__ hxbB,
    float* __restrict__ cx, float* __restrict__ hup,
    float* __restrict__ out_lp, float* __restrict__ out_idx,
    int* __restrict__ slots, int* __restrict__ go)
{
    __shared__ __align__(16) char arena[14336];
    u16* AsU = (u16*)arena;                               // 4608B
    u16* BsU = (u16*)(arena + 4608);                      // 9216B
    float (*Gs)[32][17] = (float (*)[32][17])arena;       // 8704B
    float* huS = (float*)arena;                           // 4096B
    float* vvS = (float*)(arena + 4096);                  // 4096B
    float* scS = (float*)(arena + 8192);                  // 1028B
    float* rv  = (float*)(arena + 9248);                  // 2048B
    int*   ri  = (int*)  (arena + 11296);                 // 2048B

    const int bid = blockIdx.x;
    const int t = threadIdx.x;
    const int w = t >> 6, lane = t & 63;
    int gen = 1;

    for (int step = 0; step < NP1; step++) {
        const u16* hin = (step & 1) ? hxbB : hxbA;
        u16* hout = (step & 1) ? hxbA : hxbB;

        // ============ phase A: gates GEMM + LSTM cell ======================
        {
            const int nt = bid & 63, mt = bid >> 6;
            short8v hpre[16];
            short8v a_pf[2], b0_pf[2], b1_pf[2];
            const u16 *xrow = nullptr, *brow = nullptr;
            int rA = 0, koA = 0, rB = 0, koB = 0;
            if (t < 256) {
                rA = t >> 3; koA = (t & 7) * 8;
                const int mg = mt * 32 + rA;
                const u16* hrow = hin + (size_t)mg * HH;
                #pragma unroll
                for (int i = 0; i < 16; i++)
                    hpre[i] = gload8h(hrow + i * 64 + koA);     // sc1 preload
                const int sel = (int)gload32((const u32*)&cur[mg]);
                xrow = encB + (size_t)((sel < 0) ? (BB * NN + 1)
                             : (sel == NN ? BB * NN : (mg * NN + sel))) * HH;
                rB = t >> 2; koB = (t & 3) * 16;
                brow = Wpk + (size_t)(nt * 64 + rB) * 2048;
                a_pf[0]  = *(const short8v*)(xrow + koA);
                a_pf[1]  = *(const short8v*)(xrow + 64 + koA);
                b0_pf[0] = *(const short8v*)(brow + koB);
                b1_pf[0] = *(const short8v*)(brow + koB + 8);
                b0_pf[1] = *(const short8v*)(brow + 64 + koB);
                b1_pf[1] = *(const short8v*)(brow + 64 + koB + 8);
            }
            float4v acc0 = {}, acc1 = {};
            // half 1: x-part, chunks 0..15, depth-2 prefetch
            #pragma unroll
            for (int it = 0; it < 16; ++it) {
                __syncthreads();
                if (t < 256) {
                    *(short8v*)&AsU[rA * KS2 + koA] = a_pf[it & 1];
                    *(short8v*)&BsU[rB * KS2 + koB] = b0_pf[it & 1];
                    *(short8v*)&BsU[rB * KS2 + koB + 8] = b1_pf[it & 1];
                }
                __syncthreads();
                if (t < 256) {
                    const int k2 = (it + 2) * 64;
                    if (it < 14) a_pf[it & 1] = *(const short8v*)(xrow + k2 + koA);
                    b0_pf[it & 1] = *(const short8v*)(brow + k2 + koB);
                    b1_pf[it & 1] = *(const short8v*)(brow + k2 + koB + 8);
                    #pragma unroll
                    for (int kf = 0; kf < 2; ++kf) {
                        short8v bf = *(const short8v*)&BsU[(w * 16 + (lane & 15)) * KS2 + kf * 32 + (lane >> 4) * 8];
                        short8v a0 = *(const short8v*)&AsU[(lane & 15) * KS2 + kf * 32 + (lane >> 4) * 8];
                        short8v a1 = *(const short8v*)&AsU[(16 + (lane & 15)) * KS2 + kf * 32 + (lane >> 4) * 8];
                        acc0 = __builtin_amdgcn_mfma_f32_16x16x32_bf16(a0, bf, acc0, 0, 0, 0);
                        acc1 = __builtin_amdgcn_mfma_f32_16x16x32_bf16(a1, bf, acc1, 0, 0, 0);
                    }
                }
            }
            // half 2: h-part from hpre regs, chunks 16..31
            #pragma unroll
            for (int j = 0; j < 16; ++j) {
                __syncthreads();
                if (t < 256) {
                    *(short8v*)&AsU[rA * KS2 + koA] = hpre[j];
                    *(short8v*)&BsU[rB * KS2 + koB] = b0_pf[j & 1];
                    *(short8v*)&BsU[rB * KS2 + koB + 8] = b1_pf[j & 1];
                }
                __syncthreads();
                if (t < 256) {
                    if (j < 14) {
                        const int k2 = (18 + j) * 64;
                        b0_pf[j & 1] = *(const short8v*)(brow + k2 + koB);
                        b1_pf[j & 1] = *(const short8v*)(brow + k2 + koB + 8);
                    }
                    #pragma unroll
                    for (int kf = 0; kf < 2; ++kf) {
                        short8v bf = *(const short8v*)&BsU[(w * 16 + (lane & 15)) * KS2 + kf * 32 + (lane >> 4) * 8];
                        short8v a0 = *(const short8v*)&AsU[(lane & 15) * KS2 + kf * 32 + (lane >> 4) * 8];
                        short8v a1 = *(const short8v*)&AsU[(16 + (lane & 15)) * KS2 + kf * 32 + (lane >> 4) * 8];
                        acc0 = __builtin_amdgcn_mfma_f32_16x16x32_bf16(a0, bf, acc0, 0, 0, 0);
                        acc1 = __builtin_amdgcn_mfma_f32_16x16x32_bf16(a1, bf, acc1, 0, 0, 0);
                    }
                }
            }
            __syncthreads();
            if (t < 256) {
                #pragma unroll
                for (int r = 0; r < 4; r++) {
                    Gs[w][(lane >> 4) * 4 + r][lane & 15]      = acc0[r];
                    Gs[w][16 + (lane >> 4) * 4 + r][lane & 15] = acc1[r];
                }
            }
            __syncthreads();
            if (t < 256) {
                const int m = t >> 3, cpr = (t & 7) * 2;
                const int mg2 = mt * 32 + m;
                float hn2[2];
                #pragma unroll
                for (int e = 0; e < 2; e++) {
                    const int c = cpr + e;
                    float gi  = Gs[0][m][c] + bpk[nt * 64 + c];
                    float gf  = Gs[1][m][c] + bpk[nt * 64 + 16 + c];
                    float gg  = Gs[2][m][c] + bpk[nt * 64 + 32 + c];
                    float go2 = Gs[3][m][c] + bpk[nt * 64 + 48 + c];
                    const int cg = nt * 16 + c;
                    float cold = cx[(size_t)mg2 * HH + cg];
                    float cn = fsig(gf) * cold + fsig(gi) * ftanh(gg);
                    hn2[e] = fsig(go2) * ftanh(cn);
                    cx[(size_t)mg2 * HH + cg] = cn;
                }
                u32 pk = (u32)f2b(hn2[0]) | ((u32)f2b(hn2[1]) << 16);
                gstore32((u32*)(hout + (size_t)mg2 * HH + nt * 16 + cpr), pk);
            }
        }
        pbar(slots, go, gen++);

        // ============ phase B: hUa partials ================================
        {
            const int nt2 = bid & 15, mt2 = (bid >> 4) & 3, ks = bid >> 6;
            short8v hb[4];
            short8v b0_pf, b1_pf;
            const u16* brow = nullptr;
            int rA = 0, koA = 0, rB = 0, koB = 0;
            if (t < 256) {
                rA = t >> 3; koA = (t & 7) * 8;
                const u16* arow = hout + (size_t)(mt2 * 32 + rA) * HH + ks * 256;
                #pragma unroll
                for (int i = 0; i < 4; i++)
                    hb[i] = gload8h(arow + i * 64 + koA);       // sc1 preload
                rB = t >> 2; koB = (t & 3) * 16;
                brow = Uab + (size_t)(nt2 * 64 + rB) * HH + ks * 256;
                b0_pf = *(const short8v*)(brow + koB);
                b1_pf = *(const short8v*)(brow + koB + 8);
            }
            float4v acc0 = {}, acc1 = {};
            #pragma unroll
            for (int it = 0; it < 4; ++it) {
                __syncthreads();
                if (t < 256) {
                    *(short8v*)&AsU[rA * KS2 + koA] = hb[it];
                    *(short8v*)&BsU[rB * KS2 + koB] = b0_pf;
                    *(short8v*)&BsU[rB * KS2 + koB + 8] = b1_pf;
                }
                __syncthreads();
                if (t < 256) {
                    if (it < 3) {
                        const int k0 = (it + 1) * 64;
                        b0_pf = *(const short8v*)(brow + k0 + koB);
                        b1_pf = *(const short8v*)(brow + k0 + koB + 8);
                    }
                    #pragma unroll
                    for (int kf = 0; kf < 2; ++kf) {
                        short8v bf = *(const short8v*)&BsU[(w * 16 + (lane & 15)) * KS2 + kf * 32 + (lane >> 4) * 8];
                        short8v a0 = *(const short8v*)&AsU[(lane & 15) * KS2 + kf * 32 + (lane >> 4) * 8];
                        short8v a1 = *(const short8v*)&AsU[(16 + (lane & 15)) * KS2 + kf * 32 + (lane >> 4) * 8];
                        acc0 = __builtin_amdgcn_mfma_f32_16x16x32_bf16(a0, bf, acc0, 0, 0, 0);
                        acc1 = __builtin_amdgcn_mfma_f32_16x16x32_bf16(a1, bf, acc1, 0, 0, 0);
                    }
                }
            }
            if (t < 256) {
                const int n = nt2 * 64 + w * 16 + (lane & 15);
                #pragma unroll
                for (int r = 0; r < 4; r++) {
                    const int m0 = mt2 * 32 + (lane >> 4) * 4 + r;
                    gstore32((u32*)&hup[((size_t)ks * BB + m0) * HH + n],
                             __float_as_uint(acc0[r]));
                    gstore32((u32*)&hup[((size_t)ks * BB + m0 + 16) * HH + n],
                             __float_as_uint(acc1[r]));
                }
            }
        }
        pbar(slots, go, gen++);

        // ============ phase C: scores + finalize (blocks 0..127) ===========
        if (bid < 128) {
            const int b = bid;
            #pragma unroll
            for (int cc = 0; cc < 2; cc++) {
                const int c = t + cc * 512;
                float s = 0.f;
                #pragma unroll
                for (int ks = 0; ks < 4; ks++)
                    s += __uint_as_float(gload32((const u32*)&hup[((size_t)ks * BB + b) * HH + c]));
                huS[c] = s;
                vvS[c] = vvec[c];
            }
            __syncthreads();

            const int c0 = lane * 16;
            {
                int n = w;
                const u16* rp = encWaB + ((size_t)b * NP1 + n) * HH + c0;
                short8v e0 = *(const short8v*)(rp);
                short8v e1 = *(const short8v*)(rp + 8);
                while (n < NP1) {
                    const int n2 = n + 8;
                    short8v f0 = e0, f1 = e1;
                    if (n2 < NP1) {
                        const u16* rp2 = encWaB + ((size_t)b * NP1 + n2) * HH + c0;
                        f0 = *(const short8v*)(rp2);
                        f1 = *(const short8v*)(rp2 + 8);
                    }
                    float s = 0.f;
                    #pragma unroll
                    for (int j = 0; j < 8; j++)
                        s += vvS[c0 + j] * ftanh(b2f((u16)e0[j]) + huS[c0 + j]);
                    #pragma unroll
                    for (int j = 0; j < 8; j++)
                        s += vvS[c0 + 8 + j] * ftanh(b2f((u16)e1[j]) + huS[c0 + 8 + j]);
                    #pragma unroll
                    for (int off = 32; off; off >>= 1) s += __shfl_down(s, off);
                    if (lane == 0) scS[n] = s;
                    e0 = f0; e1 = f1; n = n2;
                }
            }
            __syncthreads();

            float va = -INFINITY;
            if (t < NP1) va = (mask[b * NP1 + t] != 0) ? -INFINITY : scS[t];
            rv[t] = va; ri[t] = t;
            __syncthreads();
            for (int s = 256; s; s >>= 1) {
                if (t < s) {
                    float ov = rv[t + s]; int oi = ri[t + s];
                    if (ov > rv[t] || (ov == rv[t] && oi < ri[t])) { rv[t] = ov; ri[t] = oi; }
                }
                __syncthreads();
            }
            const float vmax = rv[0]; const int amax = ri[0];
            __syncthreads();

            float es = (t < NP1) ? expf(va - vmax) : 0.f;
            rv[t] = es;
            __syncthreads();
            for (int s = 256; s; s >>= 1) {
                if (t < s) rv[t] += rv[t + s];
                __syncthreads();
            }
            const float lse = vmax + logf(rv[0]);

            if (t < NP1)
                out_lp[((size_t)b * NP1 + step) * NP1 + t] = fmaxf(va - lse, -1e30f);
            if (t == 0) {
                out_idx[(size_t)b * NP1 + step] = (float)amax;
                gstore32((u32*)&cur[b], (u32)amax);
                if (amax < NN) mask[b * NP1 + amax] = 1;
            }
        }
        pbar(slots, go, gen++);
    }
}

// ---------------------------------------------------------------------------
extern "C" void kernel_launch(void* const* d_in, const int* in_sizes, int n_in,
                              void* d_out, int out_size, void* d_ws, size_t ws_size,
                              hipStream_t stream) {
    const float* enc  = (const float*)d_in[0];
    const float* Wih  = (const float*)d_in[1];
    const float* Whh  = (const float*)d_in[2];
    const float* bih  = (const float*)d_in[3];
    const float* bhh  = (const float*)d_in[4];
    const float* Wa   = (const float*)d_in[5];
    const float* Ua   = (const float*)d_in[6];
    const float* v    = (const float*)d_in[7];
    const float* stok = (const float*)d_in[8];
    const float* etok = (const float*)d_in[9];
    float* out = (float*)d_out;
    float* out_idx = out + (size_t)BB * NP1 * NP1;

    size_t off = 0;
    char* base = (char*)d_ws;
    auto alloc = [&](size_t bytes) -> char* {
        char* p = base + off;
        off += (bytes + 255) & ~(size_t)255;
        return p;
    };
    u16*   encWaB = (u16*)  alloc((size_t)BB * NP1 * HH * 2);
    u16*   encB   = (u16*)  alloc((size_t)(BB * NN + 2) * HH * 2);
    u16*   Wpk    = (u16*)  alloc((size_t)4096 * 2048 * 2);
    u16*   Uab    = (u16*)  alloc((size_t)HH * HH * 2);
    float* bpk    = (float*)alloc((size_t)4096 * 4);
    float* hup    = (float*)alloc((size_t)4 * BB * HH * 4);
    float* cx     = (float*)alloc((size_t)BB * HH * 4);
    u16*   hxbA   = (u16*)  alloc((size_t)BB * HH * 2);
    u16*   hxbB   = (u16*)  alloc((size_t)BB * HH * 2);
    int*   mask   = (int*)  alloc((size_t)BB * NP1 * 4);
    int*   cur    = (int*)  alloc((size_t)BB * 4);
    int*   slots  = (int*)  alloc((size_t)256 * 16 * 4);
    int*   go     = (int*)  alloc((size_t)64);
    if (off > ws_size) return;   // distinctive failure: 0-node graph

    k_binit<<<512, 256, 0, stream>>>(cx, hxbA, mask, cur, slots, go);
    k_pack<<<4096, 256, 0, stream>>>(Wih, Whh, bih, bhh, Wpk, bpk);
    k_cvte<<<BB * NN + 2, 256, 0, stream>>>(enc, etok, stok, encB);
    k_cvtu<<<HH, 256, 0, stream>>>(Ua, Uab);
    k_encWa2b<<<dim3(257, 8), 256, 0, stream>>>(enc, etok, Wa, encWaB);

    void* args[] = { (void*)&encB, (void*)&Wpk, (void*)&bpk, (void*)&Uab,
                     (void*)&encWaB, (void*)&v, (void*)&cur, (void*)&mask,
                     (void*)&hxbA, (void*)&hxbB, (void*)&cx, (void*)&hup,
                     (void*)&out, (void*)&out_idx, (void*)&slots, (void*)&go };
    hipLaunchCooperativeKernel((const void*)k_persist, dim3(256), dim3(512),
                               args, 0, stream);
}

// Round 10
// 12129.155 us; speedup vs baseline: 1.6814x; 1.1616x over previous
//
#include <hip/hip_runtime.h>
#include <math.h>

#define BB 128
#define NN 256
#define NP1 257
#define HH 1024

typedef unsigned short u16;
typedef unsigned int u32;
typedef unsigned long long u64;
typedef __attribute__((ext_vector_type(8))) short short8v;
typedef __attribute__((ext_vector_type(4))) short short4v;
typedef __attribute__((ext_vector_type(4))) float float4v;

__device__ __forceinline__ u16 f2b(float x) {            // f32 -> bf16 (RNE)
    union { float f; u32 u; } c; c.f = x;
    u32 r = (c.u + 0x7fffu + ((c.u >> 16) & 1u)) >> 16;
    return (u16)r;
}
__device__ __forceinline__ float b2f(u16 s) {
    union { u32 u; float f; } c; c.u = ((u32)s) << 16;
    return c.f;
}
__device__ __forceinline__ float ftanh(float x) {
    float e = __builtin_amdgcn_exp2f(x * 2.8853900817779268f);
    return 1.f - 2.f * __builtin_amdgcn_rcpf(e + 1.f);
}
__device__ __forceinline__ float fsig(float x) {
    return __builtin_amdgcn_rcpf(1.f + __builtin_amdgcn_exp2f(x * -1.4426950408889634f));
}

// LLC-coherent (sc1) access helpers: relaxed agent atomics, no cache fences
__device__ __forceinline__ u64 gload64(const u16* p) {
    return __hip_atomic_load((u64*)p, __ATOMIC_RELAXED, __HIP_MEMORY_SCOPE_AGENT);
}
__device__ __forceinline__ short8v gload8h(const u16* p) {
    union { u64 q[2]; short8v v; } uq;
    uq.q[0] = gload64(p);
    uq.q[1] = gload64(p + 4);
    return uq.v;
}
__device__ __forceinline__ void gstore32(u32* p, u32 v) {
    __hip_atomic_store(p, v, __ATOMIC_RELAXED, __HIP_MEMORY_SCOPE_AGENT);
}
__device__ __forceinline__ u32 gload32(const u32* p) {
    return __hip_atomic_load((u32*)p, __ATOMIC_RELAXED, __HIP_MEMORY_SCOPE_AGENT);
}
// nontemporal load (nt flag): stream past L2, don't pollute it
__device__ __forceinline__ short8v ntload8h(const u16* p) {
    union { u64 q[2]; short8v v; } uq;
    uq.q[0] = __builtin_nontemporal_load((const u64*)p);
    uq.q[1] = __builtin_nontemporal_load((const u64*)p + 1);
    return uq.v;
}

#define CPHI(m) ((m) + (((m) >> 5) << 2))
#define KS2 72    // u16 LDS row stride for 64-wide bf16 k-chunks

// ---------------------------------------------------------------------------
// Fence-free grid barrier (round-9, proven): per-block slots + go word, sc1.
__device__ __forceinline__ void pbar(int* slots, int* go, int gen) {
    asm volatile("" ::: "memory");
    __syncthreads();
    const int t = threadIdx.x;
    if (blockIdx.x == 0) {
        if (t >= 1 && t < 256) {
            while ((int)gload32((u32*)&slots[t << 4]) < gen)
                __builtin_amdgcn_s_sleep(1);
        }
        __syncthreads();
        if (t == 0) gstore32((u32*)go, (u32)gen);
    } else {
        if (t == 0) {
            gstore32((u32*)&slots[blockIdx.x << 4], (u32)gen);
            while ((int)gload32((u32*)go) < gen)
                __builtin_amdgcn_s_sleep(1);
        }
        __syncthreads();
    }
    asm volatile("" ::: "memory");
}

// ---------------------------------------------------------------------------
__global__ __launch_bounds__(256) void k_binit(float* cx, u16* hxbA, int* mask,
                                               int* cur, int* slots, int* go,
                                               int* cflag) {
    int i = blockIdx.x * 256 + threadIdx.x;
    if (i < BB * HH) cx[i] = 0.f;
    if (i < BB * HH / 2) ((u32*)hxbA)[i] = 0u;
    if (i < BB * NP1) mask[i] = 0;
    if (i < BB) cur[i] = -1;
    if (i < 256 * 16) slots[i] = 0;
    if (i < BB * 16) cflag[i] = 0;
    if (i == 0) *go = 0;
}

// ---------------------------------------------------------------------------
__global__ __launch_bounds__(256) void k_pack(const float* __restrict__ Wih,
                                              const float* __restrict__ Whh,
                                              const float* __restrict__ bih,
                                              const float* __restrict__ bhh,
                                              u16* __restrict__ Wpk,
                                              float* __restrict__ bpk) {
    const int jp = blockIdx.x;
    const int nt = jp >> 6, r = jp & 63, g = r >> 4, c = r & 15;
    const int j = g * HH + nt * 16 + c;
    const int t = threadIdx.x;
    const int k = t * 8;
    const float* s = (k < HH) ? (Wih + (size_t)j * HH + k)
                              : (Whh + (size_t)j * HH + (k - HH));
    float4 v0 = *(const float4*)(s);
    float4 v1 = *(const float4*)(s + 4);
    short8v o;
    o[0]=(short)f2b(v0.x); o[1]=(short)f2b(v0.y); o[2]=(short)f2b(v0.z); o[3]=(short)f2b(v0.w);
    o[4]=(short)f2b(v1.x); o[5]=(short)f2b(v1.y); o[6]=(short)f2b(v1.z); o[7]=(short)f2b(v1.w);
    *(short8v*)(Wpk + (size_t)jp * 2048 + k) = o;
    if (t == 0) bpk[jp] = bih[j] + bhh[j];
}

__global__ __launch_bounds__(256) void k_cvte(const float* __restrict__ enc,
                                              const float* __restrict__ etok,
                                              const float* __restrict__ stok,
                                              u16* __restrict__ encB) {
    const int row = blockIdx.x;
    const float* src = (row < BB * NN) ? enc + (size_t)row * HH
                      : (row == BB * NN ? etok : stok);
    const int t = threadIdx.x;
    float4 v = *(const float4*)(src + t * 4);
    short4v o;
    o[0]=(short)f2b(v.x); o[1]=(short)f2b(v.y); o[2]=(short)f2b(v.z); o[3]=(short)f2b(v.w);
    *(short4v*)(encB + (size_t)row * HH + t * 4) = o;
}

__global__ __launch_bounds__(256) void k_cvtu(const float* __restrict__ Ua,
                                              u16* __restrict__ Uab) {
    const int row = blockIdx.x;
    const int t = threadIdx.x;
    float4 v = *(const float4*)(Ua + (size_t)row * HH + t * 4);
    short4v o;
    o[0]=(short)f2b(v.x); o[1]=(short)f2b(v.y); o[2]=(short)f2b(v.z); o[3]=(short)f2b(v.w);
    *(short4v*)(Uab + (size_t)row * HH + t * 4) = o;
}

// ---------------------------------------------------------------------------
__global__ __launch_bounds__(256, 2) void k_encWa2b(const float* __restrict__ enc,
                                                    const float* __restrict__ etok,
                                                    const float* __restrict__ Wa,
                                                    u16* __restrict__ out) {
    __shared__ float As[32][140];
    __shared__ float Ws[32][140];
    const int mt = blockIdx.x, ntl = blockIdx.y;
    const int tid = threadIdx.x;
    const int lr = tid >> 2, lc = tid & 3;
    const int tr = tid & 15, tc = tid >> 4;

    const int r0 = mt * 128 + lr, r1 = r0 + 64;
    const int bb0 = r0 / NP1, nn0 = r0 - bb0 * NP1;
    const int bb1 = r1 / NP1, nn1 = r1 - bb1 * NP1;
    const float* a0 = (nn0 == NN) ? etok : enc + ((size_t)(bb0 * NN + nn0)) * HH;
    const float* a1 = (nn1 == NN) ? etok : enc + ((size_t)(bb1 * NN + nn1)) * HH;
    const float* w0 = Wa + (size_t)(ntl * 128 + lr) * HH;
    const float* w1 = w0 + (size_t)64 * HH;
    const int ca = CPHI(lr), cb = CPHI(lr + 64);
    const int colA = tr * 8 + ((tr >> 2) << 2);
    const int colB = tc * 8 + ((tc >> 2) << 2);

    float acc[8][8] = {};
    for (int k0 = 0; k0 < HH; k0 += 32) {
        float4 va0 = *(const float4*)(a0 + k0 + lc * 4);
        float4 va1 = *(const float4*)(a0 + k0 + lc * 4 + 16);
        float4 va2 = *(const float4*)(a1 + k0 + lc * 4);
        float4 va3 = *(const float4*)(a1 + k0 + lc * 4 + 16);
        float4 vb0 = *(const float4*)(w0 + k0 + lc * 4);
        float4 vb1 = *(const float4*)(w0 + k0 + lc * 4 + 16);
        float4 vb2 = *(const float4*)(w1 + k0 + lc * 4);
        float4 vb3 = *(const float4*)(w1 + k0 + lc * 4 + 16);
        __syncthreads();
        #pragma unroll
        for (int e = 0; e < 4; e++) {
            As[lc*4+e][ca]      = ((const float*)&va0)[e];
            As[lc*4+16+e][ca]   = ((const float*)&va1)[e];
            As[lc*4+e][cb]      = ((const float*)&va2)[e];
            As[lc*4+16+e][cb]   = ((const float*)&va3)[e];
            Ws[lc*4+e][ca]      = ((const float*)&vb0)[e];
            Ws[lc*4+16+e][ca]   = ((const float*)&vb1)[e];
            Ws[lc*4+e][cb]      = ((const float*)&vb2)[e];
            Ws[lc*4+16+e][cb]   = ((const float*)&vb3)[e];
        }
        __syncthreads();
        #pragma unroll
        for (int kk = 0; kk < 32; kk++) {
            float4 A0 = *(const float4*)&As[kk][colA];
            float4 A1 = *(const float4*)&As[kk][colA + 4];
            float4 B0 = *(const float4*)&Ws[kk][colB];
            float4 B1 = *(const float4*)&Ws[kk][colB + 4];
            float av[8] = {A0.x,A0.y,A0.z,A0.w,A1.x,A1.y,A1.z,A1.w};
            float bv[8] = {B0.x,B0.y,B0.z,B0.w,B1.x,B1.y,B1.z,B1.w};
            #pragma unroll
            for (int i = 0; i < 8; i++)
                #pragma unroll
                for (int j = 0; j < 8; j++) acc[i][j] += av[i] * bv[j];
        }
        __syncthreads();
    }
    #pragma unroll
    for (int i = 0; i < 8; i++) {
        short8v o;
        #pragma unroll
        for (int j = 0; j < 8; j++) o[j] = (short)f2b(acc[i][j]);
        *(short8v*)(out + (size_t)(mt * 128 + tr * 8 + i) * HH + ntl * 128 + tc * 8) = o;
    }
}

// ---------------------------------------------------------------------------
// Persistent decode: 256 blocks x 512 threads.
// A: 8-wave split-K gates GEMM + cell (waves 0-3 x-part, 4-7 h-part)
// B: hUa partials (waves 0-3)
// C1: scores, 2 blocks/batch (n-split), nontemporal encWaB stream
// C2: finalize (blocks 0-127), partner signaled by per-batch flag
__global__ __launch_bounds__(512, 1) void k_persist(
    const u16* __restrict__ encB, const u16* __restrict__ Wpk,
    const float* __restrict__ bpk, const u16* __restrict__ Uab,
    const u16* __restrict__ encWaB, const float* __restrict__ vvec,
    int* __restrict__ cur, int* __restrict__ mask,
    u16* __restrict__ hxbA, u16* __restrict__ hxbB,
    float* __restrict__ cx, float* __restrict__ hup,
    float* __restrict__ scSg, int* __restrict__ cflag,
    float* __restrict__ out_lp, float* __restrict__ out_idx,
    int* __restrict__ slots, int* __restrict__ go)
{
    __shared__ u16 AsX[32 * KS2];
    __shared__ u16 BsX[64 * KS2];
    __shared__ u16 AsH[32 * KS2];
    __shared__ u16 BsH[64 * KS2];
    __shared__ float Gs[8][32][17];
    __shared__ float huS[HH];
    __shared__ float vvS[HH];
    __shared__ float rv[512];
    __shared__ int   ri[512];

    const int bid = blockIdx.x;
    const int t = threadIdx.x;
    const int wv = t >> 6, lane = t & 63;
    const int tg = t & 255, w4 = (t >> 6) & 3;
    int gen = 1;

    for (int step = 0; step < NP1; step++) {
        const u16* hin = (step & 1) ? hxbB : hxbA;
        u16* hout = (step & 1) ? hxbA : hxbB;

        // ============ phase A: gates GEMM + LSTM cell (8-wave split-K) =====
        {
            const int nt = bid & 63, mt = bid >> 6;
            const int rA = tg >> 3, koA = (tg & 7) * 8;
            const int rB = tg >> 2, koB = (tg & 3) * 16;
            const int mg = mt * 32 + rA;

            short8v hpre[16];
            short8v a_pf[2], b0_pf[3], b1_pf[3];
            const u16 *xrow = nullptr, *brow = nullptr;
            if (t < 256) {          // x-group
                const int sel = (int)gload32((const u32*)&cur[mg]);
                xrow = encB + (size_t)((sel < 0) ? (BB * NN + 1)
                             : (sel == NN ? BB * NN : (mg * NN + sel))) * HH;
                brow = Wpk + (size_t)(nt * 64 + rB) * 2048;
                a_pf[0] = *(const short8v*)(xrow + koA);
                a_pf[1] = *(const short8v*)(xrow + 64 + koA);
                #pragma unroll
                for (int d = 0; d < 3; d++) {
                    b0_pf[d] = *(const short8v*)(brow + d * 64 + koB);
                    b1_pf[d] = *(const short8v*)(brow + d * 64 + koB + 8);
                }
            } else {                // h-group
                const u16* hrow = hin + (size_t)mg * HH;
                #pragma unroll
                for (int i = 0; i < 16; i++)
                    hpre[i] = gload8h(hrow + i * 64 + koA);
                brow = Wpk + (size_t)(nt * 64 + rB) * 2048 + HH;
                #pragma unroll
                for (int d = 0; d < 3; d++) {
                    b0_pf[d] = *(const short8v*)(brow + d * 64 + koB);
                    b1_pf[d] = *(const short8v*)(brow + d * 64 + koB + 8);
                }
            }
            float4v acc0 = {}, acc1 = {};
            #pragma unroll
            for (int it = 0; it < 16; ++it) {
                __syncthreads();
                if (t < 256) {
                    *(short8v*)&AsX[rA * KS2 + koA] = a_pf[it & 1];
                    *(short8v*)&BsX[rB * KS2 + koB] = b0_pf[it % 3];
                    *(short8v*)&BsX[rB * KS2 + koB + 8] = b1_pf[it % 3];
                } else {
                    *(short8v*)&AsH[rA * KS2 + koA] = hpre[it];
                    *(short8v*)&BsH[rB * KS2 + koB] = b0_pf[it % 3];
                    *(short8v*)&BsH[rB * KS2 + koB + 8] = b1_pf[it % 3];
                }
                __syncthreads();
                if (t < 256) {
                    if (it + 2 < 16)
                        a_pf[it & 1] = *(const short8v*)(xrow + (it + 2) * 64 + koA);
                    if (it + 3 < 16) {
                        b0_pf[it % 3] = *(const short8v*)(brow + (it + 3) * 64 + koB);
                        b1_pf[it % 3] = *(const short8v*)(brow + (it + 3) * 64 + koB + 8);
                    }
                    #pragma unroll
                    for (int kf = 0; kf < 2; ++kf) {
                        short8v bf = *(const short8v*)&BsX[(w4 * 16 + (lane & 15)) * KS2 + kf * 32 + (lane >> 4) * 8];
                        short8v a0 = *(const short8v*)&AsX[(lane & 15) * KS2 + kf * 32 + (lane >> 4) * 8];
                        short8v a1 = *(const short8v*)&AsX[(16 + (lane & 15)) * KS2 + kf * 32 + (lane >> 4) * 8];
                        acc0 = __builtin_amdgcn_mfma_f32_16x16x32_bf16(a0, bf, acc0, 0, 0, 0);
                        acc1 = __builtin_amdgcn_mfma_f32_16x16x32_bf16(a1, bf, acc1, 0, 0, 0);
                    }
                } else {
                    if (it + 3 < 16) {
                        b0_pf[it % 3] = *(const short8v*)(brow + (it + 3) * 64 + koB);
                        b1_pf[it % 3] = *(const short8v*)(brow + (it + 3) * 64 + koB + 8);
                    }
                    #pragma unroll
                    for (int kf = 0; kf < 2; ++kf) {
                        short8v bf = *(const short8v*)&BsH[(w4 * 16 + (lane & 15)) * KS2 + kf * 32 + (lane >> 4) * 8];
                        short8v a0 = *(const short8v*)&AsH[(lane & 15) * KS2 + kf * 32 + (lane >> 4) * 8];
                        short8v a1 = *(const short8v*)&AsH[(16 + (lane & 15)) * KS2 + kf * 32 + (lane >> 4) * 8];
                        acc0 = __builtin_amdgcn_mfma_f32_16x16x32_bf16(a0, bf, acc0, 0, 0, 0);
                        acc1 = __builtin_amdgcn_mfma_f32_16x16x32_bf16(a1, bf, acc1, 0, 0, 0);
                    }
                }
            }
            __syncthreads();
            #pragma unroll
            for (int r = 0; r < 4; r++) {
                Gs[wv][(lane >> 4) * 4 + r][lane & 15]      = acc0[r];
                Gs[wv][16 + (lane >> 4) * 4 + r][lane & 15] = acc1[r];
            }
            __syncthreads();
            if (t < 256) {
                const int m = t >> 3, cpr = (t & 7) * 2;
                const int mg2 = mt * 32 + m;
                float hn2[2];
                #pragma unroll
                for (int e = 0; e < 2; e++) {
                    const int c = cpr + e;
                    float gi  = Gs[0][m][c] + Gs[4][m][c] + bpk[nt * 64 + c];
                    float gf  = Gs[1][m][c] + Gs[5][m][c] + bpk[nt * 64 + 16 + c];
                    float gg  = Gs[2][m][c] + Gs[6][m][c] + bpk[nt * 64 + 32 + c];
                    float go2 = Gs[3][m][c] + Gs[7][m][c] + bpk[nt * 64 + 48 + c];
                    const int cg = nt * 16 + c;
                    float cold = cx[(size_t)mg2 * HH + cg];
                    float cn = fsig(gf) * cold + fsig(gi) * ftanh(gg);
                    hn2[e] = fsig(go2) * ftanh(cn);
                    cx[(size_t)mg2 * HH + cg] = cn;
                }
                u32 pk = (u32)f2b(hn2[0]) | ((u32)f2b(hn2[1]) << 16);
                gstore32((u32*)(hout + (size_t)mg2 * HH + nt * 16 + cpr), pk);
            }
        }
        pbar(slots, go, gen++);

        // ============ phase B: hUa partials (waves 0-3) ====================
        {
            const int nt2 = bid & 15, mt2 = (bid >> 4) & 3, ks = bid >> 6;
            short8v hb[4];
            short8v ub0[2], ub1[2];
            const u16* brow = nullptr;
            const int rA = tg >> 3, koA = (tg & 7) * 8;
            const int rB = tg >> 2, koB = (tg & 3) * 16;
            if (t < 256) {
                const u16* arow = hout + (size_t)(mt2 * 32 + rA) * HH + ks * 256;
                #pragma unroll
                for (int i = 0; i < 4; i++)
                    hb[i] = gload8h(arow + i * 64 + koA);
                brow = Uab + (size_t)(nt2 * 64 + rB) * HH + ks * 256;
                #pragma unroll
                for (int d = 0; d < 2; d++) {
                    ub0[d] = *(const short8v*)(brow + d * 64 + koB);
                    ub1[d] = *(const short8v*)(brow + d * 64 + koB + 8);
                }
            }
            float4v acc0 = {}, acc1 = {};
            #pragma unroll
            for (int it = 0; it < 4; ++it) {
                __syncthreads();
                if (t < 256) {
                    *(short8v*)&AsX[rA * KS2 + koA] = hb[it];
                    *(short8v*)&BsX[rB * KS2 + koB] = ub0[it & 1];
                    *(short8v*)&BsX[rB * KS2 + koB + 8] = ub1[it & 1];
                }
                __syncthreads();
                if (t < 256) {
                    if (it + 2 < 4) {
                        ub0[it & 1] = *(const short8v*)(brow + (it + 2) * 64 + koB);
                        ub1[it & 1] = *(const short8v*)(brow + (it + 2) * 64 + koB + 8);
                    }
                    #pragma unroll
                    for (int kf = 0; kf < 2; ++kf) {
                        short8v bf = *(const short8v*)&BsX[(w4 * 16 + (lane & 15)) * KS2 + kf * 32 + (lane >> 4) * 8];
                        short8v a0 = *(const short8v*)&AsX[(lane & 15) * KS2 + kf * 32 + (lane >> 4) * 8];
                        short8v a1 = *(const short8v*)&AsX[(16 + (lane & 15)) * KS2 + kf * 32 + (lane >> 4) * 8];
                        acc0 = __builtin_amdgcn_mfma_f32_16x16x32_bf16(a0, bf, acc0, 0, 0, 0);
                        acc1 = __builtin_amdgcn_mfma_f32_16x16x32_bf16(a1, bf, acc1, 0, 0, 0);
                    }
                }
            }
            if (t < 256) {
                const int n = nt2 * 64 + w4 * 16 + (lane & 15);
                #pragma unroll
                for (int r = 0; r < 4; r++) {
                    const int m0 = mt2 * 32 + (lane >> 4) * 4 + r;
                    gstore32((u32*)&hup[((size_t)ks * BB + m0) * HH + n],
                             __float_as_uint(acc0[r]));
                    gstore32((u32*)&hup[((size_t)ks * BB + m0 + 16) * HH + n],
                             __float_as_uint(acc1[r]));
                }
            }
        }
        pbar(slots, go, gen++);

        // ============ phase C1: scores (all 256 blocks, 2/batch) ===========
        {
            const int qb = bid >> 7, b = bid & 127;
            #pragma unroll
            for (int cc = 0; cc < 2; cc++) {
                const int c = t + cc * 512;
                float s = 0.f;
                #pragma unroll
                for (int ks = 0; ks < 4; ks++)
                    s += __uint_as_float(gload32((const u32*)&hup[((size_t)ks * BB + b) * HH + c]));
                huS[c] = s;
                vvS[c] = vvec[c];
            }
            __syncthreads();

            const int c0 = lane * 16;
            const int nend = qb ? NP1 : 129;
            int n = (qb ? 129 : 0) + wv;
            if (n < nend) {
                const u16* rp = encWaB + ((size_t)b * NP1 + n) * HH + c0;
                short8v e0 = ntload8h(rp);
                short8v e1 = ntload8h(rp + 8);
                while (n < nend) {
                    const int n2 = n + 8;
                    short8v f0 = e0, f1 = e1;
                    if (n2 < nend) {
                        const u16* rp2 = encWaB + ((size_t)b * NP1 + n2) * HH + c0;
                        f0 = ntload8h(rp2);
                        f1 = ntload8h(rp2 + 8);
                    }
                    float s = 0.f;
                    #pragma unroll
                    for (int j = 0; j < 8; j++)
                        s += vvS[c0 + j] * ftanh(b2f((u16)e0[j]) + huS[c0 + j]);
                    #pragma unroll
                    for (int j = 0; j < 8; j++)
                        s += vvS[c0 + 8 + j] * ftanh(b2f((u16)e1[j]) + huS[c0 + 8 + j]);
                    #pragma unroll
                    for (int off = 32; off; off >>= 1) s += __shfl_down(s, off);
                    if (lane == 0)
                        gstore32((u32*)&scSg[b * NP1 + n], __float_as_uint(s));
                    e0 = f0; e1 = f1; n = n2;
                }
            }
            __syncthreads();
            if (qb == 1 && t == 0) gstore32((u32*)&cflag[b << 4], (u32)(step + 1));
        }

        // ============ phase C2: finalize (blocks 0..127) ===================
        if (bid < 128) {
            const int b = bid;
            if (t == 0) {
                while ((int)gload32((const u32*)&cflag[b << 4]) <= step)
                    __builtin_amdgcn_s_sleep(1);
            }
            __syncthreads();

            float va = -INFINITY;
            if (t < NP1) {
                float sc = __uint_as_float(gload32((const u32*)&scSg[b * NP1 + t]));
                va = (mask[b * NP1 + t] != 0) ? -INFINITY : sc;
            }
            rv[t] = va; ri[t] = t;
            __syncthreads();
            for (int s = 256; s; s >>= 1) {
                if (t < s) {
                    float ov = rv[t + s]; int oi = ri[t + s];
                    if (ov > rv[t] || (ov == rv[t] && oi < ri[t])) { rv[t] = ov; ri[t] = oi; }
                }
                __syncthreads();
            }
            const float vmax = rv[0]; const int amax = ri[0];
            __syncthreads();

            float es = (t < NP1) ? expf(va - vmax) : 0.f;
            rv[t] = es;
            __syncthreads();
            for (int s = 256; s; s >>= 1) {
                if (t < s) rv[t] += rv[t + s];
                __syncthreads();
            }
            const float lse = vmax + logf(rv[0]);

            if (t < NP1)
                out_lp[((size_t)b * NP1 + step) * NP1 + t] = fmaxf(va - lse, -1e30f);
            if (t == 0) {
                out_idx[(size_t)b * NP1 + step] = (float)amax;
                gstore32((u32*)&cur[b], (u32)amax);
                if (amax < NN) mask[b * NP1 + amax] = 1;
            }
        }
        pbar(slots, go, gen++);
    }
}

// ---------------------------------------------------------------------------
extern "C" void kernel_launch(void* const* d_in, const int* in_sizes, int n_in,
                              void* d_out, int out_size, void* d_ws, size_t ws_size,
                              hipStream_t stream) {
    const float* enc  = (const float*)d_in[0];
    const float* Wih  = (const float*)d_in[1];
    const float* Whh  = (const float*)d_in[2];
    const float* bih  = (const float*)d_in[3];
    const float* bhh  = (const float*)d_in[4];
    const float* Wa   = (const float*)d_in[5];
    const float* Ua   = (const float*)d_in[6];
    const float* v    = (const float*)d_in[7];
    const float* stok = (const float*)d_in[8];
    const float* etok = (const float*)d_in[9];
    float* out = (float*)d_out;
    float* out_idx = out + (size_t)BB * NP1 * NP1;

    size_t off = 0;
    char* base = (char*)d_ws;
    auto alloc = [&](size_t bytes) -> char* {
        char* p = base + off;
        off += (bytes + 255) & ~(size_t)255;
        return p;
    };
    u16*   encWaB = (u16*)  alloc((size_t)BB * NP1 * HH * 2);
    u16*   encB   = (u16*)  alloc((size_t)(BB * NN + 2) * HH * 2);
    u16*   Wpk    = (u16*)  alloc((size_t)4096 * 2048 * 2);
    u16*   Uab    = (u16*)  alloc((size_t)HH * HH * 2);
    float* bpk    = (float*)alloc((size_t)4096 * 4);
    float* hup    = (float*)alloc((size_t)4 * BB * HH * 4);
    float* cx     = (float*)alloc((size_t)BB * HH * 4);
    u16*   hxbA   = (u16*)  alloc((size_t)BB * HH * 2);
    u16*   hxbB   = (u16*)  alloc((size_t)BB * HH * 2);
    float* scSg   = (float*)alloc((size_t)BB * NP1 * 4);
    int*   mask   = (int*)  alloc((size_t)BB * NP1 * 4);
    int*   cur    = (int*)  alloc((size_t)BB * 4);
    int*   slots  = (int*)  alloc((size_t)256 * 16 * 4);
    int*   go     = (int*)  alloc((size_t)64);
    int*   cflag  = (int*)  alloc((size_t)BB * 16 * 4);
    if (off > ws_size) return;   // distinctive failure: 0-node graph

    k_binit<<<512, 256, 0, stream>>>(cx, hxbA, mask, cur, slots, go, cflag);
    k_pack<<<4096, 256, 0, stream>>>(Wih, Whh, bih, bhh, Wpk, bpk);
    k_cvte<<<BB * NN + 2, 256, 0, stream>>>(enc, etok, stok, encB);
    k_cvtu<<<HH, 256, 0, stream>>>(Ua, Uab);
    k_encWa2b<<<dim3(257, 8), 256, 0, stream>>>(enc, etok, Wa, encWaB);

    void* args[] = { (void*)&encB, (void*)&Wpk, (void*)&bpk, (void*)&Uab,
                     (void*)&encWaB, (void*)&v, (void*)&cur, (void*)&mask,
                     (void*)&hxbA, (void*)&hxbB, (void*)&cx, (void*)&hup,
                     (void*)&scSg, (void*)&cflag,
                     (void*)&out, (void*)&out_idx, (void*)&slots, (void*)&go };
    hipLaunchCooperativeKernel((const void*)k_persist, dim3(256), dim3(512),
                               args, 0, stream);
}

// Round 11
// 9669.967 us; speedup vs baseline: 2.1090x; 1.2543x over previous
//
#include <hip/hip_runtime.h>
#include <math.h>

#define BB 128
#define NN 256
#define NP1 257
#define HH 1024

typedef unsigned char u8;
typedef unsigned short u16;
typedef unsigned int u32;
typedef unsigned long long u64;
typedef __attribute__((ext_vector_type(8))) short short8v;
typedef __attribute__((ext_vector_type(4))) short short4v;
typedef __attribute__((ext_vector_type(4))) float float4v;

__device__ __forceinline__ u16 f2b(float x) {            // f32 -> bf16 (RNE)
    union { float f; u32 u; } c; c.f = x;
    u32 r = (c.u + 0x7fffu + ((c.u >> 16) & 1u)) >> 16;
    return (u16)r;
}
__device__ __forceinline__ float b2f(u16 s) {
    union { u32 u; float f; } c; c.u = ((u32)s) << 16;
    return c.f;
}
__device__ __forceinline__ float ftanh(float x) {
    float e = __builtin_amdgcn_exp2f(x * 2.8853900817779268f);
    return 1.f - 2.f * __builtin_amdgcn_rcpf(e + 1.f);
}
__device__ __forceinline__ float fsig(float x) {
    return __builtin_amdgcn_rcpf(1.f + __builtin_amdgcn_exp2f(x * -1.4426950408889634f));
}

// ---- fp8 e4m3fn helpers -----------------------------------------------------
__device__ __forceinline__ u8 f2e8(float x) {            // f32 -> e4m3 (RNE)
    u32 u = __float_as_uint(x);
    u32 sgn = (u >> 24) & 0x80u;
    float ax = __uint_as_float(u & 0x7fffffffu);
    if (!(ax < 448.f)) return (u8)(sgn | 0x7Eu);         // clamp, NaN -> max
    if (ax < 0.015625f) {                                // subnormal, q = 2^-9
        int q = (int)rintf(ax * 512.f);
        if (q >= 8) return (u8)(sgn | 0x08u);
        return (u8)(sgn | (u32)q);
    }
    u32 au = u & 0x7fffffffu;
    au += 0x7ffffu + ((au >> 20) & 1u);                  // RNE at bit 20
    int e = (int)(au >> 23) - 127;
    u32 m3 = (au >> 20) & 7u;
    if (e > 8 || (e == 8 && m3 == 7)) return (u8)(sgn | 0x7Eu);
    return (u8)(sgn | ((u32)(e + 7) << 3) | m3);
}
__device__ __forceinline__ float e82f(u32 u) {           // e4m3 -> f32 (exact)
    u32 t = ((u & 0x80u) << 24) | ((u & 0x7Fu) << 20);
    return __uint_as_float(t) * 0x1p+120f;
}

// LLC-coherent (sc1) access helpers: relaxed agent atomics, no cache fences
__device__ __forceinline__ u64 gload64(const u16* p) {
    return __hip_atomic_load((u64*)p, __ATOMIC_RELAXED, __HIP_MEMORY_SCOPE_AGENT);
}
__device__ __forceinline__ short8v gload8h(const u16* p) {
    union { u64 q[2]; short8v v; } uq;
    uq.q[0] = gload64(p);
    uq.q[1] = gload64(p + 4);
    return uq.v;
}
__device__ __forceinline__ void gstore32(u32* p, u32 v) {
    __hip_atomic_store(p, v, __ATOMIC_RELAXED, __HIP_MEMORY_SCOPE_AGENT);
}
__device__ __forceinline__ u32 gload32(const u32* p) {
    return __hip_atomic_load((u32*)p, __ATOMIC_RELAXED, __HIP_MEMORY_SCOPE_AGENT);
}

#define CPHI(m) ((m) + (((m) >> 5) << 2))
#define KS2 72    // u16 LDS row stride for 64-wide bf16 k-chunks

// ---------------------------------------------------------------------------
// Fence-free grid barrier (round-9, proven): per-block slots + go word, sc1.
__device__ __forceinline__ void pbar(int* slots, int* go, int gen) {
    asm volatile("" ::: "memory");
    __syncthreads();
    const int t = threadIdx.x;
    if (blockIdx.x == 0) {
        if (t >= 1 && t < 256) {
            while ((int)gload32((u32*)&slots[t << 4]) < gen)
                __builtin_amdgcn_s_sleep(1);
        }
        __syncthreads();
        if (t == 0) gstore32((u32*)go, (u32)gen);
    } else {
        if (t == 0) {
            gstore32((u32*)&slots[blockIdx.x << 4], (u32)gen);
            while ((int)gload32((u32*)go) < gen)
                __builtin_amdgcn_s_sleep(1);
        }
        __syncthreads();
    }
    asm volatile("" ::: "memory");
}

// ---------------------------------------------------------------------------
__global__ __launch_bounds__(256) void k_binit(float* cx, u16* hxbA, int* mask,
                                               int* cur, int* slots, int* go,
                                               int* cflag, int* nlist, int* cnt) {
    int i = blockIdx.x * 256 + threadIdx.x;
    if (i < BB * HH) cx[i] = 0.f;
    if (i < BB * HH / 2) ((u32*)hxbA)[i] = 0u;
    if (i < BB * NP1) { mask[i] = 0; nlist[i] = i % NP1; }
    if (i < BB) { cur[i] = -1; cnt[i] = NP1; }
    if (i < 256 * 16) slots[i] = 0;
    if (i < BB * 16) cflag[i] = 0;
    if (i == 0) *go = 0;
}

// ---------------------------------------------------------------------------
__global__ __launch_bounds__(256) void k_pack(const float* __restrict__ Wih,
                                              const float* __restrict__ Whh,
                                              const float* __restrict__ bih,
                                              const float* __restrict__ bhh,
                                              u16* __restrict__ Wpk,
                                              float* __restrict__ bpk) {
    const int jp = blockIdx.x;
    const int nt = jp >> 6, r = jp & 63, g = r >> 4, c = r & 15;
    const int j = g * HH + nt * 16 + c;
    const int t = threadIdx.x;
    const int k = t * 8;
    const float* s = (k < HH) ? (Wih + (size_t)j * HH + k)
                              : (Whh + (size_t)j * HH + (k - HH));
    float4 v0 = *(const float4*)(s);
    float4 v1 = *(const float4*)(s + 4);
    short8v o;
    o[0]=(short)f2b(v0.x); o[1]=(short)f2b(v0.y); o[2]=(short)f2b(v0.z); o[3]=(short)f2b(v0.w);
    o[4]=(short)f2b(v1.x); o[5]=(short)f2b(v1.y); o[6]=(short)f2b(v1.z); o[7]=(short)f2b(v1.w);
    *(short8v*)(Wpk + (size_t)jp * 2048 + k) = o;
    if (t == 0) bpk[jp] = bih[j] + bhh[j];
}

__global__ __launch_bounds__(256) void k_cvte(const float* __restrict__ enc,
                                              const float* __restrict__ etok,
                                              const float* __restrict__ stok,
                                              u16* __restrict__ encB) {
    const int row = blockIdx.x;
    const float* src = (row < BB * NN) ? enc + (size_t)row * HH
                      : (row == BB * NN ? etok : stok);
    const int t = threadIdx.x;
    float4 v = *(const float4*)(src + t * 4);
    short4v o;
    o[0]=(short)f2b(v.x); o[1]=(short)f2b(v.y); o[2]=(short)f2b(v.z); o[3]=(short)f2b(v.w);
    *(short4v*)(encB + (size_t)row * HH + t * 4) = o;
}

__global__ __launch_bounds__(256) void k_cvtu(const float* __restrict__ Ua,
                                              u16* __restrict__ Uab) {
    const int row = blockIdx.x;
    const int t = threadIdx.x;
    float4 v = *(const float4*)(Ua + (size_t)row * HH + t * 4);
    short4v o;
    o[0]=(short)f2b(v.x); o[1]=(short)f2b(v.y); o[2]=(short)f2b(v.z); o[3]=(short)f2b(v.w);
    *(short4v*)(Uab + (size_t)row * HH + t * 4) = o;
}

// ---------------------------------------------------------------------------
// encWa8[r, n] (fp8 e4m3) = sum_k ext[r,k] * Wa[n,k];  f32 math, fp8 store.
__global__ __launch_bounds__(256, 2) void k_encWa8(const float* __restrict__ enc,
                                                   const float* __restrict__ etok,
                                                   const float* __restrict__ Wa,
                                                   u8* __restrict__ out) {
    __shared__ float As[32][140];
    __shared__ float Ws[32][140];
    const int mt = blockIdx.x, ntl = blockIdx.y;
    const int tid = threadIdx.x;
    const int lr = tid >> 2, lc = tid & 3;
    const int tr = tid & 15, tc = tid >> 4;

    const int r0 = mt * 128 + lr, r1 = r0 + 64;
    const int bb0 = r0 / NP1, nn0 = r0 - bb0 * NP1;
    const int bb1 = r1 / NP1, nn1 = r1 - bb1 * NP1;
    const float* a0 = (nn0 == NN) ? etok : enc + ((size_t)(bb0 * NN + nn0)) * HH;
    const float* a1 = (nn1 == NN) ? etok : enc + ((size_t)(bb1 * NN + nn1)) * HH;
    const float* w0 = Wa + (size_t)(ntl * 128 + lr) * HH;
    const float* w1 = w0 + (size_t)64 * HH;
    const int ca = CPHI(lr), cb = CPHI(lr + 64);
    const int colA = tr * 8 + ((tr >> 2) << 2);
    const int colB = tc * 8 + ((tc >> 2) << 2);

    float acc[8][8] = {};
    for (int k0 = 0; k0 < HH; k0 += 32) {
        float4 va0 = *(const float4*)(a0 + k0 + lc * 4);
        float4 va1 = *(const float4*)(a0 + k0 + lc * 4 + 16);
        float4 va2 = *(const float4*)(a1 + k0 + lc * 4);
        float4 va3 = *(const float4*)(a1 + k0 + lc * 4 + 16);
        float4 vb0 = *(const float4*)(w0 + k0 + lc * 4);
        float4 vb1 = *(const float4*)(w0 + k0 + lc * 4 + 16);
        float4 vb2 = *(const float4*)(w1 + k0 + lc * 4);
        float4 vb3 = *(const float4*)(w1 + k0 + lc * 4 + 16);
        __syncthreads();
        #pragma unroll
        for (int e = 0; e < 4; e++) {
            As[lc*4+e][ca]      = ((const float*)&va0)[e];
            As[lc*4+16+e][ca]   = ((const float*)&va1)[e];
            As[lc*4+e][cb]      = ((const float*)&va2)[e];
            As[lc*4+16+e][cb]   = ((const float*)&va3)[e];
            Ws[lc*4+e][ca]      = ((const float*)&vb0)[e];
            Ws[lc*4+16+e][ca]   = ((const float*)&vb1)[e];
            Ws[lc*4+e][cb]      = ((const float*)&vb2)[e];
            Ws[lc*4+16+e][cb]   = ((const float*)&vb3)[e];
        }
        __syncthreads();
        #pragma unroll
        for (int kk = 0; kk < 32; kk++) {
            float4 A0 = *(const float4*)&As[kk][colA];
            float4 A1 = *(const float4*)&As[kk][colA + 4];
            float4 B0 = *(const float4*)&Ws[kk][colB];
            float4 B1 = *(const float4*)&Ws[kk][colB + 4];
            float av[8] = {A0.x,A0.y,A0.z,A0.w,A1.x,A1.y,A1.z,A1.w};
            float bv[8] = {B0.x,B0.y,B0.z,B0.w,B1.x,B1.y,B1.z,B1.w};
            #pragma unroll
            for (int i = 0; i < 8; i++)
                #pragma unroll
                for (int j = 0; j < 8; j++) acc[i][j] += av[i] * bv[j];
        }
        __syncthreads();
    }
    #pragma unroll
    for (int i = 0; i < 8; i++) {
        u64 pk = 0;
        #pragma unroll
        for (int j = 0; j < 8; j++)
            pk |= (u64)f2e8(acc[i][j]) << (8 * j);
        *(u64*)(out + (size_t)(mt * 128 + tr * 8 + i) * HH + ntl * 128 + tc * 8) = pk;
    }
}

// ---------------------------------------------------------------------------
// Persistent decode: 256 blocks x 512 threads.
// A: 8-wave split-K gates GEMM + cell;  B: hUa partials (waves 0-3)
// C1: scores over UNMASKED slots only (compact list, fp8 encWa, nt loads)
// C2: finalize + swap-remove selected index from list
__global__ __launch_bounds__(512, 1) void k_persist(
    const u16* __restrict__ encB, const u16* __restrict__ Wpk,
    const float* __restrict__ bpk, const u16* __restrict__ Uab,
    const u8* __restrict__ encWa8, const float* __restrict__ vvec,
    int* __restrict__ cur, int* __restrict__ mask,
    u16* __restrict__ hxbA, u16* __restrict__ hxbB,
    float* __restrict__ cx, float* __restrict__ hup,
    float* __restrict__ scSg, int* __restrict__ cflag,
    int* __restrict__ nlist, int* __restrict__ cnt,
    float* __restrict__ out_lp, float* __restrict__ out_idx,
    int* __restrict__ slots, int* __restrict__ go)
{
    __shared__ u16 AsX[32 * KS2];
    __shared__ u16 BsX[64 * KS2];
    __shared__ u16 AsH[32 * KS2];
    __shared__ u16 BsH[64 * KS2];
    __shared__ float Gs[8][32][17];
    __shared__ float huS[HH];
    __shared__ float vvS[HH];
    __shared__ float rv[512];
    __shared__ int   ri[512];
    __shared__ int   nlS[NP1];
    __shared__ int   posS;

    const int bid = blockIdx.x;
    const int t = threadIdx.x;
    const int wv = t >> 6, lane = t & 63;
    const int tg = t & 255, w4 = (t >> 6) & 3;
    int gen = 1;

    for (int step = 0; step < NP1; step++) {
        const u16* hin = (step & 1) ? hxbB : hxbA;
        u16* hout = (step & 1) ? hxbA : hxbB;

        // ============ phase A: gates GEMM + LSTM cell (8-wave split-K) =====
        {
            const int nt = bid & 63, mt = bid >> 6;
            const int rA = tg >> 3, koA = (tg & 7) * 8;
            const int rB = tg >> 2, koB = (tg & 3) * 16;
            const int mg = mt * 32 + rA;

            short8v hpre[16];
            short8v a_pf[2], b0_pf[3], b1_pf[3];
            const u16 *xrow = nullptr, *brow = nullptr;
            if (t < 256) {          // x-group
                const int sel = (int)gload32((const u32*)&cur[mg]);
                xrow = encB + (size_t)((sel < 0) ? (BB * NN + 1)
                             : (sel == NN ? BB * NN : (mg * NN + sel))) * HH;
                brow = Wpk + (size_t)(nt * 64 + rB) * 2048;
                a_pf[0] = *(const short8v*)(xrow + koA);
                a_pf[1] = *(const short8v*)(xrow + 64 + koA);
                #pragma unroll
                for (int d = 0; d < 3; d++) {
                    b0_pf[d] = *(const short8v*)(brow + d * 64 + koB);
                    b1_pf[d] = *(const short8v*)(brow + d * 64 + koB + 8);
                }
            } else {                // h-group
                const u16* hrow = hin + (size_t)mg * HH;
                #pragma unroll
                for (int i = 0; i < 16; i++)
                    hpre[i] = gload8h(hrow + i * 64 + koA);
                brow = Wpk + (size_t)(nt * 64 + rB) * 2048 + HH;
                #pragma unroll
                for (int d = 0; d < 3; d++) {
                    b0_pf[d] = *(const short8v*)(brow + d * 64 + koB);
                    b1_pf[d] = *(const short8v*)(brow + d * 64 + koB + 8);
                }
            }
            float4v acc0 = {}, acc1 = {};
            #pragma unroll
            for (int it = 0; it < 16; ++it) {
                __syncthreads();
                if (t < 256) {
                    *(short8v*)&AsX[rA * KS2 + koA] = a_pf[it & 1];
                    *(short8v*)&BsX[rB * KS2 + koB] = b0_pf[it % 3];
                    *(short8v*)&BsX[rB * KS2 + koB + 8] = b1_pf[it % 3];
                } else {
                    *(short8v*)&AsH[rA * KS2 + koA] = hpre[it];
                    *(short8v*)&BsH[rB * KS2 + koB] = b0_pf[it % 3];
                    *(short8v*)&BsH[rB * KS2 + koB + 8] = b1_pf[it % 3];
                }
                __syncthreads();
                if (t < 256) {
                    if (it + 2 < 16)
                        a_pf[it & 1] = *(const short8v*)(xrow + (it + 2) * 64 + koA);
                    if (it + 3 < 16) {
                        b0_pf[it % 3] = *(const short8v*)(brow + (it + 3) * 64 + koB);
                        b1_pf[it % 3] = *(const short8v*)(brow + (it + 3) * 64 + koB + 8);
                    }
                    #pragma unroll
                    for (int kf = 0; kf < 2; ++kf) {
                        short8v bf = *(const short8v*)&BsX[(w4 * 16 + (lane & 15)) * KS2 + kf * 32 + (lane >> 4) * 8];
                        short8v a0 = *(const short8v*)&AsX[(lane & 15) * KS2 + kf * 32 + (lane >> 4) * 8];
                        short8v a1 = *(const short8v*)&AsX[(16 + (lane & 15)) * KS2 + kf * 32 + (lane >> 4) * 8];
                        acc0 = __builtin_amdgcn_mfma_f32_16x16x32_bf16(a0, bf, acc0, 0, 0, 0);
                        acc1 = __builtin_amdgcn_mfma_f32_16x16x32_bf16(a1, bf, acc1, 0, 0, 0);
                    }
                } else {
                    if (it + 3 < 16) {
                        b0_pf[it % 3] = *(const short8v*)(brow + (it + 3) * 64 + koB);
                        b1_pf[it % 3] = *(const short8v*)(brow + (it + 3) * 64 + koB + 8);
                    }
                    #pragma unroll
                    for (int kf = 0; kf < 2; ++kf) {
                        short8v bf = *(const short8v*)&BsH[(w4 * 16 + (lane & 15)) * KS2 + kf * 32 + (lane >> 4) * 8];
                        short8v a0 = *(const short8v*)&AsH[(lane & 15) * KS2 + kf * 32 + (lane >> 4) * 8];
                        short8v a1 = *(const short8v*)&AsH[(16 + (lane & 15)) * KS2 + kf * 32 + (lane >> 4) * 8];
                        acc0 = __builtin_amdgcn_mfma_f32_16x16x32_bf16(a0, bf, acc0, 0, 0, 0);
                        acc1 = __builtin_amdgcn_mfma_f32_16x16x32_bf16(a1, bf, acc1, 0, 0, 0);
                    }
                }
            }
            __syncthreads();
            #pragma unroll
            for (int r = 0; r < 4; r++) {
                Gs[wv][(lane >> 4) * 4 + r][lane & 15]      = acc0[r];
                Gs[wv][16 + (lane >> 4) * 4 + r][lane & 15] = acc1[r];
            }
            __syncthreads();
            if (t < 256) {
                const int m = t >> 3, cpr = (t & 7) * 2;
                const int mg2 = mt * 32 + m;
                float hn2[2];
                #pragma unroll
                for (int e = 0; e < 2; e++) {
                    const int c = cpr + e;
                    float gi  = Gs[0][m][c] + Gs[4][m][c] + bpk[nt * 64 + c];
                    float gf  = Gs[1][m][c] + Gs[5][m][c] + bpk[nt * 64 + 16 + c];
                    float gg  = Gs[2][m][c] + Gs[6][m][c] + bpk[nt * 64 + 32 + c];
                    float go2 = Gs[3][m][c] + Gs[7][m][c] + bpk[nt * 64 + 48 + c];
                    const int cg = nt * 16 + c;
                    float cold = cx[(size_t)mg2 * HH + cg];
                    float cn = fsig(gf) * cold + fsig(gi) * ftanh(gg);
                    hn2[e] = fsig(go2) * ftanh(cn);
                    cx[(size_t)mg2 * HH + cg] = cn;
                }
                u32 pk = (u32)f2b(hn2[0]) | ((u32)f2b(hn2[1]) << 16);
                gstore32((u32*)(hout + (size_t)mg2 * HH + nt * 16 + cpr), pk);
            }
        }
        pbar(slots, go, gen++);

        // ============ phase B: hUa partials (waves 0-3) ====================
        {
            const int nt2 = bid & 15, mt2 = (bid >> 4) & 3, ks = bid >> 6;
            short8v hb[4];
            short8v ub0[2], ub1[2];
            const u16* brow = nullptr;
            const int rA = tg >> 3, koA = (tg & 7) * 8;
            const int rB = tg >> 2, koB = (tg & 3) * 16;
            if (t < 256) {
                const u16* arow = hout + (size_t)(mt2 * 32 + rA) * HH + ks * 256;
                #pragma unroll
                for (int i = 0; i < 4; i++)
                    hb[i] = gload8h(arow + i * 64 + koA);
                brow = Uab + (size_t)(nt2 * 64 + rB) * HH + ks * 256;
                #pragma unroll
                for (int d = 0; d < 2; d++) {
                    ub0[d] = *(const short8v*)(brow + d * 64 + koB);
                    ub1[d] = *(const short8v*)(brow + d * 64 + koB + 8);
                }
            }
            float4v acc0 = {}, acc1 = {};
            #pragma unroll
            for (int it = 0; it < 4; ++it) {
                __syncthreads();
                if (t < 256) {
                    *(short8v*)&AsX[rA * KS2 + koA] = hb[it];
                    *(short8v*)&BsX[rB * KS2 + koB] = ub0[it & 1];
                    *(short8v*)&BsX[rB * KS2 + koB + 8] = ub1[it & 1];
                }
                __syncthreads();
                if (t < 256) {
                    if (it + 2 < 4) {
                        ub0[it & 1] = *(const short8v*)(brow + (it + 2) * 64 + koB);
                        ub1[it & 1] = *(const short8v*)(brow + (it + 2) * 64 + koB + 8);
                    }
                    #pragma unroll
                    for (int kf = 0; kf < 2; ++kf) {
                        short8v bf = *(const short8v*)&BsX[(w4 * 16 + (lane & 15)) * KS2 + kf * 32 + (lane >> 4) * 8];
                        short8v a0 = *(const short8v*)&AsX[(lane & 15) * KS2 + kf * 32 + (lane >> 4) * 8];
                        short8v a1 = *(const short8v*)&AsX[(16 + (lane & 15)) * KS2 + kf * 32 + (lane >> 4) * 8];
                        acc0 = __builtin_amdgcn_mfma_f32_16x16x32_bf16(a0, bf, acc0, 0, 0, 0);
                        acc1 = __builtin_amdgcn_mfma_f32_16x16x32_bf16(a1, bf, acc1, 0, 0, 0);
                    }
                }
            }
            if (t < 256) {
                const int n = nt2 * 64 + w4 * 16 + (lane & 15);
                #pragma unroll
                for (int r = 0; r < 4; r++) {
                    const int m0 = mt2 * 32 + (lane >> 4) * 4 + r;
                    gstore32((u32*)&hup[((size_t)ks * BB + m0) * HH + n],
                             __float_as_uint(acc0[r]));
                    gstore32((u32*)&hup[((size_t)ks * BB + m0 + 16) * HH + n],
                             __float_as_uint(acc1[r]));
                }
            }
        }
        pbar(slots, go, gen++);

        // ============ phase C1: scores over UNMASKED slots (2 blocks/batch)
        int cntb_v = 0;
        {
            const int qb = bid >> 7, b = bid & 127;
            #pragma unroll
            for (int cc = 0; cc < 2; cc++) {
                const int c = t + cc * 512;
                float s = 0.f;
                #pragma unroll
                for (int ks = 0; ks < 4; ks++)
                    s += __uint_as_float(gload32((const u32*)&hup[((size_t)ks * BB + b) * HH + c]));
                huS[c] = s;
                vvS[c] = vvec[c];
            }
            cntb_v = (int)gload32((const u32*)&cnt[b]);
            for (int i = t; i < cntb_v; i += 512)
                nlS[i] = (int)gload32((const u32*)&nlist[b * NP1 + i]);
            __syncthreads();

            const int half = (cntb_v + 1) >> 1;
            const int iend = qb ? cntb_v : half;
            const int c0 = lane * 16;
            int i = (qb ? half : 0) + wv;
            if (i < iend) {
                const u8* rp = encWa8 + ((size_t)b * NP1 + nlS[i]) * HH + c0;
                u64 q0 = __builtin_nontemporal_load((const u64*)rp);
                u64 q1 = __builtin_nontemporal_load((const u64*)rp + 1);
                while (i < iend) {
                    const int i2 = i + 8;
                    u64 p0 = q0, p1 = q1;
                    if (i2 < iend) {
                        const u8* rp2 = encWa8 + ((size_t)b * NP1 + nlS[i2]) * HH + c0;
                        q0 = __builtin_nontemporal_load((const u64*)rp2);
                        q1 = __builtin_nontemporal_load((const u64*)rp2 + 1);
                    }
                    float s = 0.f;
                    #pragma unroll
                    for (int j = 0; j < 8; j++)
                        s += vvS[c0 + j] * ftanh(e82f((u32)(p0 >> (8 * j)) & 0xFFu) + huS[c0 + j]);
                    #pragma unroll
                    for (int j = 0; j < 8; j++)
                        s += vvS[c0 + 8 + j] * ftanh(e82f((u32)(p1 >> (8 * j)) & 0xFFu) + huS[c0 + 8 + j]);
                    #pragma unroll
                    for (int off = 32; off; off >>= 1) s += __shfl_down(s, off);
                    if (lane == 0)
                        gstore32((u32*)&scSg[b * NP1 + nlS[i]], __float_as_uint(s));
                    i = i2;
                }
            }
            __syncthreads();
            if (qb == 1 && t == 0) gstore32((u32*)&cflag[b << 4], (u32)(step + 1));
        }

        // ============ phase C2: finalize + list swap-remove (blocks 0..127)
        if (bid < 128) {
            const int b = bid;
            if (t == 0) {
                while ((int)gload32((const u32*)&cflag[b << 4]) <= step)
                    __builtin_amdgcn_s_sleep(1);
            }
            __syncthreads();

            float va = -INFINITY;
            if (t < NP1) {
                float sc = __uint_as_float(gload32((const u32*)&scSg[b * NP1 + t]));
                va = (mask[b * NP1 + t] != 0) ? -INFINITY : sc;
            }
            rv[t] = va; ri[t] = t;
            __syncthreads();
            for (int s = 256; s; s >>= 1) {
                if (t < s) {
                    float ov = rv[t + s]; int oi = ri[t + s];
                    if (ov > rv[t] || (ov == rv[t] && oi < ri[t])) { rv[t] = ov; ri[t] = oi; }
                }
                __syncthreads();
            }
            const float vmax = rv[0]; const int amax = ri[0];
            __syncthreads();

            float es = (t < NP1) ? expf(va - vmax) : 0.f;
            rv[t] = es;
            __syncthreads();
            for (int s = 256; s; s >>= 1) {
                if (t < s) rv[t] += rv[t + s];
                __syncthreads();
            }
            const float lse = vmax + logf(rv[0]);

            if (t < NP1)
                out_lp[((size_t)b * NP1 + step) * NP1 + t] = fmaxf(va - lse, -1e30f);

            // swap-remove amax from the unmasked list (end token stays)
            if (t == 0) posS = -1;
            __syncthreads();
            if (t < cntb_v && nlS[t] == amax) posS = t;
            __syncthreads();
            if (t == 0) {
                if (amax < NN && posS >= 0) {
                    gstore32((u32*)&nlist[b * NP1 + posS], (u32)nlS[cntb_v - 1]);
                    gstore32((u32*)&cnt[b], (u32)(cntb_v - 1));
                }
                out_idx[(size_t)b * NP1 + step] = (float)amax;
                gstore32((u32*)&cur[b], (u32)amax);
                if (amax < NN) mask[b * NP1 + amax] = 1;
            }
        }
        pbar(slots, go, gen++);
    }
}

// ---------------------------------------------------------------------------
extern "C" void kernel_launch(void* const* d_in, const int* in_sizes, int n_in,
                              void* d_out, int out_size, void* d_ws, size_t ws_size,
                              hipStream_t stream) {
    const float* enc  = (const float*)d_in[0];
    const float* Wih  = (const float*)d_in[1];
    const float* Whh  = (const float*)d_in[2];
    const float* bih  = (const float*)d_in[3];
    const float* bhh  = (const float*)d_in[4];
    const float* Wa   = (const float*)d_in[5];
    const float* Ua   = (const float*)d_in[6];
    const float* v    = (const float*)d_in[7];
    const float* stok = (const float*)d_in[8];
    const float* etok = (const float*)d_in[9];
    float* out = (float*)d_out;
    float* out_idx = out + (size_t)BB * NP1 * NP1;

    size_t off = 0;
    char* base = (char*)d_ws;
    auto alloc = [&](size_t bytes) -> char* {
        char* p = base + off;
        off += (bytes + 255) & ~(size_t)255;
        return p;
    };
    u8*    encWa8 = (u8*)   alloc((size_t)BB * NP1 * HH);          // 33.7 MB
    u16*   encB   = (u16*)  alloc((size_t)(BB * NN + 2) * HH * 2); // 67.1 MB
    u16*   Wpk    = (u16*)  alloc((size_t)4096 * 2048 * 2);        // 16.8 MB
    u16*   Uab    = (u16*)  alloc((size_t)HH * HH * 2);
    float* bpk    = (float*)alloc((size_t)4096 * 4);
    float* hup    = (float*)alloc((size_t)4 * BB * HH * 4);
    float* cx     = (float*)alloc((size_t)BB * HH * 4);
    u16*   hxbA   = (u16*)  alloc((size_t)BB * HH * 2);
    u16*   hxbB   = (u16*)  alloc((size_t)BB * HH * 2);
    float* scSg   = (float*)alloc((size_t)BB * NP1 * 4);
    int*   mask   = (int*)  alloc((size_t)BB * NP1 * 4);
    int*   nlist  = (int*)  alloc((size_t)BB * NP1 * 4);
    int*   cnt    = (int*)  alloc((size_t)BB * 4);
    int*   cur    = (int*)  alloc((size_t)BB * 4);
    int*   slots  = (int*)  alloc((size_t)256 * 16 * 4);
    int*   go     = (int*)  alloc((size_t)64);
    int*   cflag  = (int*)  alloc((size_t)BB * 16 * 4);
    if (off > ws_size) return;   // distinctive failure: 0-node graph

    k_binit<<<512, 256, 0, stream>>>(cx, hxbA, mask, cur, slots, go, cflag,
                                     nlist, cnt);
    k_pack<<<4096, 256, 0, stream>>>(Wih, Whh, bih, bhh, Wpk, bpk);
    k_cvte<<<BB * NN + 2, 256, 0, stream>>>(enc, etok, stok, encB);
    k_cvtu<<<HH, 256, 0, stream>>>(Ua, Uab);
    k_encWa8<<<dim3(257, 8), 256, 0, stream>>>(enc, etok, Wa, encWa8);

    void* args[] = { (void*)&encB, (void*)&Wpk, (void*)&bpk, (void*)&Uab,
                     (void*)&encWa8, (void*)&v, (void*)&cur, (void*)&mask,
                     (void*)&hxbA, (void*)&hxbB, (void*)&cx, (void*)&hup,
                     (void*)&scSg, (void*)&cflag, (void*)&nlist, (void*)&cnt,
                     (void*)&out, (void*)&out_idx, (void*)&slots, (void*)&go };
    hipLaunchCooperativeKernel((const void*)k_persist, dim3(256), dim3(512),
                               args, 0, stream);
}

// Round 12
// 9485.778 us; speedup vs baseline: 2.1500x; 1.0194x over previous
//
#include <hip/hip_runtime.h>
#include <math.h>

#define BB 128
#define NN 256
#define NP1 257
#define HH 1024

typedef unsigned char u8;
typedef unsigned short u16;
typedef unsigned int u32;
typedef unsigned long long u64;
typedef __attribute__((ext_vector_type(8))) short short8v;
typedef __attribute__((ext_vector_type(4))) short short4v;
typedef __attribute__((ext_vector_type(4))) float float4v;

__device__ __forceinline__ u16 f2b(float x) {            // f32 -> bf16 (RNE)
    union { float f; u32 u; } c; c.f = x;
    u32 r = (c.u + 0x7fffu + ((c.u >> 16) & 1u)) >> 16;
    return (u16)r;
}
__device__ __forceinline__ float b2f(u16 s) {
    union { u32 u; float f; } c; c.u = ((u32)s) << 16;
    return c.f;
}
__device__ __forceinline__ float ftanh(float x) {
    float e = __builtin_amdgcn_exp2f(x * 2.8853900817779268f);
    return 1.f - 2.f * __builtin_amdgcn_rcpf(e + 1.f);
}
__device__ __forceinline__ float fsig(float x) {
    return __builtin_amdgcn_rcpf(1.f + __builtin_amdgcn_exp2f(x * -1.4426950408889634f));
}

// ---- fp8 e4m3fn helpers -----------------------------------------------------
__device__ __forceinline__ u8 f2e8(float x) {            // f32 -> e4m3 (RNE)
    u32 u = __float_as_uint(x);
    u32 sgn = (u >> 24) & 0x80u;
    float ax = __uint_as_float(u & 0x7fffffffu);
    if (!(ax < 448.f)) return (u8)(sgn | 0x7Eu);         // clamp, NaN -> max
    if (ax < 0.015625f) {                                // subnormal, q = 2^-9
        int q = (int)rintf(ax * 512.f);
        if (q >= 8) return (u8)(sgn | 0x08u);
        return (u8)(sgn | (u32)q);
    }
    u32 au = u & 0x7fffffffu;
    au += 0x7ffffu + ((au >> 20) & 1u);                  // RNE at bit 20
    int e = (int)(au >> 23) - 127;
    u32 m3 = (au >> 20) & 7u;
    if (e > 8 || (e == 8 && m3 == 7)) return (u8)(sgn | 0x7Eu);
    return (u8)(sgn | ((u32)(e + 7) << 3) | m3);
}
__device__ __forceinline__ float e82f(u32 u) {           // e4m3 -> f32 (exact)
    u32 t = ((u & 0x80u) << 24) | ((u & 0x7Fu) << 20);
    return __uint_as_float(t) * 0x1p+120f;
}

// LLC-coherent (sc1) access helpers: relaxed agent atomics bypass the per-XCD
// L2 but are served by (and allocate in) the 256MB LLC -> no L2 pollution AND
// LLC residency. (Round-11 lesson: nt-loads skip the LLC too -> 5 GB/dispatch
// HBM refetch of a 34 MB buffer.)
__device__ __forceinline__ u64 gload64(const u16* p) {
    return __hip_atomic_load((u64*)p, __ATOMIC_RELAXED, __HIP_MEMORY_SCOPE_AGENT);
}
__device__ __forceinline__ u64 gload64b(const u8* p) {
    return __hip_atomic_load((const u64*)p, __ATOMIC_RELAXED, __HIP_MEMORY_SCOPE_AGENT);
}
__device__ __forceinline__ short8v gload8h(const u16* p) {
    union { u64 q[2]; short8v v; } uq;
    uq.q[0] = gload64(p);
    uq.q[1] = gload64(p + 4);
    return uq.v;
}
__device__ __forceinline__ void gstore32(u32* p, u32 v) {
    __hip_atomic_store(p, v, __ATOMIC_RELAXED, __HIP_MEMORY_SCOPE_AGENT);
}
__device__ __forceinline__ u32 gload32(const u32* p) {
    return __hip_atomic_load((u32*)p, __ATOMIC_RELAXED, __HIP_MEMORY_SCOPE_AGENT);
}

#define CPHI(m) ((m) + (((m) >> 5) << 2))
#define KS2 72    // u16 LDS row stride for 64-wide bf16 k-chunks

// ---------------------------------------------------------------------------
// Fence-free grid barrier (round-9, proven): per-block slots + go word, sc1.
__device__ __forceinline__ void pbar(int* slots, int* go, int gen) {
    asm volatile("" ::: "memory");
    __syncthreads();
    const int t = threadIdx.x;
    if (blockIdx.x == 0) {
        if (t >= 1 && t < 256) {
            while ((int)gload32((u32*)&slots[t << 4]) < gen)
                __builtin_amdgcn_s_sleep(1);
        }
        __syncthreads();
        if (t == 0) gstore32((u32*)go, (u32)gen);
    } else {
        if (t == 0) {
            gstore32((u32*)&slots[blockIdx.x << 4], (u32)gen);
            while ((int)gload32((u32*)go) < gen)
                __builtin_amdgcn_s_sleep(1);
        }
        __syncthreads();
    }
    asm volatile("" ::: "memory");
}

// ---------------------------------------------------------------------------
__global__ __launch_bounds__(256) void k_binit(float* cx, u16* hxbA, int* mask,
                                               int* cur, int* slots, int* go,
                                               int* cflag, int* nlist, int* cnt) {
    int i = blockIdx.x * 256 + threadIdx.x;
    if (i < BB * HH) cx[i] = 0.f;
    if (i < BB * HH / 2) ((u32*)hxbA)[i] = 0u;
    if (i < BB * NP1) { mask[i] = 0; nlist[i] = i % NP1; }
    if (i < BB) { cur[i] = -1; cnt[i] = NP1; }
    if (i < 256 * 16) slots[i] = 0;
    if (i < BB * 16) cflag[i] = 0;
    if (i == 0) *go = 0;
}

// ---------------------------------------------------------------------------
__global__ __launch_bounds__(256) void k_pack(const float* __restrict__ Wih,
                                              const float* __restrict__ Whh,
                                              const float* __restrict__ bih,
                                              const float* __restrict__ bhh,
                                              u16* __restrict__ Wpk,
                                              float* __restrict__ bpk) {
    const int jp = blockIdx.x;
    const int nt = jp >> 6, r = jp & 63, g = r >> 4, c = r & 15;
    const int j = g * HH + nt * 16 + c;
    const int t = threadIdx.x;
    const int k = t * 8;
    const float* s = (k < HH) ? (Wih + (size_t)j * HH + k)
                              : (Whh + (size_t)j * HH + (k - HH));
    float4 v0 = *(const float4*)(s);
    float4 v1 = *(const float4*)(s + 4);
    short8v o;
    o[0]=(short)f2b(v0.x); o[1]=(short)f2b(v0.y); o[2]=(short)f2b(v0.z); o[3]=(short)f2b(v0.w);
    o[4]=(short)f2b(v1.x); o[5]=(short)f2b(v1.y); o[6]=(short)f2b(v1.z); o[7]=(short)f2b(v1.w);
    *(short8v*)(Wpk + (size_t)jp * 2048 + k) = o;
    if (t == 0) bpk[jp] = bih[j] + bhh[j];
}

__global__ __launch_bounds__(256) void k_cvte(const float* __restrict__ enc,
                                              const float* __restrict__ etok,
                                              const float* __restrict__ stok,
                                              u16* __restrict__ encB) {
    const int row = blockIdx.x;
    const float* src = (row < BB * NN) ? enc + (size_t)row * HH
                      : (row == BB * NN ? etok : stok);
    const int t = threadIdx.x;
    float4 v = *(const float4*)(src + t * 4);
    short4v o;
    o[0]=(short)f2b(v.x); o[1]=(short)f2b(v.y); o[2]=(short)f2b(v.z); o[3]=(short)f2b(v.w);
    *(short4v*)(encB + (size_t)row * HH + t * 4) = o;
}

__global__ __launch_bounds__(256) void k_cvtu(const float* __restrict__ Ua,
                                              u16* __restrict__ Uab) {
    const int row = blockIdx.x;
    const int t = threadIdx.x;
    float4 v = *(const float4*)(Ua + (size_t)row * HH + t * 4);
    short4v o;
    o[0]=(short)f2b(v.x); o[1]=(short)f2b(v.y); o[2]=(short)f2b(v.z); o[3]=(short)f2b(v.w);
    *(short4v*)(Uab + (size_t)row * HH + t * 4) = o;
}

// ---------------------------------------------------------------------------
// encWa8[r, n] (fp8 e4m3) = sum_k ext[r,k] * Wa[n,k];  f32 math, fp8 store.
__global__ __launch_bounds__(256, 2) void k_encWa8(const float* __restrict__ enc,
                                                   const float* __restrict__ etok,
                                                   const float* __restrict__ Wa,
                                                   u8* __restrict__ out) {
    __shared__ float As[32][140];
    __shared__ float Ws[32][140];
    const int mt = blockIdx.x, ntl = blockIdx.y;
    const int tid = threadIdx.x;
    const int lr = tid >> 2, lc = tid & 3;
    const int tr = tid & 15, tc = tid >> 4;

    const int r0 = mt * 128 + lr, r1 = r0 + 64;
    const int bb0 = r0 / NP1, nn0 = r0 - bb0 * NP1;
    const int bb1 = r1 / NP1, nn1 = r1 - bb1 * NP1;
    const float* a0 = (nn0 == NN) ? etok : enc + ((size_t)(bb0 * NN + nn0)) * HH;
    const float* a1 = (nn1 == NN) ? etok : enc + ((size_t)(bb1 * NN + nn1)) * HH;
    const float* w0 = Wa + (size_t)(ntl * 128 + lr) * HH;
    const float* w1 = w0 + (size_t)64 * HH;
    const int ca = CPHI(lr), cb = CPHI(lr + 64);
    const int colA = tr * 8 + ((tr >> 2) << 2);
    const int colB = tc * 8 + ((tc >> 2) << 2);

    float acc[8][8] = {};
    for (int k0 = 0; k0 < HH; k0 += 32) {
        float4 va0 = *(const float4*)(a0 + k0 + lc * 4);
        float4 va1 = *(const float4*)(a0 + k0 + lc * 4 + 16);
        float4 va2 = *(const float4*)(a1 + k0 + lc * 4);
        float4 va3 = *(const float4*)(a1 + k0 + lc * 4 + 16);
        float4 vb0 = *(const float4*)(w0 + k0 + lc * 4);
        float4 vb1 = *(const float4*)(w0 + k0 + lc * 4 + 16);
        float4 vb2 = *(const float4*)(w1 + k0 + lc * 4);
        float4 vb3 = *(const float4*)(w1 + k0 + lc * 4 + 16);
        __syncthreads();
        #pragma unroll
        for (int e = 0; e < 4; e++) {
            As[lc*4+e][ca]      = ((const float*)&va0)[e];
            As[lc*4+16+e][ca]   = ((const float*)&va1)[e];
            As[lc*4+e][cb]      = ((const float*)&va2)[e];
            As[lc*4+16+e][cb]   = ((const float*)&va3)[e];
            Ws[lc*4+e][ca]      = ((const float*)&vb0)[e];
            Ws[lc*4+16+e][ca]   = ((const float*)&vb1)[e];
            Ws[lc*4+e][cb]      = ((const float*)&vb2)[e];
            Ws[lc*4+16+e][cb]   = ((const float*)&vb3)[e];
        }
        __syncthreads();
        #pragma unroll
        for (int kk = 0; kk < 32; kk++) {
            float4 A0 = *(const float4*)&As[kk][colA];
            float4 A1 = *(const float4*)&As[kk][colA + 4];
            float4 B0 = *(const float4*)&Ws[kk][colB];
            float4 B1 = *(const float4*)&Ws[kk][colB + 4];
            float av[8] = {A0.x,A0.y,A0.z,A0.w,A1.x,A1.y,A1.z,A1.w};
            float bv[8] = {B0.x,B0.y,B0.z,B0.w,B1.x,B1.y,B1.z,B1.w};
            #pragma unroll
            for (int i = 0; i < 8; i++)
                #pragma unroll
                for (int j = 0; j < 8; j++) acc[i][j] += av[i] * bv[j];
        }
        __syncthreads();
    }
    #pragma unroll
    for (int i = 0; i < 8; i++) {
        u64 pk = 0;
        #pragma unroll
        for (int j = 0; j < 8; j++)
            pk |= (u64)f2e8(acc[i][j]) << (8 * j);
        *(u64*)(out + (size_t)(mt * 128 + tr * 8 + i) * HH + ntl * 128 + tc * 8) = pk;
    }
}

// ---------------------------------------------------------------------------
// Persistent decode: 256 blocks x 512 threads.
// A: 8-wave split-K gates GEMM + cell;  B: hUa partials (waves 0-3)
// C1: scores over UNMASKED slots only (compact list, fp8 encWa, sc1 loads)
// C2: finalize + swap-remove selected index from list
__global__ __launch_bounds__(512, 1) void k_persist(
    const u16* __restrict__ encB, const u16* __restrict__ Wpk,
    const float* __restrict__ bpk, const u16* __restrict__ Uab,
    const u8* __restrict__ encWa8, const float* __restrict__ vvec,
    int* __restrict__ cur, int* __restrict__ mask,
    u16* __restrict__ hxbA, u16* __restrict__ hxbB,
    float* __restrict__ cx, float* __restrict__ hup,
    float* __restrict__ scSg, int* __restrict__ cflag,
    int* __restrict__ nlist, int* __restrict__ cnt,
    float* __restrict__ out_lp, float* __restrict__ out_idx,
    int* __restrict__ slots, int* __restrict__ go)
{
    __shared__ u16 AsX[32 * KS2];
    __shared__ u16 BsX[64 * KS2];
    __shared__ u16 AsH[32 * KS2];
    __shared__ u16 BsH[64 * KS2];
    __shared__ float Gs[8][32][17];
    __shared__ float huS[HH];
    __shared__ float vvS[HH];
    __shared__ float rv[512];
    __shared__ int   ri[512];
    __shared__ int   nlS[NP1];
    __shared__ int   posS;

    const int bid = blockIdx.x;
    const int t = threadIdx.x;
    const int wv = t >> 6, lane = t & 63;
    const int tg = t & 255, w4 = (t >> 6) & 3;
    int gen = 1;

    for (int step = 0; step < NP1; step++) {
        const u16* hin = (step & 1) ? hxbB : hxbA;
        u16* hout = (step & 1) ? hxbA : hxbB;

        // ============ phase A: gates GEMM + LSTM cell (8-wave split-K) =====
        {
            const int nt = bid & 63, mt = bid >> 6;
            const int rA = tg >> 3, koA = (tg & 7) * 8;
            const int rB = tg >> 2, koB = (tg & 3) * 16;
            const int mg = mt * 32 + rA;

            short8v hpre[16];
            short8v a_pf[2], b0_pf[3], b1_pf[3];
            const u16 *xrow = nullptr, *brow = nullptr;
            if (t < 256) {          // x-group
                const int sel = (int)gload32((const u32*)&cur[mg]);
                xrow = encB + (size_t)((sel < 0) ? (BB * NN + 1)
                             : (sel == NN ? BB * NN : (mg * NN + sel))) * HH;
                brow = Wpk + (size_t)(nt * 64 + rB) * 2048;
                a_pf[0] = *(const short8v*)(xrow + koA);
                a_pf[1] = *(const short8v*)(xrow + 64 + koA);
                #pragma unroll
                for (int d = 0; d < 3; d++) {
                    b0_pf[d] = *(const short8v*)(brow + d * 64 + koB);
                    b1_pf[d] = *(const short8v*)(brow + d * 64 + koB + 8);
                }
            } else {                // h-group
                const u16* hrow = hin + (size_t)mg * HH;
                #pragma unroll
                for (int i = 0; i < 16; i++)
                    hpre[i] = gload8h(hrow + i * 64 + koA);
                brow = Wpk + (size_t)(nt * 64 + rB) * 2048 + HH;
                #pragma unroll
                for (int d = 0; d < 3; d++) {
                    b0_pf[d] = *(const short8v*)(brow + d * 64 + koB);
                    b1_pf[d] = *(const short8v*)(brow + d * 64 + koB + 8);
                }
            }
            float4v acc0 = {}, acc1 = {};
            #pragma unroll
            for (int it = 0; it < 16; ++it) {
                __syncthreads();
                if (t < 256) {
                    *(short8v*)&AsX[rA * KS2 + koA] = a_pf[it & 1];
                    *(short8v*)&BsX[rB * KS2 + koB] = b0_pf[it % 3];
                    *(short8v*)&BsX[rB * KS2 + koB + 8] = b1_pf[it % 3];
                } else {
                    *(short8v*)&AsH[rA * KS2 + koA] = hpre[it];
                    *(short8v*)&BsH[rB * KS2 + koB] = b0_pf[it % 3];
                    *(short8v*)&BsH[rB * KS2 + koB + 8] = b1_pf[it % 3];
                }
                __syncthreads();
                if (t < 256) {
                    if (it + 2 < 16)
                        a_pf[it & 1] = *(const short8v*)(xrow + (it + 2) * 64 + koA);
                    if (it + 3 < 16) {
                        b0_pf[it % 3] = *(const short8v*)(brow + (it + 3) * 64 + koB);
                        b1_pf[it % 3] = *(const short8v*)(brow + (it + 3) * 64 + koB + 8);
                    }
                    #pragma unroll
                    for (int kf = 0; kf < 2; ++kf) {
                        short8v bf = *(const short8v*)&BsX[(w4 * 16 + (lane & 15)) * KS2 + kf * 32 + (lane >> 4) * 8];
                        short8v a0 = *(const short8v*)&AsX[(lane & 15) * KS2 + kf * 32 + (lane >> 4) * 8];
                        short8v a1 = *(const short8v*)&AsX[(16 + (lane & 15)) * KS2 + kf * 32 + (lane >> 4) * 8];
                        acc0 = __builtin_amdgcn_mfma_f32_16x16x32_bf16(a0, bf, acc0, 0, 0, 0);
                        acc1 = __builtin_amdgcn_mfma_f32_16x16x32_bf16(a1, bf, acc1, 0, 0, 0);
                    }
                } else {
                    if (it + 3 < 16) {
                        b0_pf[it % 3] = *(const short8v*)(brow + (it + 3) * 64 + koB);
                        b1_pf[it % 3] = *(const short8v*)(brow + (it + 3) * 64 + koB + 8);
                    }
                    #pragma unroll
                    for (int kf = 0; kf < 2; ++kf) {
                        short8v bf = *(const short8v*)&BsH[(w4 * 16 + (lane & 15)) * KS2 + kf * 32 + (lane >> 4) * 8];
                        short8v a0 = *(const short8v*)&AsH[(lane & 15) * KS2 + kf * 32 + (lane >> 4) * 8];
                        short8v a1 = *(const short8v*)&AsH[(16 + (lane & 15)) * KS2 + kf * 32 + (lane >> 4) * 8];
                        acc0 = __builtin_amdgcn_mfma_f32_16x16x32_bf16(a0, bf, acc0, 0, 0, 0);
                        acc1 = __builtin_amdgcn_mfma_f32_16x16x32_bf16(a1, bf, acc1, 0, 0, 0);
                    }
                }
            }
            __syncthreads();
            #pragma unroll
            for (int r = 0; r < 4; r++) {
                Gs[wv][(lane >> 4) * 4 + r][lane & 15]      = acc0[r];
                Gs[wv][16 + (lane >> 4) * 4 + r][lane & 15] = acc1[r];
            }
            __syncthreads();
            if (t < 256) {
                const int m = t >> 3, cpr = (t & 7) * 2;
                const int mg2 = mt * 32 + m;
                float hn2[2];
                #pragma unroll
                for (int e = 0; e < 2; e++) {
                    const int c = cpr + e;
                    float gi  = Gs[0][m][c] + Gs[4][m][c] + bpk[nt * 64 + c];
                    float gf  = Gs[1][m][c] + Gs[5][m][c] + bpk[nt * 64 + 16 + c];
                    float gg  = Gs[2][m][c] + Gs[6][m][c] + bpk[nt * 64 + 32 + c];
                    float go2 = Gs[3][m][c] + Gs[7][m][c] + bpk[nt * 64 + 48 + c];
                    const int cg = nt * 16 + c;
                    float cold = cx[(size_t)mg2 * HH + cg];
                    float cn = fsig(gf) * cold + fsig(gi) * ftanh(gg);
                    hn2[e] = fsig(go2) * ftanh(cn);
                    cx[(size_t)mg2 * HH + cg] = cn;
                }
                u32 pk = (u32)f2b(hn2[0]) | ((u32)f2b(hn2[1]) << 16);
                gstore32((u32*)(hout + (size_t)mg2 * HH + nt * 16 + cpr), pk);
            }
        }
        pbar(slots, go, gen++);

        // ============ phase B: hUa partials (waves 0-3) ====================
        {
            const int nt2 = bid & 15, mt2 = (bid >> 4) & 3, ks = bid >> 6;
            short8v hb[4];
            short8v ub0[2], ub1[2];
            const u16* brow = nullptr;
            const int rA = tg >> 3, koA = (tg & 7) * 8;
            const int rB = tg >> 2, koB = (tg & 3) * 16;
            if (t < 256) {
                const u16* arow = hout + (size_t)(mt2 * 32 + rA) * HH + ks * 256;
                #pragma unroll
                for (int i = 0; i < 4; i++)
                    hb[i] = gload8h(arow + i * 64 + koA);
                brow = Uab + (size_t)(nt2 * 64 + rB) * HH + ks * 256;
                #pragma unroll
                for (int d = 0; d < 2; d++) {
                    ub0[d] = *(const short8v*)(brow + d * 64 + koB);
                    ub1[d] = *(const short8v*)(brow + d * 64 + koB + 8);
                }
            }
            float4v acc0 = {}, acc1 = {};
            #pragma unroll
            for (int it = 0; it < 4; ++it) {
                __syncthreads();
                if (t < 256) {
                    *(short8v*)&AsX[rA * KS2 + koA] = hb[it];
                    *(short8v*)&BsX[rB * KS2 + koB] = ub0[it & 1];
                    *(short8v*)&BsX[rB * KS2 + koB + 8] = ub1[it & 1];
                }
                __syncthreads();
                if (t < 256) {
                    if (it + 2 < 4) {
                        ub0[it & 1] = *(const short8v*)(brow + (it + 2) * 64 + koB);
                        ub1[it & 1] = *(const short8v*)(brow + (it + 2) * 64 + koB + 8);
                    }
                    #pragma unroll
                    for (int kf = 0; kf < 2; ++kf) {
                        short8v bf = *(const short8v*)&BsX[(w4 * 16 + (lane & 15)) * KS2 + kf * 32 + (lane >> 4) * 8];
                        short8v a0 = *(const short8v*)&AsX[(lane & 15) * KS2 + kf * 32 + (lane >> 4) * 8];
                        short8v a1 = *(const short8v*)&AsX[(16 + (lane & 15)) * KS2 + kf * 32 + (lane >> 4) * 8];
                        acc0 = __builtin_amdgcn_mfma_f32_16x16x32_bf16(a0, bf, acc0, 0, 0, 0);
                        acc1 = __builtin_amdgcn_mfma_f32_16x16x32_bf16(a1, bf, acc1, 0, 0, 0);
                    }
                }
            }
            if (t < 256) {
                const int n = nt2 * 64 + w4 * 16 + (lane & 15);
                #pragma unroll
                for (int r = 0; r < 4; r++) {
                    const int m0 = mt2 * 32 + (lane >> 4) * 4 + r;
                    gstore32((u32*)&hup[((size_t)ks * BB + m0) * HH + n],
                             __float_as_uint(acc0[r]));
                    gstore32((u32*)&hup[((size_t)ks * BB + m0 + 16) * HH + n],
                             __float_as_uint(acc1[r]));
                }
            }
        }
        pbar(slots, go, gen++);

        // ============ phase C1: scores over UNMASKED slots (2 blocks/batch)
        int cntb_v = 0;
        {
            const int qb = bid >> 7, b = bid & 127;
            #pragma unroll
            for (int cc = 0; cc < 2; cc++) {
                const int c = t + cc * 512;
                float s = 0.f;
                #pragma unroll
                for (int ks = 0; ks < 4; ks++)
                    s += __uint_as_float(gload32((const u32*)&hup[((size_t)ks * BB + b) * HH + c]));
                huS[c] = s;
                vvS[c] = vvec[c];
            }
            cntb_v = (int)gload32((const u32*)&cnt[b]);
            for (int i = t; i < cntb_v; i += 512)
                nlS[i] = (int)gload32((const u32*)&nlist[b * NP1 + i]);
            __syncthreads();

            const int half = (cntb_v + 1) >> 1;
            const int iend = qb ? cntb_v : half;
            const int c0 = lane * 16;
            int i = (qb ? half : 0) + wv;
            if (i < iend) {
                const u8* rp = encWa8 + ((size_t)b * NP1 + nlS[i]) * HH + c0;
                u64 q0 = gload64b(rp);
                u64 q1 = gload64b(rp + 8);
                while (i < iend) {
                    const int i2 = i + 8;
                    u64 p0 = q0, p1 = q1;
                    if (i2 < iend) {
                        const u8* rp2 = encWa8 + ((size_t)b * NP1 + nlS[i2]) * HH + c0;
                        q0 = gload64b(rp2);
                        q1 = gload64b(rp2 + 8);
                    }
                    float s = 0.f;
                    #pragma unroll
                    for (int j = 0; j < 8; j++)
                        s += vvS[c0 + j] * ftanh(e82f((u32)(p0 >> (8 * j)) & 0xFFu) + huS[c0 + j]);
                    #pragma unroll
                    for (int j = 0; j < 8; j++)
                        s += vvS[c0 + 8 + j] * ftanh(e82f((u32)(p1 >> (8 * j)) & 0xFFu) + huS[c0 + 8 + j]);
                    #pragma unroll
                    for (int off = 32; off; off >>= 1) s += __shfl_down(s, off);
                    if (lane == 0)
                        gstore32((u32*)&scSg[b * NP1 + nlS[i]], __float_as_uint(s));
                    i = i2;
                }
            }
            __syncthreads();
            if (qb == 1 && t == 0) gstore32((u32*)&cflag[b << 4], (u32)(step + 1));
        }

        // ============ phase C2: finalize + list swap-remove (blocks 0..127)
        if (bid < 128) {
            const int b = bid;
            if (t == 0) {
                while ((int)gload32((const u32*)&cflag[b << 4]) <= step)
                    __builtin_amdgcn_s_sleep(1);
            }
            __syncthreads();

            float va = -INFINITY;
            if (t < NP1) {
                float sc = __uint_as_float(gload32((const u32*)&scSg[b * NP1 + t]));
                va = (mask[b * NP1 + t] != 0) ? -INFINITY : sc;
            }
            rv[t] = va; ri[t] = t;
            __syncthreads();
            for (int s = 256; s; s >>= 1) {
                if (t < s) {
                    float ov = rv[t + s]; int oi = ri[t + s];
                    if (ov > rv[t] || (ov == rv[t] && oi < ri[t])) { rv[t] = ov; ri[t] = oi; }
                }
                __syncthreads();
            }
            const float vmax = rv[0]; const int amax = ri[0];
            __syncthreads();

            float es = (t < NP1) ? expf(va - vmax) : 0.f;
            rv[t] = es;
            __syncthreads();
            for (int s = 256; s; s >>= 1) {
                if (t < s) rv[t] += rv[t + s];
                __syncthreads();
            }
            const float lse = vmax + logf(rv[0]);

            if (t < NP1)
                out_lp[((size_t)b * NP1 + step) * NP1 + t] = fmaxf(va - lse, -1e30f);

            // swap-remove amax from the unmasked list (end token stays)
            if (t == 0) posS = -1;
            __syncthreads();
            if (t < cntb_v && nlS[t] == amax) posS = t;
            __syncthreads();
            if (t == 0) {
                if (amax < NN && posS >= 0) {
                    gstore32((u32*)&nlist[b * NP1 + posS], (u32)nlS[cntb_v - 1]);
                    gstore32((u32*)&cnt[b], (u32)(cntb_v - 1));
                }
                out_idx[(size_t)b * NP1 + step] = (float)amax;
                gstore32((u32*)&cur[b], (u32)amax);
                if (amax < NN) mask[b * NP1 + amax] = 1;
            }
        }
        pbar(slots, go, gen++);
    }
}

// ---------------------------------------------------------------------------
extern "C" void kernel_launch(void* const* d_in, const int* in_sizes, int n_in,
                              void* d_out, int out_size, void* d_ws, size_t ws_size,
                              hipStream_t stream) {
    const float* enc  = (const float*)d_in[0];
    const float* Wih  = (const float*)d_in[1];
    const float* Whh  = (const float*)d_in[2];
    const float* bih  = (const float*)d_in[3];
    const float* bhh  = (const float*)d_in[4];
    const float* Wa   = (const float*)d_in[5];
    const float* Ua   = (const float*)d_in[6];
    const float* v    = (const float*)d_in[7];
    const float* stok = (const float*)d_in[8];
    const float* etok = (const float*)d_in[9];
    float* out = (float*)d_out;
    float* out_idx = out + (size_t)BB * NP1 * NP1;

    size_t off = 0;
    char* base = (char*)d_ws;
    auto alloc = [&](size_t bytes) -> char* {
        char* p = base + off;
        off += (bytes + 255) & ~(size_t)255;
        return p;
    };
    u8*    encWa8 = (u8*)   alloc((size_t)BB * NP1 * HH);          // 33.7 MB
    u16*   encB   = (u16*)  alloc((size_t)(BB * NN + 2) * HH * 2); // 67.1 MB
    u16*   Wpk    = (u16*)  alloc((size_t)4096 * 2048 * 2);        // 16.8 MB
    u16*   Uab    = (u16*)  alloc((size_t)HH * HH * 2);
    float* bpk    = (float*)alloc((size_t)4096 * 4);
    float* hup    = (float*)alloc((size_t)4 * BB * HH * 4);
    float* cx     = (float*)alloc((size_t)BB * HH * 4);
    u16*   hxbA   = (u16*)  alloc((size_t)BB * HH * 2);
    u16*   hxbB   = (u16*)  alloc((size_t)BB * HH * 2);
    float* scSg   = (float*)alloc((size_t)BB * NP1 * 4);
    int*   mask   = (int*)  alloc((size_t)BB * NP1 * 4);
    int*   nlist  = (int*)  alloc((size_t)BB * NP1 * 4);
    int*   cnt    = (int*)  alloc((size_t)BB * 4);
    int*   cur    = (int*)  alloc((size_t)BB * 4);
    int*   slots  = (int*)  alloc((size_t)256 * 16 * 4);
    int*   go     = (int*)  alloc((size_t)64);
    int*   cflag  = (int*)  alloc((size_t)BB * 16 * 4);
    if (off > ws_size) return;   // distinctive failure: 0-node graph

    k_binit<<<512, 256, 0, stream>>>(cx, hxbA, mask, cur, slots, go, cflag,
                                     nlist, cnt);
    k_pack<<<4096, 256, 0, stream>>>(Wih, Whh, bih, bhh, Wpk, bpk);
    k_cvte<<<BB * NN + 2, 256, 0, stream>>>(enc, etok, stok, encB);
    k_cvtu<<<HH, 256, 0, stream>>>(Ua, Uab);
    k_encWa8<<<dim3(257, 8), 256, 0, stream>>>(enc, etok, Wa, encWa8);

    void* args[] = { (void*)&encB, (void*)&Wpk, (void*)&bpk, (void*)&Uab,
                     (void*)&encWa8, (void*)&v, (void*)&cur, (void*)&mask,
                     (void*)&hxbA, (void*)&hxbB, (void*)&cx, (void*)&hup,
                     (void*)&scSg, (void*)&cflag, (void*)&nlist, (void*)&cnt,
                     (void*)&out, (void*)&out_idx, (void*)&slots, (void*)&go };
    hipLaunchCooperativeKernel((const void*)k_persist, dim3(256), dim3(512),
                               args, 0, stream);
}

// Round 13
// 8725.848 us; speedup vs baseline: 2.3372x; 1.0871x over previous
//
#include <hip/hip_runtime.h>
#include <math.h>

#define BB 128
#define NN 256
#define NP1 257
#define HH 1024

typedef unsigned char u8;
typedef unsigned short u16;
typedef unsigned int u32;
typedef unsigned long long u64;
typedef __attribute__((ext_vector_type(8))) short short8v;
typedef __attribute__((ext_vector_type(4))) short short4v;
typedef __attribute__((ext_vector_type(4))) float float4v;

__device__ __forceinline__ u16 f2b(float x) {            // f32 -> bf16 (RNE)
    union { float f; u32 u; } c; c.f = x;
    u32 r = (c.u + 0x7fffu + ((c.u >> 16) & 1u)) >> 16;
    return (u16)r;
}
__device__ __forceinline__ float b2f(u16 s) {
    union { u32 u; float f; } c; c.u = ((u32)s) << 16;
    return c.f;
}
__device__ __forceinline__ float ftanh(float x) {
    float e = __builtin_amdgcn_exp2f(x * 2.8853900817779268f);
    return 1.f - 2.f * __builtin_amdgcn_rcpf(e + 1.f);
}
__device__ __forceinline__ float fsig(float x) {
    return __builtin_amdgcn_rcpf(1.f + __builtin_amdgcn_exp2f(x * -1.4426950408889634f));
}

// ---- fp8 e4m3fn helpers -----------------------------------------------------
__device__ __forceinline__ u8 f2e8(float x) {            // f32 -> e4m3 (RNE)
    u32 u = __float_as_uint(x);
    u32 sgn = (u >> 24) & 0x80u;
    float ax = __uint_as_float(u & 0x7fffffffu);
    if (!(ax < 448.f)) return (u8)(sgn | 0x7Eu);         // clamp, NaN -> max
    if (ax < 0.015625f) {                                // subnormal, q = 2^-9
        int q = (int)rintf(ax * 512.f);
        if (q >= 8) return (u8)(sgn | 0x08u);
        return (u8)(sgn | (u32)q);
    }
    u32 au = u & 0x7fffffffu;
    au += 0x7ffffu + ((au >> 20) & 1u);                  // RNE at bit 20
    int e = (int)(au >> 23) - 127;
    u32 m3 = (au >> 20) & 7u;
    if (e > 8 || (e == 8 && m3 == 7)) return (u8)(sgn | 0x7Eu);
    return (u8)(sgn | ((u32)(e + 7) << 3) | m3);
}
__device__ __forceinline__ float e82f(u32 u) {           // e4m3 -> f32 (exact)
    u32 t = ((u & 0x80u) << 24) | ((u & 0x7Fu) << 20);
    return __uint_as_float(t) * 0x1p+120f;
}

// LLC-coherent (sc1) access helpers: relaxed agent atomics bypass per-XCD L2,
// served by + allocate in the 256MB LLC. (Round-12 lesson: FETCH_SIZE counts
// beyond-L2 traffic incl. LLC hits; encWa8 IS LLC-resident.)
__device__ __forceinline__ u64 gload64(const u16* p) {
    return __hip_atomic_load((u64*)p, __ATOMIC_RELAXED, __HIP_MEMORY_SCOPE_AGENT);
}
__device__ __forceinline__ u64 gload64b(const u8* p) {
    return __hip_atomic_load((const u64*)p, __ATOMIC_RELAXED, __HIP_MEMORY_SCOPE_AGENT);
}
__device__ __forceinline__ short8v gload8h(const u16* p) {
    union { u64 q[2]; short8v v; } uq;
    uq.q[0] = gload64(p);
    uq.q[1] = gload64(p + 4);
    return uq.v;
}
__device__ __forceinline__ void gstore32(u32* p, u32 v) {
    __hip_atomic_store(p, v, __ATOMIC_RELAXED, __HIP_MEMORY_SCOPE_AGENT);
}
__device__ __forceinline__ u32 gload32(const u32* p) {
    return __hip_atomic_load((u32*)p, __ATOMIC_RELAXED, __HIP_MEMORY_SCOPE_AGENT);
}

#define CPHI(m) ((m) + (((m) >> 5) << 2))
// Swizzled LDS tile: [rows][64 u16] (128B row stride = full bank revolution);
// 16B-column c stored at c ^ (row&7). Latin-square -> writes AND fragment
// reads are exactly 8 accesses per 4-bank group = conflict-free optimal.
// (Round-12 fix: old 144B stride gave 8-way diagonal conflicts on staging.)
#define SWZ(r, c) (((r) << 6) + ((((c) ^ ((r) & 7))) << 3))

// ---------------------------------------------------------------------------
// Fence-free grid barrier (round-9, proven): per-block slots + go word, sc1.
__device__ __forceinline__ void pbar(int* slots, int* go, int gen) {
    asm volatile("" ::: "memory");
    __syncthreads();
    const int t = threadIdx.x;
    if (blockIdx.x == 0) {
        if (t >= 1 && t < 256) {
            while ((int)gload32((u32*)&slots[t << 4]) < gen)
                __builtin_amdgcn_s_sleep(1);
        }
        __syncthreads();
        if (t == 0) gstore32((u32*)go, (u32)gen);
    } else {
        if (t == 0) {
            gstore32((u32*)&slots[blockIdx.x << 4], (u32)gen);
            while ((int)gload32((u32*)go) < gen)
                __builtin_amdgcn_s_sleep(1);
        }
        __syncthreads();
    }
    asm volatile("" ::: "memory");
}

// ---------------------------------------------------------------------------
__global__ __launch_bounds__(256) void k_binit(float* cx, u16* hxbA, int* mask,
                                               int* cur, int* slots, int* go,
                                               int* cflag, int* nlist, int* cnt) {
    int i = blockIdx.x * 256 + threadIdx.x;
    if (i < BB * HH) cx[i] = 0.f;
    if (i < BB * HH / 2) ((u32*)hxbA)[i] = 0u;
    if (i < BB * NP1) { mask[i] = 0; nlist[i] = i % NP1; }
    if (i < BB) { cur[i] = -1; cnt[i] = NP1; }
    if (i < 256 * 16) slots[i] = 0;
    if (i < BB * 16) cflag[i] = 0;
    if (i == 0) *go = 0;
}

// ---------------------------------------------------------------------------
__global__ __launch_bounds__(256) void k_pack(const float* __restrict__ Wih,
                                              const float* __restrict__ Whh,
                                              const float* __restrict__ bih,
                                              const float* __restrict__ bhh,
                                              u16* __restrict__ Wpk,
                                              float* __restrict__ bpk) {
    const int jp = blockIdx.x;
    const int nt = jp >> 6, r = jp & 63, g = r >> 4, c = r & 15;
    const int j = g * HH + nt * 16 + c;
    const int t = threadIdx.x;
    const int k = t * 8;
    const float* s = (k < HH) ? (Wih + (size_t)j * HH + k)
                              : (Whh + (size_t)j * HH + (k - HH));
    float4 v0 = *(const float4*)(s);
    float4 v1 = *(const float4*)(s + 4);
    short8v o;
    o[0]=(short)f2b(v0.x); o[1]=(short)f2b(v0.y); o[2]=(short)f2b(v0.z); o[3]=(short)f2b(v0.w);
    o[4]=(short)f2b(v1.x); o[5]=(short)f2b(v1.y); o[6]=(short)f2b(v1.z); o[7]=(short)f2b(v1.w);
    *(short8v*)(Wpk + (size_t)jp * 2048 + k) = o;
    if (t == 0) bpk[jp] = bih[j] + bhh[j];
}

__global__ __launch_bounds__(256) void k_cvte(const float* __restrict__ enc,
                                              const float* __restrict__ etok,
                                              const float* __restrict__ stok,
                                              u16* __restrict__ encB) {
    const int row = blockIdx.x;
    const float* src = (row < BB * NN) ? enc + (size_t)row * HH
                      : (row == BB * NN ? etok : stok);
    const int t = threadIdx.x;
    float4 v = *(const float4*)(src + t * 4);
    short4v o;
    o[0]=(short)f2b(v.x); o[1]=(short)f2b(v.y); o[2]=(short)f2b(v.z); o[3]=(short)f2b(v.w);
    *(short4v*)(encB + (size_t)row * HH + t * 4) = o;
}

__global__ __launch_bounds__(256) void k_cvtu(const float* __restrict__ Ua,
                                              u16* __restrict__ Uab) {
    const int row = blockIdx.x;
    const int t = threadIdx.x;
    float4 v = *(const float4*)(Ua + (size_t)row * HH + t * 4);
    short4v o;
    o[0]=(short)f2b(v.x); o[1]=(short)f2b(v.y); o[2]=(short)f2b(v.z); o[3]=(short)f2b(v.w);
    *(short4v*)(Uab + (size_t)row * HH + t * 4) = o;
}

// ---------------------------------------------------------------------------
// encWa8[r, n] (fp8 e4m3) = sum_k ext[r,k] * Wa[n,k];  f32 math, fp8 store.
__global__ __launch_bounds__(256, 2) void k_encWa8(const float* __restrict__ enc,
                                                   const float* __restrict__ etok,
                                                   const float* __restrict__ Wa,
                                                   u8* __restrict__ out) {
    __shared__ float As[32][140];
    __shared__ float Ws[32][140];
    const int mt = blockIdx.x, ntl = blockIdx.y;
    const int tid = threadIdx.x;
    const int lr = tid >> 2, lc = tid & 3;
    const int tr = tid & 15, tc = tid >> 4;

    const int r0 = mt * 128 + lr, r1 = r0 + 64;
    const int bb0 = r0 / NP1, nn0 = r0 - bb0 * NP1;
    const int bb1 = r1 / NP1, nn1 = r1 - bb1 * NP1;
    const float* a0 = (nn0 == NN) ? etok : enc + ((size_t)(bb0 * NN + nn0)) * HH;
    const float* a1 = (nn1 == NN) ? etok : enc + ((size_t)(bb1 * NN + nn1)) * HH;
    const float* w0 = Wa + (size_t)(ntl * 128 + lr) * HH;
    const float* w1 = w0 + (size_t)64 * HH;
    const int ca = CPHI(lr), cb = CPHI(lr + 64);
    const int colA = tr * 8 + ((tr >> 2) << 2);
    const int colB = tc * 8 + ((tc >> 2) << 2);

    float acc[8][8] = {};
    for (int k0 = 0; k0 < HH; k0 += 32) {
        float4 va0 = *(const float4*)(a0 + k0 + lc * 4);
        float4 va1 = *(const float4*)(a0 + k0 + lc * 4 + 16);
        float4 va2 = *(const float4*)(a1 + k0 + lc * 4);
        float4 va3 = *(const float4*)(a1 + k0 + lc * 4 + 16);
        float4 vb0 = *(const float4*)(w0 + k0 + lc * 4);
        float4 vb1 = *(const float4*)(w0 + k0 + lc * 4 + 16);
        float4 vb2 = *(const float4*)(w1 + k0 + lc * 4);
        float4 vb3 = *(const float4*)(w1 + k0 + lc * 4 + 16);
        __syncthreads();
        #pragma unroll
        for (int e = 0; e < 4; e++) {
            As[lc*4+e][ca]      = ((const float*)&va0)[e];
            As[lc*4+16+e][ca]   = ((const float*)&va1)[e];
            As[lc*4+e][cb]      = ((const float*)&va2)[e];
            As[lc*4+16+e][cb]   = ((const float*)&va3)[e];
            Ws[lc*4+e][ca]      = ((const float*)&vb0)[e];
            Ws[lc*4+16+e][ca]   = ((const float*)&vb1)[e];
            Ws[lc*4+e][cb]      = ((const float*)&vb2)[e];
            Ws[lc*4+16+e][cb]   = ((const float*)&vb3)[e];
        }
        __syncthreads();
        #pragma unroll
        for (int kk = 0; kk < 32; kk++) {
            float4 A0 = *(const float4*)&As[kk][colA];
            float4 A1 = *(const float4*)&As[kk][colA + 4];
            float4 B0 = *(const float4*)&Ws[kk][colB];
            float4 B1 = *(const float4*)&Ws[kk][colB + 4];
            float av[8] = {A0.x,A0.y,A0.z,A0.w,A1.x,A1.y,A1.z,A1.w};
            float bv[8] = {B0.x,B0.y,B0.z,B0.w,B1.x,B1.y,B1.z,B1.w};
            #pragma unroll
            for (int i = 0; i < 8; i++)
                #pragma unroll
                for (int j = 0; j < 8; j++) acc[i][j] += av[i] * bv[j];
        }
        __syncthreads();
    }
    #pragma unroll
    for (int i = 0; i < 8; i++) {
        u64 pk = 0;
        #pragma unroll
        for (int j = 0; j < 8; j++)
            pk |= (u64)f2e8(acc[i][j]) << (8 * j);
        *(u64*)(out + (size_t)(mt * 128 + tr * 8 + i) * HH + ntl * 128 + tc * 8) = pk;
    }
}

// ---------------------------------------------------------------------------
// Persistent decode: 256 blocks x 512 threads.
// A: 8-wave split-K gates GEMM + cell (BOTH groups preload all A-chunks)
// B: hUa partials (waves 0-3)
// C1: scores over UNMASKED slots only (compact list, fp8 encWa, sc1 loads)
// C2: finalize + swap-remove selected index from list
__global__ __launch_bounds__(512, 1) void k_persist(
    const u16* __restrict__ encB, const u16* __restrict__ Wpk,
    const float* __restrict__ bpk, const u16* __restrict__ Uab,
    const u8* __restrict__ encWa8, const float* __restrict__ vvec,
    int* __restrict__ cur, int* __restrict__ mask,
    u16* __restrict__ hxbA, u16* __restrict__ hxbB,
    float* __restrict__ cx, float* __restrict__ hup,
    float* __restrict__ scSg, int* __restrict__ cflag,
    int* __restrict__ nlist, int* __restrict__ cnt,
    float* __restrict__ out_lp, float* __restrict__ out_idx,
    int* __restrict__ slots, int* __restrict__ go)
{
    __shared__ u16 AsX[32 * 64];
    __shared__ u16 BsX[64 * 64];
    __shared__ u16 AsH[32 * 64];
    __shared__ u16 BsH[64 * 64];
    __shared__ float Gs[8][32][17];
    __shared__ float huS[HH];
    __shared__ float vvS[HH];
    __shared__ float rv[512];
    __shared__ int   ri[512];
    __shared__ int   nlS[NP1];
    __shared__ int   posS;

    const int bid = blockIdx.x;
    const int t = threadIdx.x;
    const int wv = t >> 6, lane = t & 63;
    const int tg = t & 255, w4 = (t >> 6) & 3;
    int gen = 1;

    for (int step = 0; step < NP1; step++) {
        const u16* hin = (step & 1) ? hxbB : hxbA;
        u16* hout = (step & 1) ? hxbA : hxbB;

        // ============ phase A: gates GEMM + LSTM cell (8-wave split-K) =====
        {
            const int nt = bid & 63, mt = bid >> 6;
            const int rA = tg >> 3, koA = (tg & 7) * 8;      // A: 32r x 8 cols
            const int cA16 = tg & 7;
            const int rB = tg >> 2, koB = (tg & 3) * 16;     // B: 64r x 2x16B
            const int cB16 = (tg & 3) * 2;
            const int mg = mt * 32 + rA;

            short8v apre[16];
            short8v b0_pf[3], b1_pf[3];
            const u16* brow = nullptr;
            if (t < 256) {          // x-group: preload ALL 16 x-chunks upfront
                const int sel = (int)gload32((const u32*)&cur[mg]);
                const u16* xrow = encB + (size_t)((sel < 0) ? (BB * NN + 1)
                             : (sel == NN ? BB * NN : (mg * NN + sel))) * HH;
                #pragma unroll
                for (int i = 0; i < 16; i++)
                    apre[i] = *(const short8v*)(xrow + i * 64 + koA);
                brow = Wpk + (size_t)(nt * 64 + rB) * 2048;
            } else {                // h-group: preload ALL 16 h-chunks (sc1)
                const u16* hrow = hin + (size_t)mg * HH;
                #pragma unroll
                for (int i = 0; i < 16; i++)
                    apre[i] = gload8h(hrow + i * 64 + koA);
                brow = Wpk + (size_t)(nt * 64 + rB) * 2048 + HH;
            }
            #pragma unroll
            for (int d = 0; d < 3; d++) {
                b0_pf[d] = *(const short8v*)(brow + d * 64 + koB);
                b1_pf[d] = *(const short8v*)(brow + d * 64 + koB + 8);
            }
            float4v acc0 = {}, acc1 = {};
            #pragma unroll
            for (int it = 0; it < 16; ++it) {
                __syncthreads();
                if (t < 256) {
                    *(short8v*)&AsX[SWZ(rA, cA16)] = apre[it];
                    *(short8v*)&BsX[SWZ(rB, cB16)] = b0_pf[it % 3];
                    *(short8v*)&BsX[SWZ(rB, cB16 + 1)] = b1_pf[it % 3];
                } else {
                    *(short8v*)&AsH[SWZ(rA, cA16)] = apre[it];
                    *(short8v*)&BsH[SWZ(rB, cB16)] = b0_pf[it % 3];
                    *(short8v*)&BsH[SWZ(rB, cB16 + 1)] = b1_pf[it % 3];
                }
                __syncthreads();
                if (it + 3 < 16) {
                    b0_pf[it % 3] = *(const short8v*)(brow + (it + 3) * 64 + koB);
                    b1_pf[it % 3] = *(const short8v*)(brow + (it + 3) * 64 + koB + 8);
                }
                if (t < 256) {
                    #pragma unroll
                    for (int kf = 0; kf < 2; ++kf) {
                        const int c16 = kf * 4 + (lane >> 4);
                        short8v bf = *(const short8v*)&BsX[SWZ(w4 * 16 + (lane & 15), c16)];
                        short8v a0 = *(const short8v*)&AsX[SWZ(lane & 15, c16)];
                        short8v a1 = *(const short8v*)&AsX[SWZ(16 + (lane & 15), c16)];
                        acc0 = __builtin_amdgcn_mfma_f32_16x16x32_bf16(a0, bf, acc0, 0, 0, 0);
                        acc1 = __builtin_amdgcn_mfma_f32_16x16x32_bf16(a1, bf, acc1, 0, 0, 0);
                    }
                } else {
                    #pragma unroll
                    for (int kf = 0; kf < 2; ++kf) {
                        const int c16 = kf * 4 + (lane >> 4);
                        short8v bf = *(const short8v*)&BsH[SWZ(w4 * 16 + (lane & 15), c16)];
                        short8v a0 = *(const short8v*)&AsH[SWZ(lane & 15, c16)];
                        short8v a1 = *(const short8v*)&AsH[SWZ(16 + (lane & 15), c16)];
                        acc0 = __builtin_amdgcn_mfma_f32_16x16x32_bf16(a0, bf, acc0, 0, 0, 0);
                        acc1 = __builtin_amdgcn_mfma_f32_16x16x32_bf16(a1, bf, acc1, 0, 0, 0);
                    }
                }
            }
            __syncthreads();
            #pragma unroll
            for (int r = 0; r < 4; r++) {
                Gs[wv][(lane >> 4) * 4 + r][lane & 15]      = acc0[r];
                Gs[wv][16 + (lane >> 4) * 4 + r][lane & 15] = acc1[r];
            }
            __syncthreads();
            if (t < 256) {
                const int m = t >> 3, cpr = (t & 7) * 2;
                const int mg2 = mt * 32 + m;
                float hn2[2];
                #pragma unroll
                for (int e = 0; e < 2; e++) {
                    const int c = cpr + e;
                    float gi  = Gs[0][m][c] + Gs[4][m][c] + bpk[nt * 64 + c];
                    float gf  = Gs[1][m][c] + Gs[5][m][c] + bpk[nt * 64 + 16 + c];
                    float gg  = Gs[2][m][c] + Gs[6][m][c] + bpk[nt * 64 + 32 + c];
                    float go2 = Gs[3][m][c] + Gs[7][m][c] + bpk[nt * 64 + 48 + c];
                    const int cg = nt * 16 + c;
                    float cold = cx[(size_t)mg2 * HH + cg];
                    float cn = fsig(gf) * cold + fsig(gi) * ftanh(gg);
                    hn2[e] = fsig(go2) * ftanh(cn);
                    cx[(size_t)mg2 * HH + cg] = cn;
                }
                u32 pk = (u32)f2b(hn2[0]) | ((u32)f2b(hn2[1]) << 16);
                gstore32((u32*)(hout + (size_t)mg2 * HH + nt * 16 + cpr), pk);
            }
        }
        pbar(slots, go, gen++);

        // ============ phase B: hUa partials (waves 0-3) ====================
        {
            const int nt2 = bid & 15, mt2 = (bid >> 4) & 3, ks = bid >> 6;
            const int rA = tg >> 3, koA = (tg & 7) * 8;
            const int cA16 = tg & 7;
            const int rB = tg >> 2, koB = (tg & 3) * 16;
            const int cB16 = (tg & 3) * 2;
            short8v hb[4];
            short8v ub0[2], ub1[2];
            const u16* brow = nullptr;
            if (t < 256) {
                const u16* arow = hout + (size_t)(mt2 * 32 + rA) * HH + ks * 256;
                #pragma unroll
                for (int i = 0; i < 4; i++)
                    hb[i] = gload8h(arow + i * 64 + koA);
                brow = Uab + (size_t)(nt2 * 64 + rB) * HH + ks * 256;
                #pragma unroll
                for (int d = 0; d < 2; d++) {
                    ub0[d] = *(const short8v*)(brow + d * 64 + koB);
                    ub1[d] = *(const short8v*)(brow + d * 64 + koB + 8);
                }
            }
            float4v acc0 = {}, acc1 = {};
            #pragma unroll
            for (int it = 0; it < 4; ++it) {
                __syncthreads();
                if (t < 256) {
                    *(short8v*)&AsX[SWZ(rA, cA16)] = hb[it];
                    *(short8v*)&BsX[SWZ(rB, cB16)] = ub0[it & 1];
                    *(short8v*)&BsX[SWZ(rB, cB16 + 1)] = ub1[it & 1];
                }
                __syncthreads();
                if (t < 256) {
                    if (it + 2 < 4) {
                        ub0[it & 1] = *(const short8v*)(brow + (it + 2) * 64 + koB);
                        ub1[it & 1] = *(const short8v*)(brow + (it + 2) * 64 + koB + 8);
                    }
                    #pragma unroll
                    for (int kf = 0; kf < 2; ++kf) {
                        const int c16 = kf * 4 + (lane >> 4);
                        short8v bf = *(const short8v*)&BsX[SWZ(w4 * 16 + (lane & 15), c16)];
                        short8v a0 = *(const short8v*)&AsX[SWZ(lane & 15, c16)];
                        short8v a1 = *(const short8v*)&AsX[SWZ(16 + (lane & 15), c16)];
                        acc0 = __builtin_amdgcn_mfma_f32_16x16x32_bf16(a0, bf, acc0, 0, 0, 0);
                        acc1 = __builtin_amdgcn_mfma_f32_16x16x32_bf16(a1, bf, acc1, 0, 0, 0);
                    }
                }
            }
            if (t < 256) {
                const int n = nt2 * 64 + w4 * 16 + (lane & 15);
                #pragma unroll
                for (int r = 0; r < 4; r++) {
                    const int m0 = mt2 * 32 + (lane >> 4) * 4 + r;
                    gstore32((u32*)&hup[((size_t)ks * BB + m0) * HH + n],
                             __float_as_uint(acc0[r]));
                    gstore32((u32*)&hup[((size_t)ks * BB + m0 + 16) * HH + n],
                             __float_as_uint(acc1[r]));
                }
            }
        }
        pbar(slots, go, gen++);

        // ============ phase C1: scores over UNMASKED slots (2 blocks/batch)
        int cntb_v = 0;
        {
            const int qb = bid >> 7, b = bid & 127;
            #pragma unroll
            for (int cc = 0; cc < 2; cc++) {
                const int c = t + cc * 512;
                float s = 0.f;
                #pragma unroll
                for (int ks = 0; ks < 4; ks++)
                    s += __uint_as_float(gload32((const u32*)&hup[((size_t)ks * BB + b) * HH + c]));
                huS[c] = s;
                vvS[c] = vvec[c];
            }
            cntb_v = (int)gload32((const u32*)&cnt[b]);
            for (int i = t; i < cntb_v; i += 512)
                nlS[i] = (int)gload32((const u32*)&nlist[b * NP1 + i]);
            __syncthreads();

            const int half = (cntb_v + 1) >> 1;
            const int iend = qb ? cntb_v : half;
            const int c0 = lane * 16;
            int i = (qb ? half : 0) + wv;
            if (i < iend) {
                const u8* rp = encWa8 + ((size_t)b * NP1 + nlS[i]) * HH + c0;
                u64 q0 = gload64b(rp);
                u64 q1 = gload64b(rp + 8);
                while (i < iend) {
                    const int i2 = i + 8;
                    u64 p0 = q0, p1 = q1;
                    if (i2 < iend) {
                        const u8* rp2 = encWa8 + ((size_t)b * NP1 + nlS[i2]) * HH + c0;
                        q0 = gload64b(rp2);
                        q1 = gload64b(rp2 + 8);
                    }
                    float s = 0.f;
                    #pragma unroll
                    for (int j = 0; j < 8; j++)
                        s += vvS[c0 + j] * ftanh(e82f((u32)(p0 >> (8 * j)) & 0xFFu) + huS[c0 + j]);
                    #pragma unroll
                    for (int j = 0; j < 8; j++)
                        s += vvS[c0 + 8 + j] * ftanh(e82f((u32)(p1 >> (8 * j)) & 0xFFu) + huS[c0 + 8 + j]);
                    #pragma unroll
                    for (int off = 32; off; off >>= 1) s += __shfl_down(s, off);
                    if (lane == 0)
                        gstore32((u32*)&scSg[b * NP1 + nlS[i]], __float_as_uint(s));
                    i = i2;
                }
            }
            __syncthreads();
            if (qb == 1 && t == 0) gstore32((u32*)&cflag[b << 4], (u32)(step + 1));
        }

        // ============ phase C2: finalize + list swap-remove (blocks 0..127)
        if (bid < 128) {
            const int b = bid;
            if (t == 0) {
                while ((int)gload32((const u32*)&cflag[b << 4]) <= step)
                    __builtin_amdgcn_s_sleep(1);
            }
            __syncthreads();

            float va = -INFINITY;
            if (t < NP1) {
                float sc = __uint_as_float(gload32((const u32*)&scSg[b * NP1 + t]));
                va = (mask[b * NP1 + t] != 0) ? -INFINITY : sc;
            }
            rv[t] = va; ri[t] = t;
            __syncthreads();
            for (int s = 256; s; s >>= 1) {
                if (t < s) {
                    float ov = rv[t + s]; int oi = ri[t + s];
                    if (ov > rv[t] || (ov == rv[t] && oi < ri[t])) { rv[t] = ov; ri[t] = oi; }
                }
                __syncthreads();
            }
            const float vmax = rv[0]; const int amax = ri[0];
            __syncthreads();

            float es = (t < NP1) ? expf(va - vmax) : 0.f;
            rv[t] = es;
            __syncthreads();
            for (int s = 256; s; s >>= 1) {
                if (t < s) rv[t] += rv[t + s];
                __syncthreads();
            }
            const float lse = vmax + logf(rv[0]);

            if (t < NP1)
                out_lp[((size_t)b * NP1 + step) * NP1 + t] = fmaxf(va - lse, -1e30f);

            // swap-remove amax from the unmasked list (end token stays)
            if (t == 0) posS = -1;
            __syncthreads();
            if (t < cntb_v && nlS[t] == amax) posS = t;
            __syncthreads();
            if (t == 0) {
                if (amax < NN && posS >= 0) {
                    gstore32((u32*)&nlist[b * NP1 + posS], (u32)nlS[cntb_v - 1]);
                    gstore32((u32*)&cnt[b], (u32)(cntb_v - 1));
                }
                out_idx[(size_t)b * NP1 + step] = (float)amax;
                gstore32((u32*)&cur[b], (u32)amax);
                if (amax < NN) mask[b * NP1 + amax] = 1;
            }
        }
        pbar(slots, go, gen++);
    }
}

// ---------------------------------------------------------------------------
extern "C" void kernel_launch(void* const* d_in, const int* in_sizes, int n_in,
                              void* d_out, int out_size, void* d_ws, size_t ws_size,
                              hipStream_t stream) {
    const float* enc  = (const float*)d_in[0];
    const float* Wih  = (const float*)d_in[1];
    const float* Whh  = (const float*)d_in[2];
    const float* bih  = (const float*)d_in[3];
    const float* bhh  = (const float*)d_in[4];
    const float* Wa   = (const float*)d_in[5];
    const float* Ua   = (const float*)d_in[6];
    const float* v    = (const float*)d_in[7];
    const float* stok = (const float*)d_in[8];
    const float* etok = (const float*)d_in[9];
    float* out = (float*)d_out;
    float* out_idx = out + (size_t)BB * NP1 * NP1;

    size_t off = 0;
    char* base = (char*)d_ws;
    auto alloc = [&](size_t bytes) -> char* {
        char* p = base + off;
        off += (bytes + 255) & ~(size_t)255;
        return p;
    };
    u8*    encWa8 = (u8*)   alloc((size_t)BB * NP1 * HH);          // 33.7 MB
    u16*   encB   = (u16*)  alloc((size_t)(BB * NN + 2) * HH * 2); // 67.1 MB
    u16*   Wpk    = (u16*)  alloc((size_t)4096 * 2048 * 2);        // 16.8 MB
    u16*   Uab    = (u16*)  alloc((size_t)HH * HH * 2);
    float* bpk    = (float*)alloc((size_t)4096 * 4);
    float* hup    = (float*)alloc((size_t)4 * BB * HH * 4);
    float* cx     = (float*)alloc((size_t)BB * HH * 4);
    u16*   hxbA   = (u16*)  alloc((size_t)BB * HH * 2);
    u16*   hxbB   = (u16*)  alloc((size_t)BB * HH * 2);
    float* scSg   = (float*)alloc((size_t)BB * NP1 * 4);
    int*   mask   = (int*)  alloc((size_t)BB * NP1 * 4);
    int*   nlist  = (int*)  alloc((size_t)BB * NP1 * 4);
    int*   cnt    = (int*)  alloc((size_t)BB * 4);
    int*   cur    = (int*)  alloc((size_t)BB * 4);
    int*   slots  = (int*)  alloc((size_t)256 * 16 * 4);
    int*   go     = (int*)  alloc((size_t)64);
    int*   cflag  = (int*)  alloc((size_t)BB * 16 * 4);
    if (off > ws_size) return;   // distinctive failure: 0-node graph

    k_binit<<<512, 256, 0, stream>>>(cx, hxbA, mask, cur, slots, go, cflag,
                                     nlist, cnt);
    k_pack<<<4096, 256, 0, stream>>>(Wih, Whh, bih, bhh, Wpk, bpk);
    k_cvte<<<BB * NN + 2, 256, 0, stream>>>(enc, etok, stok, encB);
    k_cvtu<<<HH, 256, 0, stream>>>(Ua, Uab);
    k_encWa8<<<dim3(257, 8), 256, 0, stream>>>(enc, etok, Wa, encWa8);

    void* args[] = { (void*)&encB, (void*)&Wpk, (void*)&bpk, (void*)&Uab,
                     (void*)&encWa8, (void*)&v, (void*)&cur, (void*)&mask,
                     (void*)&hxbA, (void*)&hxbB, (void*)&cx, (void*)&hup,
                     (void*)&scSg, (void*)&cflag, (void*)&nlist, (void*)&cnt,
                     (void*)&out, (void*)&out_idx, (void*)&slots, (void*)&go };
    hipLaunchCooperativeKernel((const void*)k_persist, dim3(256), dim3(512),
                               args, 0, stream);
}

// Round 14
// 8642.825 us; speedup vs baseline: 2.3597x; 1.0096x over previous
//
#include <hip/hip_runtime.h>
#include <math.h>

#define BB 128
#define NN 256
#define NP1 257
#define HH 1024

typedef unsigned char u8;
typedef unsigned short u16;
typedef unsigned int u32;
typedef unsigned long long u64;
typedef __attribute__((ext_vector_type(8))) short short8v;
typedef __attribute__((ext_vector_type(4))) short short4v;
typedef __attribute__((ext_vector_type(4))) float float4v;

__device__ __forceinline__ u16 f2b(float x) {            // f32 -> bf16 (RNE)
    union { float f; u32 u; } c; c.f = x;
    u32 r = (c.u + 0x7fffu + ((c.u >> 16) & 1u)) >> 16;
    return (u16)r;
}
__device__ __forceinline__ float b2f(u16 s) {
    union { u32 u; float f; } c; c.u = ((u32)s) << 16;
    return c.f;
}
__device__ __forceinline__ float ftanh(float x) {
    float e = __builtin_amdgcn_exp2f(x * 2.8853900817779268f);
    return 1.f - 2.f * __builtin_amdgcn_rcpf(e + 1.f);
}
__device__ __forceinline__ float fsig(float x) {
    return __builtin_amdgcn_rcpf(1.f + __builtin_amdgcn_exp2f(x * -1.4426950408889634f));
}

// ---- fp8 e4m3fn helpers -----------------------------------------------------
__device__ __forceinline__ u8 f2e8(float x) {            // f32 -> e4m3 (RNE)
    u32 u = __float_as_uint(x);
    u32 sgn = (u >> 24) & 0x80u;
    float ax = __uint_as_float(u & 0x7fffffffu);
    if (!(ax < 448.f)) return (u8)(sgn | 0x7Eu);         // clamp, NaN -> max
    if (ax < 0.015625f) {                                // subnormal, q = 2^-9
        int q = (int)rintf(ax * 512.f);
        if (q >= 8) return (u8)(sgn | 0x08u);
        return (u8)(sgn | (u32)q);
    }
    u32 au = u & 0x7fffffffu;
    au += 0x7ffffu + ((au >> 20) & 1u);                  // RNE at bit 20
    int e = (int)(au >> 23) - 127;
    u32 m3 = (au >> 20) & 7u;
    if (e > 8 || (e == 8 && m3 == 7)) return (u8)(sgn | 0x7Eu);
    return (u8)(sgn | ((u32)(e + 7) << 3) | m3);
}
__device__ __forceinline__ float e82f(u32 u) {           // e4m3 -> f32 (exact)
    u32 t = ((u & 0x80u) << 24) | ((u & 0x7Fu) << 20);
    return __uint_as_float(t) * 0x1p+120f;
}

// LLC-coherent (sc1) access helpers: relaxed agent atomics bypass per-XCD L2,
// served by + allocate in the 256MB LLC.
__device__ __forceinline__ u64 gload64(const u16* p) {
    return __hip_atomic_load((u64*)p, __ATOMIC_RELAXED, __HIP_MEMORY_SCOPE_AGENT);
}
__device__ __forceinline__ u64 gload64b(const u8* p) {
    return __hip_atomic_load((const u64*)p, __ATOMIC_RELAXED, __HIP_MEMORY_SCOPE_AGENT);
}
__device__ __forceinline__ short8v gload8h(const u16* p) {
    union { u64 q[2]; short8v v; } uq;
    uq.q[0] = gload64(p);
    uq.q[1] = gload64(p + 4);
    return uq.v;
}
__device__ __forceinline__ void gstore32(u32* p, u32 v) {
    __hip_atomic_store(p, v, __ATOMIC_RELAXED, __HIP_MEMORY_SCOPE_AGENT);
}
__device__ __forceinline__ u32 gload32(const u32* p) {
    return __hip_atomic_load((u32*)p, __ATOMIC_RELAXED, __HIP_MEMORY_SCOPE_AGENT);
}

#define CPHI(m) ((m) + (((m) >> 5) << 2))
// Swizzled bf16 MFMA tile (round-13, proven): row stride 64 u16, col^row&7.
#define SWZ(r, c) (((r) << 6) + ((((c) ^ ((r) & 7))) << 3))
// Pad-1-per-32 for f32 arrays read at stride 16 (round-14 fix): lane l reads
// HPHI(l*16+j) -> bank (l/2 + j) mod 32 (even) / (16+(l-1)/2 + j) (odd):
// full 32-bank coverage, 2 lanes/bank = free. Unpadded was 32-way conflict.
#define HPHI(c) ((c) + ((c) >> 5))

// ---------------------------------------------------------------------------
// Fence-free grid barrier (round-9, proven): per-block slots + go word, sc1.
__device__ __forceinline__ void pbar(int* slots, int* go, int gen) {
    asm volatile("" ::: "memory");
    __syncthreads();
    const int t = threadIdx.x;
    if (blockIdx.x == 0) {
        if (t >= 1 && t < 256) {
            while ((int)gload32((u32*)&slots[t << 4]) < gen)
                __builtin_amdgcn_s_sleep(1);
        }
        __syncthreads();
        if (t == 0) gstore32((u32*)go, (u32)gen);
    } else {
        if (t == 0) {
            gstore32((u32*)&slots[blockIdx.x << 4], (u32)gen);
            while ((int)gload32((u32*)go) < gen)
                __builtin_amdgcn_s_sleep(1);
        }
        __syncthreads();
    }
    asm volatile("" ::: "memory");
}

// ---------------------------------------------------------------------------
__global__ __launch_bounds__(256) void k_binit(float* cx, u16* hxbA, int* mask,
                                               int* cur, int* slots, int* go,
                                               int* cflag, int* nlist, int* cnt) {
    int i = blockIdx.x * 256 + threadIdx.x;
    if (i < BB * HH) cx[i] = 0.f;
    if (i < BB * HH / 2) ((u32*)hxbA)[i] = 0u;
    if (i < BB * NP1) { mask[i] = 0; nlist[i] = i % NP1; }
    if (i < BB) { cur[i] = -1; cnt[i] = NP1; }
    if (i < 256 * 16) slots[i] = 0;
    if (i < BB * 16) cflag[i] = 0;
    if (i == 0) *go = 0;
}

// ---------------------------------------------------------------------------
__global__ __launch_bounds__(256) void k_pack(const float* __restrict__ Wih,
                                              const float* __restrict__ Whh,
                                              const float* __restrict__ bih,
                                              const float* __restrict__ bhh,
                                              u16* __restrict__ Wpk,
                                              float* __restrict__ bpk) {
    const int jp = blockIdx.x;
    const int nt = jp >> 6, r = jp & 63, g = r >> 4, c = r & 15;
    const int j = g * HH + nt * 16 + c;
    const int t = threadIdx.x;
    const int k = t * 8;
    const float* s = (k < HH) ? (Wih + (size_t)j * HH + k)
                              : (Whh + (size_t)j * HH + (k - HH));
    float4 v0 = *(const float4*)(s);
    float4 v1 = *(const float4*)(s + 4);
    short8v o;
    o[0]=(short)f2b(v0.x); o[1]=(short)f2b(v0.y); o[2]=(short)f2b(v0.z); o[3]=(short)f2b(v0.w);
    o[4]=(short)f2b(v1.x); o[5]=(short)f2b(v1.y); o[6]=(short)f2b(v1.z); o[7]=(short)f2b(v1.w);
    *(short8v*)(Wpk + (size_t)jp * 2048 + k) = o;
    if (t == 0) bpk[jp] = bih[j] + bhh[j];
}

__global__ __launch_bounds__(256) void k_cvte(const float* __restrict__ enc,
                                              const float* __restrict__ etok,
                                              const float* __restrict__ stok,
                                              u16* __restrict__ encB) {
    const int row = blockIdx.x;
    const float* src = (row < BB * NN) ? enc + (size_t)row * HH
                      : (row == BB * NN ? etok : stok);
    const int t = threadIdx.x;
    float4 v = *(const float4*)(src + t * 4);
    short4v o;
    o[0]=(short)f2b(v.x); o[1]=(short)f2b(v.y); o[2]=(short)f2b(v.z); o[3]=(short)f2b(v.w);
    *(short4v*)(encB + (size_t)row * HH + t * 4) = o;
}

__global__ __launch_bounds__(256) void k_cvtu(const float* __restrict__ Ua,
                                              u16* __restrict__ Uab) {
    const int row = blockIdx.x;
    const int t = threadIdx.x;
    float4 v = *(const float4*)(Ua + (size_t)row * HH + t * 4);
    short4v o;
    o[0]=(short)f2b(v.x); o[1]=(short)f2b(v.y); o[2]=(short)f2b(v.z); o[3]=(short)f2b(v.w);
    *(short4v*)(Uab + (size_t)row * HH + t * 4) = o;
}

// ---------------------------------------------------------------------------
// encWa8[r, n] (fp8 e4m3) = sum_k ext[r,k] * Wa[n,k];  f32 math, fp8 store.
__global__ __launch_bounds__(256, 2) void k_encWa8(const float* __restrict__ enc,
                                                   const float* __restrict__ etok,
                                                   const float* __restrict__ Wa,
                                                   u8* __restrict__ out) {
    __shared__ float As[32][140];
    __shared__ float Ws[32][140];
    const int mt = blockIdx.x, ntl = blockIdx.y;
    const int tid = threadIdx.x;
    const int lr = tid >> 2, lc = tid & 3;
    const int tr = tid & 15, tc = tid >> 4;

    const int r0 = mt * 128 + lr, r1 = r0 + 64;
    const int bb0 = r0 / NP1, nn0 = r0 - bb0 * NP1;
    const int bb1 = r1 / NP1, nn1 = r1 - bb1 * NP1;
    const float* a0 = (nn0 == NN) ? etok : enc + ((size_t)(bb0 * NN + nn0)) * HH;
    const float* a1 = (nn1 == NN) ? etok : enc + ((size_t)(bb1 * NN + nn1)) * HH;
    const float* w0 = Wa + (size_t)(ntl * 128 + lr) * HH;
    const float* w1 = w0 + (size_t)64 * HH;
    const int ca = CPHI(lr), cb = CPHI(lr + 64);
    const int colA = tr * 8 + ((tr >> 2) << 2);
    const int colB = tc * 8 + ((tc >> 2) << 2);

    float acc[8][8] = {};
    for (int k0 = 0; k0 < HH; k0 += 32) {
        float4 va0 = *(const float4*)(a0 + k0 + lc * 4);
        float4 va1 = *(const float4*)(a0 + k0 + lc * 4 + 16);
        float4 va2 = *(const float4*)(a1 + k0 + lc * 4);
        float4 va3 = *(const float4*)(a1 + k0 + lc * 4 + 16);
        float4 vb0 = *(const float4*)(w0 + k0 + lc * 4);
        float4 vb1 = *(const float4*)(w0 + k0 + lc * 4 + 16);
        float4 vb2 = *(const float4*)(w1 + k0 + lc * 4);
        float4 vb3 = *(const float4*)(w1 + k0 + lc * 4 + 16);
        __syncthreads();
        #pragma unroll
        for (int e = 0; e < 4; e++) {
            As[lc*4+e][ca]      = ((const float*)&va0)[e];
            As[lc*4+16+e][ca]   = ((const float*)&va1)[e];
            As[lc*4+e][cb]      = ((const float*)&va2)[e];
            As[lc*4+16+e][cb]   = ((const float*)&va3)[e];
            Ws[lc*4+e][ca]      = ((const float*)&vb0)[e];
            Ws[lc*4+16+e][ca]   = ((const float*)&vb1)[e];
            Ws[lc*4+e][cb]      = ((const float*)&vb2)[e];
            Ws[lc*4+16+e][cb]   = ((const float*)&vb3)[e];
        }
        __syncthreads();
        #pragma unroll
        for (int kk = 0; kk < 32; kk++) {
            float4 A0 = *(const float4*)&As[kk][colA];
            float4 A1 = *(const float4*)&As[kk][colA + 4];
            float4 B0 = *(const float4*)&Ws[kk][colB];
            float4 B1 = *(const float4*)&Ws[kk][colB + 4];
            float av[8] = {A0.x,A0.y,A0.z,A0.w,A1.x,A1.y,A1.z,A1.w};
            float bv[8] = {B0.x,B0.y,B0.z,B0.w,B1.x,B1.y,B1.z,B1.w};
            #pragma unroll
            for (int i = 0; i < 8; i++)
                #pragma unroll
                for (int j = 0; j < 8; j++) acc[i][j] += av[i] * bv[j];
        }
        __syncthreads();
    }
    #pragma unroll
    for (int i = 0; i < 8; i++) {
        u64 pk = 0;
        #pragma unroll
        for (int j = 0; j < 8; j++)
            pk |= (u64)f2e8(acc[i][j]) << (8 * j);
        *(u64*)(out + (size_t)(mt * 128 + tr * 8 + i) * HH + ntl * 128 + tc * 8) = pk;
    }
}

// ---------------------------------------------------------------------------
// Persistent decode: 256 blocks x 512 threads.
// A: 8-wave split-K gates GEMM + cell;  B: hUa partials (waves 0-3)
// C1: scores over UNMASKED rows, 4-row double-buffered pipeline, HPHI-padded
//     hu/vv LDS (conflict-free), fp8 encWa via sc1
// C2: finalize + swap-remove selected index from list
__global__ __launch_bounds__(512, 1) void k_persist(
    const u16* __restrict__ encB, const u16* __restrict__ Wpk,
    const float* __restrict__ bpk, const u16* __restrict__ Uab,
    const u8* __restrict__ encWa8, const float* __restrict__ vvec,
    int* __restrict__ cur, int* __restrict__ mask,
    u16* __restrict__ hxbA, u16* __restrict__ hxbB,
    float* __restrict__ cx, float* __restrict__ hup,
    float* __restrict__ scSg, int* __restrict__ cflag,
    int* __restrict__ nlist, int* __restrict__ cnt,
    float* __restrict__ out_lp, float* __restrict__ out_idx,
    int* __restrict__ slots, int* __restrict__ go)
{
    __shared__ u16 AsX[32 * 64];
    __shared__ u16 BsX[64 * 64];
    __shared__ u16 AsH[32 * 64];
    __shared__ u16 BsH[64 * 64];
    __shared__ float Gs[8][32][17];
    __shared__ float huS[HH + 32];
    __shared__ float vvS[HH + 32];
    __shared__ float rv[512];
    __shared__ int   ri[512];
    __shared__ int   nlS[NP1];
    __shared__ int   posS;

    const int bid = blockIdx.x;
    const int t = threadIdx.x;
    const int wv = t >> 6, lane = t & 63;
    const int tg = t & 255, w4 = (t >> 6) & 3;
    int gen = 1;

    for (int step = 0; step < NP1; step++) {
        const u16* hin = (step & 1) ? hxbB : hxbA;
        u16* hout = (step & 1) ? hxbA : hxbB;

        // ============ phase A: gates GEMM + LSTM cell (8-wave split-K) =====
        {
            const int nt = bid & 63, mt = bid >> 6;
            const int rA = tg >> 3, koA = (tg & 7) * 8;      // A: 32r x 8 cols
            const int cA16 = tg & 7;
            const int rB = tg >> 2, koB = (tg & 3) * 16;     // B: 64r x 2x16B
            const int cB16 = (tg & 3) * 2;
            const int mg = mt * 32 + rA;

            short8v apre[16];
            short8v b0_pf[3], b1_pf[3];
            const u16* brow = nullptr;
            if (t < 256) {          // x-group: preload ALL 16 x-chunks upfront
                const int sel = (int)gload32((const u32*)&cur[mg]);
                const u16* xrow = encB + (size_t)((sel < 0) ? (BB * NN + 1)
                             : (sel == NN ? BB * NN : (mg * NN + sel))) * HH;
                #pragma unroll
                for (int i = 0; i < 16; i++)
                    apre[i] = *(const short8v*)(xrow + i * 64 + koA);
                brow = Wpk + (size_t)(nt * 64 + rB) * 2048;
            } else {                // h-group: preload ALL 16 h-chunks (sc1)
                const u16* hrow = hin + (size_t)mg * HH;
                #pragma unroll
                for (int i = 0; i < 16; i++)
                    apre[i] = gload8h(hrow + i * 64 + koA);
                brow = Wpk + (size_t)(nt * 64 + rB) * 2048 + HH;
            }
            #pragma unroll
            for (int d = 0; d < 3; d++) {
                b0_pf[d] = *(const short8v*)(brow + d * 64 + koB);
                b1_pf[d] = *(const short8v*)(brow + d * 64 + koB + 8);
            }
            float4v acc0 = {}, acc1 = {};
            #pragma unroll
            for (int it = 0; it < 16; ++it) {
                __syncthreads();
                if (t < 256) {
                    *(short8v*)&AsX[SWZ(rA, cA16)] = apre[it];
                    *(short8v*)&BsX[SWZ(rB, cB16)] = b0_pf[it % 3];
                    *(short8v*)&BsX[SWZ(rB, cB16 + 1)] = b1_pf[it % 3];
                } else {
                    *(short8v*)&AsH[SWZ(rA, cA16)] = apre[it];
                    *(short8v*)&BsH[SWZ(rB, cB16)] = b0_pf[it % 3];
                    *(short8v*)&BsH[SWZ(rB, cB16 + 1)] = b1_pf[it % 3];
                }
                __syncthreads();
                if (it + 3 < 16) {
                    b0_pf[it % 3] = *(const short8v*)(brow + (it + 3) * 64 + koB);
                    b1_pf[it % 3] = *(const short8v*)(brow + (it + 3) * 64 + koB + 8);
                }
                if (t < 256) {
                    #pragma unroll
                    for (int kf = 0; kf < 2; ++kf) {
                        const int c16 = kf * 4 + (lane >> 4);
                        short8v bf = *(const short8v*)&BsX[SWZ(w4 * 16 + (lane & 15), c16)];
                        short8v a0 = *(const short8v*)&AsX[SWZ(lane & 15, c16)];
                        short8v a1 = *(const short8v*)&AsX[SWZ(16 + (lane & 15), c16)];
                        acc0 = __builtin_amdgcn_mfma_f32_16x16x32_bf16(a0, bf, acc0, 0, 0, 0);
                        acc1 = __builtin_amdgcn_mfma_f32_16x16x32_bf16(a1, bf, acc1, 0, 0, 0);
                    }
                } else {
                    #pragma unroll
                    for (int kf = 0; kf < 2; ++kf) {
                        const int c16 = kf * 4 + (lane >> 4);
                        short8v bf = *(const short8v*)&BsH[SWZ(w4 * 16 + (lane & 15), c16)];
                        short8v a0 = *(const short8v*)&AsH[SWZ(lane & 15, c16)];
                        short8v a1 = *(const short8v*)&AsH[SWZ(16 + (lane & 15), c16)];
                        acc0 = __builtin_amdgcn_mfma_f32_16x16x32_bf16(a0, bf, acc0, 0, 0, 0);
                        acc1 = __builtin_amdgcn_mfma_f32_16x16x32_bf16(a1, bf, acc1, 0, 0, 0);
                    }
                }
            }
            __syncthreads();
            #pragma unroll
            for (int r = 0; r < 4; r++) {
                Gs[wv][(lane >> 4) * 4 + r][lane & 15]      = acc0[r];
                Gs[wv][16 + (lane >> 4) * 4 + r][lane & 15] = acc1[r];
            }
            __syncthreads();
            if (t < 256) {
                const int m = t >> 3, cpr = (t & 7) * 2;
                const int mg2 = mt * 32 + m;
                float hn2[2];
                #pragma unroll
                for (int e = 0; e < 2; e++) {
                    const int c = cpr + e;
                    float gi  = Gs[0][m][c] + Gs[4][m][c] + bpk[nt * 64 + c];
                    float gf  = Gs[1][m][c] + Gs[5][m][c] + bpk[nt * 64 + 16 + c];
                    float gg  = Gs[2][m][c] + Gs[6][m][c] + bpk[nt * 64 + 32 + c];
                    float go2 = Gs[3][m][c] + Gs[7][m][c] + bpk[nt * 64 + 48 + c];
                    const int cg = nt * 16 + c;
                    float cold = cx[(size_t)mg2 * HH + cg];
                    float cn = fsig(gf) * cold + fsig(gi) * ftanh(gg);
                    hn2[e] = fsig(go2) * ftanh(cn);
                    cx[(size_t)mg2 * HH + cg] = cn;
                }
                u32 pk = (u32)f2b(hn2[0]) | ((u32)f2b(hn2[1]) << 16);
                gstore32((u32*)(hout + (size_t)mg2 * HH + nt * 16 + cpr), pk);
            }
        }
        pbar(slots, go, gen++);

        // ============ phase B: hUa partials (waves 0-3) ====================
        {
            const int nt2 = bid & 15, mt2 = (bid >> 4) & 3, ks = bid >> 6;
            const int rA = tg >> 3, koA = (tg & 7) * 8;
            const int cA16 = tg & 7;
            const int rB = tg >> 2, koB = (tg & 3) * 16;
            const int cB16 = (tg & 3) * 2;
            short8v hb[4];
            short8v ub0[2], ub1[2];
            const u16* brow = nullptr;
            if (t < 256) {
                const u16* arow = hout + (size_t)(mt2 * 32 + rA) * HH + ks * 256;
                #pragma unroll
                for (int i = 0; i < 4; i++)
                    hb[i] = gload8h(arow + i * 64 + koA);
                brow = Uab + (size_t)(nt2 * 64 + rB) * HH + ks * 256;
                #pragma unroll
                for (int d = 0; d < 2; d++) {
                    ub0[d] = *(const short8v*)(brow + d * 64 + koB);
                    ub1[d] = *(const short8v*)(brow + d * 64 + koB + 8);
                }
            }
            float4v acc0 = {}, acc1 = {};
            #pragma unroll
            for (int it = 0; it < 4; ++it) {
                __syncthreads();
                if (t < 256) {
                    *(short8v*)&AsX[SWZ(rA, cA16)] = hb[it];
                    *(short8v*)&BsX[SWZ(rB, cB16)] = ub0[it & 1];
                    *(short8v*)&BsX[SWZ(rB, cB16 + 1)] = ub1[it & 1];
                }
                __syncthreads();
                if (t < 256) {
                    if (it + 2 < 4) {
                        ub0[it & 1] = *(const short8v*)(brow + (it + 2) * 64 + koB);
                        ub1[it & 1] = *(const short8v*)(brow + (it + 2) * 64 + koB + 8);
                    }
                    #pragma unroll
                    for (int kf = 0; kf < 2; ++kf) {
                        const int c16 = kf * 4 + (lane >> 4);
                        short8v bf = *(const short8v*)&BsX[SWZ(w4 * 16 + (lane & 15), c16)];
                        short8v a0 = *(const short8v*)&AsX[SWZ(lane & 15, c16)];
                        short8v a1 = *(const short8v*)&AsX[SWZ(16 + (lane & 15), c16)];
                        acc0 = __builtin_amdgcn_mfma_f32_16x16x32_bf16(a0, bf, acc0, 0, 0, 0);
                        acc1 = __builtin_amdgcn_mfma_f32_16x16x32_bf16(a1, bf, acc1, 0, 0, 0);
                    }
                }
            }
            if (t < 256) {
                const int n = nt2 * 64 + w4 * 16 + (lane & 15);
                #pragma unroll
                for (int r = 0; r < 4; r++) {
                    const int m0 = mt2 * 32 + (lane >> 4) * 4 + r;
                    gstore32((u32*)&hup[((size_t)ks * BB + m0) * HH + n],
                             __float_as_uint(acc0[r]));
                    gstore32((u32*)&hup[((size_t)ks * BB + m0 + 16) * HH + n],
                             __float_as_uint(acc1[r]));
                }
            }
        }
        pbar(slots, go, gen++);

        // ============ phase C1: scores over UNMASKED slots (2 blocks/batch)
        int cntb_v = 0;
        {
            const int qb = bid >> 7, b = bid & 127;
            #pragma unroll
            for (int cc = 0; cc < 2; cc++) {
                const int c = t + cc * 512;
                float s = 0.f;
                #pragma unroll
                for (int ks = 0; ks < 4; ks++)
                    s += __uint_as_float(gload32((const u32*)&hup[((size_t)ks * BB + b) * HH + c]));
                huS[HPHI(c)] = s;
                vvS[HPHI(c)] = vvec[c];
            }
            cntb_v = (int)gload32((const u32*)&cnt[b]);
            for (int i = t; i < cntb_v; i += 512)
                nlS[i] = (int)gload32((const u32*)&nlist[b * NP1 + i]);
            __syncthreads();

            const int half = (cntb_v + 1) >> 1;
            const int iend = qb ? cntb_v : half;
            const int istart = (qb ? half : 0) + wv * 4;
            const int c0 = lane * 16;

            auto loadrow = [&](int ii, u64& A, u64& B) {
                const int idx = nlS[(ii < iend) ? ii : (iend - 1)];
                const u8* rp = encWa8 + ((size_t)b * NP1 + idx) * HH + c0;
                A = gload64b(rp);
                B = gload64b(rp + 8);
            };
            auto rowscore = [&](u64 p0, u64 p1) -> float {
                float s = 0.f;
                #pragma unroll
                for (int j = 0; j < 8; j++)
                    s += vvS[HPHI(c0 + j)] * ftanh(e82f((u32)(p0 >> (8 * j)) & 0xFFu) + huS[HPHI(c0 + j)]);
                #pragma unroll
                for (int j = 0; j < 8; j++)
                    s += vvS[HPHI(c0 + 8 + j)] * ftanh(e82f((u32)(p1 >> (8 * j)) & 0xFFu) + huS[HPHI(c0 + 8 + j)]);
                #pragma unroll
                for (int off = 32; off; off >>= 1) s += __shfl_down(s, off);
                return s;
            };

            if (istart < iend) {
                u64 qa0, qc0, qa1, qc1, qa2, qc2, qa3, qc3;
                loadrow(istart + 0, qa0, qc0);
                loadrow(istart + 1, qa1, qc1);
                loadrow(istart + 2, qa2, qc2);
                loadrow(istart + 3, qa3, qc3);
                for (int i = istart; i < iend; i += 32) {
                    u64 pa0, pc0, pa1, pc1, pa2, pc2, pa3, pc3;
                    const int inext = i + 32;
                    if (inext < iend) {
                        loadrow(inext + 0, pa0, pc0);
                        loadrow(inext + 1, pa1, pc1);
                        loadrow(inext + 2, pa2, pc2);
                        loadrow(inext + 3, pa3, pc3);
                    } else {
                        pa0 = qa0; pc0 = qc0; pa1 = qa1; pc1 = qc1;
                        pa2 = qa2; pc2 = qc2; pa3 = qa3; pc3 = qc3;
                    }
                    float s0 = rowscore(qa0, qc0);
                    float s1 = rowscore(qa1, qc1);
                    float s2 = rowscore(qa2, qc2);
                    float s3 = rowscore(qa3, qc3);
                    if (lane == 0) {
                        gstore32((u32*)&scSg[b * NP1 + nlS[i]], __float_as_uint(s0));
                        if (i + 1 < iend)
                            gstore32((u32*)&scSg[b * NP1 + nlS[i + 1]], __float_as_uint(s1));
                        if (i + 2 < iend)
                            gstore32((u32*)&scSg[b * NP1 + nlS[i + 2]], __float_as_uint(s2));
                        if (i + 3 < iend)
                            gstore32((u32*)&scSg[b * NP1 + nlS[i + 3]], __float_as_uint(s3));
                    }
                    qa0 = pa0; qc0 = pc0; qa1 = pa1; qc1 = pc1;
                    qa2 = pa2; qc2 = pc2; qa3 = pa3; qc3 = pc3;
                }
            }
            __syncthreads();
            if (qb == 1 && t == 0) gstore32((u32*)&cflag[b << 4], (u32)(step + 1));
        }

        // ============ phase C2: finalize + list swap-remove (blocks 0..127)
        if (bid < 128) {
            const int b = bid;
            if (t == 0) {
                while ((int)gload32((const u32*)&cflag[b << 4]) <= step)
                    __builtin_amdgcn_s_sleep(1);
            }
            __syncthreads();

            float va = -INFINITY;
            if (t < NP1) {
                float sc = __uint_as_float(gload32((const u32*)&scSg[b * NP1 + t]));
                va = (mask[b * NP1 + t] != 0) ? -INFINITY : sc;
            }
            rv[t] = va; ri[t] = t;
            __syncthreads();
            for (int s = 256; s; s >>= 1) {
                if (t < s) {
                    float ov = rv[t + s]; int oi = ri[t + s];
                    if (ov > rv[t] || (ov == rv[t] && oi < ri[t])) { rv[t] = ov; ri[t] = oi; }
                }
                __syncthreads();
            }
            const float vmax = rv[0]; const int amax = ri[0];
            __syncthreads();

            float es = (t < NP1) ? expf(va - vmax) : 0.f;
            rv[t] = es;
            __syncthreads();
            for (int s = 256; s; s >>= 1) {
                if (t < s) rv[t] += rv[t + s];
                __syncthreads();
            }
            const float lse = vmax + logf(rv[0]);

            if (t < NP1)
                out_lp[((size_t)b * NP1 + step) * NP1 + t] = fmaxf(va - lse, -1e30f);

            // swap-remove amax from the unmasked list (end token stays)
            if (t == 0) posS = -1;
            __syncthreads();
            if (t < cntb_v && nlS[t] == amax) posS = t;
            __syncthreads();
            if (t == 0) {
                if (amax < NN && posS >= 0) {
                    gstore32((u32*)&nlist[b * NP1 + posS], (u32)nlS[cntb_v - 1]);
                    gstore32((u32*)&cnt[b], (u32)(cntb_v - 1));
                }
                out_idx[(size_t)b * NP1 + step] = (float)amax;
                gstore32((u32*)&cur[b], (u32)amax);
                if (amax < NN) mask[b * NP1 + amax] = 1;
            }
        }
        pbar(slots, go, gen++);
    }
}

// ---------------------------------------------------------------------------
extern "C" void kernel_launch(void* const* d_in, const int* in_sizes, int n_in,
                              void* d_out, int out_size, void* d_ws, size_t ws_size,
                              hipStream_t stream) {
    const float* enc  = (const float*)d_in[0];
    const float* Wih  = (const float*)d_in[1];
    const float* Whh  = (const float*)d_in[2];
    const float* bih  = (const float*)d_in[3];
    const float* bhh  = (const float*)d_in[4];
    const float* Wa   = (const float*)d_in[5];
    const float* Ua   = (const float*)d_in[6];
    const float* v    = (const float*)d_in[7];
    const float* stok = (const float*)d_in[8];
    const float* etok = (const float*)d_in[9];
    float* out = (float*)d_out;
    float* out_idx = out + (size_t)BB * NP1 * NP1;

    size_t off = 0;
    char* base = (char*)d_ws;
    auto alloc = [&](size_t bytes) -> char* {
        char* p = base + off;
        off += (bytes + 255) & ~(size_t)255;
        return p;
    };
    u8*    encWa8 = (u8*)   alloc((size_t)BB * NP1 * HH);          // 33.7 MB
    u16*   encB   = (u16*)  alloc((size_t)(BB * NN + 2) * HH * 2); // 67.1 MB
    u16*   Wpk    = (u16*)  alloc((size_t)4096 * 2048 * 2);        // 16.8 MB
    u16*   Uab    = (u16*)  alloc((size_t)HH * HH * 2);
    float* bpk    = (float*)alloc((size_t)4096 * 4);
    float* hup    = (float*)alloc((size_t)4 * BB * HH * 4);
    float* cx     = (float*)alloc((size_t)BB * HH * 4);
    u16*   hxbA   = (u16*)  alloc((size_t)BB * HH * 2);
    u16*   hxbB   = (u16*)  alloc((size_t)BB * HH * 2);
    float* scSg   = (float*)alloc((size_t)BB * NP1 * 4);
    int*   mask   = (int*)  alloc((size_t)BB * NP1 * 4);
    int*   nlist  = (int*)  alloc((size_t)BB * NP1 * 4);
    int*   cnt    = (int*)  alloc((size_t)BB * 4);
    int*   cur    = (int*)  alloc((size_t)BB * 4);
    int*   slots  = (int*)  alloc((size_t)256 * 16 * 4);
    int*   go     = (int*)  alloc((size_t)64);
    int*   cflag  = (int*)  alloc((size_t)BB * 16 * 4);
    if (off > ws_size) return;   // distinctive failure: 0-node graph

    k_binit<<<512, 256, 0, stream>>>(cx, hxbA, mask, cur, slots, go, cflag,
                                     nlist, cnt);
    k_pack<<<4096, 256, 0, stream>>>(Wih, Whh, bih, bhh, Wpk, bpk);
    k_cvte<<<BB * NN + 2, 256, 0, stream>>>(enc, etok, stok, encB);
    k_cvtu<<<HH, 256, 0, stream>>>(Ua, Uab);
    k_encWa8<<<dim3(257, 8), 256, 0, stream>>>(enc, etok, Wa, encWa8);

    void* args[] = { (void*)&encB, (void*)&Wpk, (void*)&bpk, (void*)&Uab,
                     (void*)&encWa8, (void*)&v, (void*)&cur, (void*)&mask,
                     (void*)&hxbA, (void*)&hxbB, (void*)&cx, (void*)&hup,
                     (void*)&scSg, (void*)&cflag, (void*)&nlist, (void*)&cnt,
                     (void*)&out, (void*)&out_idx, (void*)&slots, (void*)&go };
    hipLaunchCooperativeKernel((const void*)k_persist, dim3(256), dim3(512),
                               args, 0, stream);
}

// Round 15
// 8487.608 us; speedup vs baseline: 2.4028x; 1.0183x over previous
//
#include <hip/hip_runtime.h>
#include <math.h>

#define BB 128
#define NN 256
#define NP1 257
#define HH 1024

typedef unsigned char u8;
typedef unsigned short u16;
typedef unsigned int u32;
typedef unsigned long long u64;
typedef __attribute__((ext_vector_type(8))) short short8v;
typedef __attribute__((ext_vector_type(4))) short short4v;
typedef __attribute__((ext_vector_type(4))) float float4v;

__device__ __forceinline__ u16 f2b(float x) {            // f32 -> bf16 (RNE)
    union { float f; u32 u; } c; c.f = x;
    u32 r = (c.u + 0x7fffu + ((c.u >> 16) & 1u)) >> 16;
    return (u16)r;
}
__device__ __forceinline__ float b2f(u16 s) {
    union { u32 u; float f; } c; c.u = ((u32)s) << 16;
    return c.f;
}
__device__ __forceinline__ float ftanh(float x) {
    float e = __builtin_amdgcn_exp2f(x * 2.8853900817779268f);
    return 1.f - 2.f * __builtin_amdgcn_rcpf(e + 1.f);
}
__device__ __forceinline__ float fsig(float x) {
    return __builtin_amdgcn_rcpf(1.f + __builtin_amdgcn_exp2f(x * -1.4426950408889634f));
}

// ---- fp8 e4m3fn helpers -----------------------------------------------------
__device__ __forceinline__ u8 f2e8(float x) {            // f32 -> e4m3 (RNE)
    u32 u = __float_as_uint(x);
    u32 sgn = (u >> 24) & 0x80u;
    float ax = __uint_as_float(u & 0x7fffffffu);
    if (!(ax < 448.f)) return (u8)(sgn | 0x7Eu);         // clamp, NaN -> max
    if (ax < 0.015625f) {                                // subnormal, q = 2^-9
        int q = (int)rintf(ax * 512.f);
        if (q >= 8) return (u8)(sgn | 0x08u);
        return (u8)(sgn | (u32)q);
    }
    u32 au = u & 0x7fffffffu;
    au += 0x7ffffu + ((au >> 20) & 1u);                  // RNE at bit 20
    int e = (int)(au >> 23) - 127;
    u32 m3 = (au >> 20) & 7u;
    if (e > 8 || (e == 8 && m3 == 7)) return (u8)(sgn | 0x7Eu);
    return (u8)(sgn | ((u32)(e + 7) << 3) | m3);
}
__device__ __forceinline__ float e82f(u32 u) {           // e4m3 -> f32 (exact)
    u32 t = ((u & 0x80u) << 24) | ((u & 0x7Fu) << 20);
    return __uint_as_float(t) * 0x1p+120f;
}

// LLC-coherent (sc1) access helpers
__device__ __forceinline__ u64 gload64(const u16* p) {
    return __hip_atomic_load((u64*)p, __ATOMIC_RELAXED, __HIP_MEMORY_SCOPE_AGENT);
}
__device__ __forceinline__ u64 gload64b(const u8* p) {
    return __hip_atomic_load((const u64*)p, __ATOMIC_RELAXED, __HIP_MEMORY_SCOPE_AGENT);
}
__device__ __forceinline__ short8v gload8h(const u16* p) {
    union { u64 q[2]; short8v v; } uq;
    uq.q[0] = gload64(p);
    uq.q[1] = gload64(p + 4);
    return uq.v;
}
__device__ __forceinline__ void gstore32(u32* p, u32 v) {
    __hip_atomic_store(p, v, __ATOMIC_RELAXED, __HIP_MEMORY_SCOPE_AGENT);
}
__device__ __forceinline__ u32 gload32(const u32* p) {
    return __hip_atomic_load((u32*)p, __ATOMIC_RELAXED, __HIP_MEMORY_SCOPE_AGENT);
}

#define CPHI(m) ((m) + (((m) >> 5) << 2))
// Swizzled bf16 MFMA tile (round-13, proven): row stride 64 u16, col^row&7.
#define SWZ(r, c) (((r) << 6) + ((((c) ^ ((r) & 7))) << 3))
// Pad-1-per-32 for f32 arrays read at stride 16 (round-14, proven).
#define HPHI(c) ((c) + ((c) >> 5))

// LDS-only barrier for GEMM inner loops (round-15): __syncthreads() lowers to
// s_waitcnt vmcnt(0) lgkmcnt(0) + s_barrier [HIP-compiler], which DRAINS the
// global prefetch queue every iteration (ring prefetch was dead weight rounds
// 7-14). lgkmcnt(0)-only + raw s_barrier keeps VMEM in flight across
// iterations; register deps get compiler-counted vmcnt automatically.
#define GBAR() do {                                        \
    asm volatile("s_waitcnt lgkmcnt(0)" ::: "memory");     \
    __builtin_amdgcn_s_barrier();                          \
} while (0)

// ---------------------------------------------------------------------------
// Fence-free grid barrier (round-9, proven): per-block slots + go word, sc1.
// Keeps __syncthreads (its vmcnt(0) drain is REQUIRED: sc1 stores must reach
// LLC before the arrival signal).
__device__ __forceinline__ void pbar(int* slots, int* go, int gen) {
    asm volatile("" ::: "memory");
    __syncthreads();
    const int t = threadIdx.x;
    if (blockIdx.x == 0) {
        if (t >= 1 && t < 256) {
            while ((int)gload32((u32*)&slots[t << 4]) < gen)
                __builtin_amdgcn_s_sleep(1);
        }
        __syncthreads();
        if (t == 0) gstore32((u32*)go, (u32)gen);
    } else {
        if (t == 0) {
            gstore32((u32*)&slots[blockIdx.x << 4], (u32)gen);
            while ((int)gload32((u32*)go) < gen)
                __builtin_amdgcn_s_sleep(1);
        }
        __syncthreads();
    }
    asm volatile("" ::: "memory");
}

// ---------------------------------------------------------------------------
__global__ __launch_bounds__(256) void k_binit(float* cx, u16* hxbA, int* mask,
                                               int* cur, int* slots, int* go,
                                               int* cflag, int* nlist, int* cnt) {
    int i = blockIdx.x * 256 + threadIdx.x;
    if (i < BB * HH) cx[i] = 0.f;
    if (i < BB * HH / 2) ((u32*)hxbA)[i] = 0u;
    if (i < BB * NP1) { mask[i] = 0; nlist[i] = i % NP1; }
    if (i < BB) { cur[i] = -1; cnt[i] = NP1; }
    if (i < 256 * 16) slots[i] = 0;
    if (i < BB * 16) cflag[i] = 0;
    if (i == 0) *go = 0;
}

// ---------------------------------------------------------------------------
__global__ __launch_bounds__(256) void k_pack(const float* __restrict__ Wih,
                                              const float* __restrict__ Whh,
                                              const float* __restrict__ bih,
                                              const float* __restrict__ bhh,
                                              u16* __restrict__ Wpk,
                                              float* __restrict__ bpk) {
    const int jp = blockIdx.x;
    const int nt = jp >> 6, r = jp & 63, g = r >> 4, c = r & 15;
    const int j = g * HH + nt * 16 + c;
    const int t = threadIdx.x;
    const int k = t * 8;
    const float* s = (k < HH) ? (Wih + (size_t)j * HH + k)
                              : (Whh + (size_t)j * HH + (k - HH));
    float4 v0 = *(const float4*)(s);
    float4 v1 = *(const float4*)(s + 4);
    short8v o;
    o[0]=(short)f2b(v0.x); o[1]=(short)f2b(v0.y); o[2]=(short)f2b(v0.z); o[3]=(short)f2b(v0.w);
    o[4]=(short)f2b(v1.x); o[5]=(short)f2b(v1.y); o[6]=(short)f2b(v1.z); o[7]=(short)f2b(v1.w);
    *(short8v*)(Wpk + (size_t)jp * 2048 + k) = o;
    if (t == 0) bpk[jp] = bih[j] + bhh[j];
}

__global__ __launch_bounds__(256) void k_cvte(const float* __restrict__ enc,
                                              const float* __restrict__ etok,
                                              const float* __restrict__ stok,
                                              u16* __restrict__ encB) {
    const int row = blockIdx.x;
    const float* src = (row < BB * NN) ? enc + (size_t)row * HH
                      : (row == BB * NN ? etok : stok);
    const int t = threadIdx.x;
    float4 v = *(const float4*)(src + t * 4);
    short4v o;
    o[0]=(short)f2b(v.x); o[1]=(short)f2b(v.y); o[2]=(short)f2b(v.z); o[3]=(short)f2b(v.w);
    *(short4v*)(encB + (size_t)row * HH + t * 4) = o;
}

__global__ __launch_bounds__(256) void k_cvtu(const float* __restrict__ Ua,
                                              u16* __restrict__ Uab) {
    const int row = blockIdx.x;
    const int t = threadIdx.x;
    float4 v = *(const float4*)(Ua + (size_t)row * HH + t * 4);
    short4v o;
    o[0]=(short)f2b(v.x); o[1]=(short)f2b(v.y); o[2]=(short)f2b(v.z); o[3]=(short)f2b(v.w);
    *(short4v*)(Uab + (size_t)row * HH + t * 4) = o;
}

// ---------------------------------------------------------------------------
// encWa8[r, n] (fp8 e4m3) = sum_k ext[r,k] * Wa[n,k];  f32 math, fp8 store.
__global__ __launch_bounds__(256, 2) void k_encWa8(const float* __restrict__ enc,
                                                   const float* __restrict__ etok,
                                                   const float* __restrict__ Wa,
                                                   u8* __restrict__ out) {
    __shared__ float As[32][140];
    __shared__ float Ws[32][140];
    const int mt = blockIdx.x, ntl = blockIdx.y;
    const int tid = threadIdx.x;
    const int lr = tid >> 2, lc = tid & 3;
    const int tr = tid & 15, tc = tid >> 4;

    const int r0 = mt * 128 + lr, r1 = r0 + 64;
    const int bb0 = r0 / NP1, nn0 = r0 - bb0 * NP1;
    const int bb1 = r1 / NP1, nn1 = r1 - bb1 * NP1;
    const float* a0 = (nn0 == NN) ? etok : enc + ((size_t)(bb0 * NN + nn0)) * HH;
    const float* a1 = (nn1 == NN) ? etok : enc + ((size_t)(bb1 * NN + nn1)) * HH;
    const float* w0 = Wa + (size_t)(ntl * 128 + lr) * HH;
    const float* w1 = w0 + (size_t)64 * HH;
    const int ca = CPHI(lr), cb = CPHI(lr + 64);
    const int colA = tr * 8 + ((tr >> 2) << 2);
    const int colB = tc * 8 + ((tc >> 2) << 2);

    float acc[8][8] = {};
    for (int k0 = 0; k0 < HH; k0 += 32) {
        float4 va0 = *(const float4*)(a0 + k0 + lc * 4);
        float4 va1 = *(const float4*)(a0 + k0 + lc * 4 + 16);
        float4 va2 = *(const float4*)(a1 + k0 + lc * 4);
        float4 va3 = *(const float4*)(a1 + k0 + lc * 4 + 16);
        float4 vb0 = *(const float4*)(w0 + k0 + lc * 4);
        float4 vb1 = *(const float4*)(w0 + k0 + lc * 4 + 16);
        float4 vb2 = *(const float4*)(w1 + k0 + lc * 4);
        float4 vb3 = *(const float4*)(w1 + k0 + lc * 4 + 16);
        __syncthreads();
        #pragma unroll
        for (int e = 0; e < 4; e++) {
            As[lc*4+e][ca]      = ((const float*)&va0)[e];
            As[lc*4+16+e][ca]   = ((const float*)&va1)[e];
            As[lc*4+e][cb]      = ((const float*)&va2)[e];
            As[lc*4+16+e][cb]   = ((const float*)&va3)[e];
            Ws[lc*4+e][ca]      = ((const float*)&vb0)[e];
            Ws[lc*4+16+e][ca]   = ((const float*)&vb1)[e];
            Ws[lc*4+e][cb]      = ((const float*)&vb2)[e];
            Ws[lc*4+16+e][cb]   = ((const float*)&vb3)[e];
        }
        __syncthreads();
        #pragma unroll
        for (int kk = 0; kk < 32; kk++) {
            float4 A0 = *(const float4*)&As[kk][colA];
            float4 A1 = *(const float4*)&As[kk][colA + 4];
            float4 B0 = *(const float4*)&Ws[kk][colB];
            float4 B1 = *(const float4*)&Ws[kk][colB + 4];
            float av[8] = {A0.x,A0.y,A0.z,A0.w,A1.x,A1.y,A1.z,A1.w};
            float bv[8] = {B0.x,B0.y,B0.z,B0.w,B1.x,B1.y,B1.z,B1.w};
            #pragma unroll
            for (int i = 0; i < 8; i++)
                #pragma unroll
                for (int j = 0; j < 8; j++) acc[i][j] += av[i] * bv[j];
        }
        __syncthreads();
    }
    #pragma unroll
    for (int i = 0; i < 8; i++) {
        u64 pk = 0;
        #pragma unroll
        for (int j = 0; j < 8; j++)
            pk |= (u64)f2e8(acc[i][j]) << (8 * j);
        *(u64*)(out + (size_t)(mt * 128 + tr * 8 + i) * HH + ntl * 128 + tc * 8) = pk;
    }
}

// ---------------------------------------------------------------------------
// Persistent decode: 256 blocks x 512 threads.
// A: 8-wave split-K gates GEMM + cell (GBAR loop barriers, prefetch in flight)
// B: hUa partials (GBAR loop barriers)
// C1: scores over UNMASKED rows, 4-row double-buffered pipeline
// C2: finalize with wave-level reductions + list swap-remove
__global__ __launch_bounds__(512, 1) void k_persist(
    const u16* __restrict__ encB, const u16* __restrict__ Wpk,
    const float* __restrict__ bpk, const u16* __restrict__ Uab,
    const u8* __restrict__ encWa8, const float* __restrict__ vvec,
    int* __restrict__ cur, int* __restrict__ mask,
    u16* __restrict__ hxbA, u16* __restrict__ hxbB,
    float* __restrict__ cx, float* __restrict__ hup,
    float* __restrict__ scSg, int* __restrict__ cflag,
    int* __restrict__ nlist, int* __restrict__ cnt,
    float* __restrict__ out_lp, float* __restrict__ out_idx,
    int* __restrict__ slots, int* __restrict__ go)
{
    __shared__ u16 AsX[32 * 64];
    __shared__ u16 BsX[64 * 64];
    __shared__ u16 AsH[32 * 64];
    __shared__ u16 BsH[64 * 64];
    __shared__ float Gs[8][32][17];
    __shared__ float huS[HH + 32];
    __shared__ float vvS[HH + 32];
    __shared__ float rv[32];
    __shared__ int   ri[16];
    __shared__ int   nlS[NP1];
    __shared__ int   posS;

    const int bid = blockIdx.x;
    const int t = threadIdx.x;
    const int wv = t >> 6, lane = t & 63;
    const int tg = t & 255, w4 = (t >> 6) & 3;
    int gen = 1;

    for (int step = 0; step < NP1; step++) {
        const u16* hin = (step & 1) ? hxbB : hxbA;
        u16* hout = (step & 1) ? hxbA : hxbB;

        // ============ phase A: gates GEMM + LSTM cell (8-wave split-K) =====
        {
            const int nt = bid & 63, mt = bid >> 6;
            const int rA = tg >> 3, koA = (tg & 7) * 8;      // A: 32r x 8 cols
            const int cA16 = tg & 7;
            const int rB = tg >> 2, koB = (tg & 3) * 16;     // B: 64r x 2x16B
            const int cB16 = (tg & 3) * 2;
            const int mg = mt * 32 + rA;

            short8v apre[16];
            short8v b0_pf[3], b1_pf[3];
            const u16* brow = nullptr;
            if (t < 256) {          // x-group: preload ALL 16 x-chunks upfront
                const int sel = (int)gload32((const u32*)&cur[mg]);
                const u16* xrow = encB + (size_t)((sel < 0) ? (BB * NN + 1)
                             : (sel == NN ? BB * NN : (mg * NN + sel))) * HH;
                #pragma unroll
                for (int i = 0; i < 16; i++)
                    apre[i] = *(const short8v*)(xrow + i * 64 + koA);
                brow = Wpk + (size_t)(nt * 64 + rB) * 2048;
            } else {                // h-group: preload ALL 16 h-chunks (sc1)
                const u16* hrow = hin + (size_t)mg * HH;
                #pragma unroll
                for (int i = 0; i < 16; i++)
                    apre[i] = gload8h(hrow + i * 64 + koA);
                brow = Wpk + (size_t)(nt * 64 + rB) * 2048 + HH;
            }
            #pragma unroll
            for (int d = 0; d < 3; d++) {
                b0_pf[d] = *(const short8v*)(brow + d * 64 + koB);
                b1_pf[d] = *(const short8v*)(brow + d * 64 + koB + 8);
            }
            float4v acc0 = {}, acc1 = {};
            #pragma unroll
            for (int it = 0; it < 16; ++it) {
                GBAR();
                if (t < 256) {
                    *(short8v*)&AsX[SWZ(rA, cA16)] = apre[it];
                    *(short8v*)&BsX[SWZ(rB, cB16)] = b0_pf[it % 3];
                    *(short8v*)&BsX[SWZ(rB, cB16 + 1)] = b1_pf[it % 3];
                } else {
                    *(short8v*)&AsH[SWZ(rA, cA16)] = apre[it];
                    *(short8v*)&BsH[SWZ(rB, cB16)] = b0_pf[it % 3];
                    *(short8v*)&BsH[SWZ(rB, cB16 + 1)] = b1_pf[it % 3];
                }
                GBAR();
                if (it + 3 < 16) {
                    b0_pf[it % 3] = *(const short8v*)(brow + (it + 3) * 64 + koB);
                    b1_pf[it % 3] = *(const short8v*)(brow + (it + 3) * 64 + koB + 8);
                }
                if (t < 256) {
                    #pragma unroll
                    for (int kf = 0; kf < 2; ++kf) {
                        const int c16 = kf * 4 + (lane >> 4);
                        short8v bf = *(const short8v*)&BsX[SWZ(w4 * 16 + (lane & 15), c16)];
                        short8v a0 = *(const short8v*)&AsX[SWZ(lane & 15, c16)];
                        short8v a1 = *(const short8v*)&AsX[SWZ(16 + (lane & 15), c16)];
                        acc0 = __builtin_amdgcn_mfma_f32_16x16x32_bf16(a0, bf, acc0, 0, 0, 0);
                        acc1 = __builtin_amdgcn_mfma_f32_16x16x32_bf16(a1, bf, acc1, 0, 0, 0);
                    }
                } else {
                    #pragma unroll
                    for (int kf = 0; kf < 2; ++kf) {
                        const int c16 = kf * 4 + (lane >> 4);
                        short8v bf = *(const short8v*)&BsH[SWZ(w4 * 16 + (lane & 15), c16)];
                        short8v a0 = *(const short8v*)&AsH[SWZ(lane & 15, c16)];
                        short8v a1 = *(const short8v*)&AsH[SWZ(16 + (lane & 15), c16)];
                        acc0 = __builtin_amdgcn_mfma_f32_16x16x32_bf16(a0, bf, acc0, 0, 0, 0);
                        acc1 = __builtin_amdgcn_mfma_f32_16x16x32_bf16(a1, bf, acc1, 0, 0, 0);
                    }
                }
            }
            __syncthreads();
            #pragma unroll
            for (int r = 0; r < 4; r++) {
                Gs[wv][(lane >> 4) * 4 + r][lane & 15]      = acc0[r];
                Gs[wv][16 + (lane >> 4) * 4 + r][lane & 15] = acc1[r];
            }
            __syncthreads();
            if (t < 256) {
                const int m = t >> 3, cpr = (t & 7) * 2;
                const int mg2 = mt * 32 + m;
                float hn2[2];
                #pragma unroll
                for (int e = 0; e < 2; e++) {
                    const int c = cpr + e;
                    float gi  = Gs[0][m][c] + Gs[4][m][c] + bpk[nt * 64 + c];
                    float gf  = Gs[1][m][c] + Gs[5][m][c] + bpk[nt * 64 + 16 + c];
                    float gg  = Gs[2][m][c] + Gs[6][m][c] + bpk[nt * 64 + 32 + c];
                    float go2 = Gs[3][m][c] + Gs[7][m][c] + bpk[nt * 64 + 48 + c];
                    const int cg = nt * 16 + c;
                    float cold = cx[(size_t)mg2 * HH + cg];
                    float cn = fsig(gf) * cold + fsig(gi) * ftanh(gg);
                    hn2[e] = fsig(go2) * ftanh(cn);
                    cx[(size_t)mg2 * HH + cg] = cn;
                }
                u32 pk = (u32)f2b(hn2[0]) | ((u32)f2b(hn2[1]) << 16);
                gstore32((u32*)(hout + (size_t)mg2 * HH + nt * 16 + cpr), pk);
            }
        }
        pbar(slots, go, gen++);

        // ============ phase B: hUa partials (waves 0-3) ====================
        {
            const int nt2 = bid & 15, mt2 = (bid >> 4) & 3, ks = bid >> 6;
            const int rA = tg >> 3, koA = (tg & 7) * 8;
            const int cA16 = tg & 7;
            const int rB = tg >> 2, koB = (tg & 3) * 16;
            const int cB16 = (tg & 3) * 2;
            short8v hb[4];
            short8v ub0[2], ub1[2];
            const u16* brow = nullptr;
            if (t < 256) {
                const u16* arow = hout + (size_t)(mt2 * 32 + rA) * HH + ks * 256;
                #pragma unroll
                for (int i = 0; i < 4; i++)
                    hb[i] = gload8h(arow + i * 64 + koA);
                brow = Uab + (size_t)(nt2 * 64 + rB) * HH + ks * 256;
                #pragma unroll
                for (int d = 0; d < 2; d++) {
                    ub0[d] = *(const short8v*)(brow + d * 64 + koB);
                    ub1[d] = *(const short8v*)(brow + d * 64 + koB + 8);
                }
            }
            float4v acc0 = {}, acc1 = {};
            #pragma unroll
            for (int it = 0; it < 4; ++it) {
                GBAR();
                if (t < 256) {
                    *(short8v*)&AsX[SWZ(rA, cA16)] = hb[it];
                    *(short8v*)&BsX[SWZ(rB, cB16)] = ub0[it & 1];
                    *(short8v*)&BsX[SWZ(rB, cB16 + 1)] = ub1[it & 1];
                }
                GBAR();
                if (t < 256) {
                    if (it + 2 < 4) {
                        ub0[it & 1] = *(const short8v*)(brow + (it + 2) * 64 + koB);
                        ub1[it & 1] = *(const short8v*)(brow + (it + 2) * 64 + koB + 8);
                    }
                    #pragma unroll
                    for (int kf = 0; kf < 2; ++kf) {
                        const int c16 = kf * 4 + (lane >> 4);
                        short8v bf = *(const short8v*)&BsX[SWZ(w4 * 16 + (lane & 15), c16)];
                        short8v a0 = *(const short8v*)&AsX[SWZ(lane & 15, c16)];
                        short8v a1 = *(const short8v*)&AsX[SWZ(16 + (lane & 15), c16)];
                        acc0 = __builtin_amdgcn_mfma_f32_16x16x32_bf16(a0, bf, acc0, 0, 0, 0);
                        acc1 = __builtin_amdgcn_mfma_f32_16x16x32_bf16(a1, bf, acc1, 0, 0, 0);
                    }
                }
            }
            if (t < 256) {
                const int n = nt2 * 64 + w4 * 16 + (lane & 15);
                #pragma unroll
                for (int r = 0; r < 4; r++) {
                    const int m0 = mt2 * 32 + (lane >> 4) * 4 + r;
                    gstore32((u32*)&hup[((size_t)ks * BB + m0) * HH + n],
                             __float_as_uint(acc0[r]));
                    gstore32((u32*)&hup[((size_t)ks * BB + m0 + 16) * HH + n],
                             __float_as_uint(acc1[r]));
                }
            }
        }
        pbar(slots, go, gen++);

        // ============ phase C1: scores over UNMASKED slots (2 blocks/batch)
        int cntb_v = 0;
        {
            const int qb = bid >> 7, b = bid & 127;
            #pragma unroll
            for (int cc = 0; cc < 2; cc++) {
                const int c = t + cc * 512;
                float s = 0.f;
                #pragma unroll
                for (int ks = 0; ks < 4; ks++)
                    s += __uint_as_float(gload32((const u32*)&hup[((size_t)ks * BB + b) * HH + c]));
                huS[HPHI(c)] = s;
                vvS[HPHI(c)] = vvec[c];
            }
            cntb_v = (int)gload32((const u32*)&cnt[b]);
            for (int i = t; i < cntb_v; i += 512)
                nlS[i] = (int)gload32((const u32*)&nlist[b * NP1 + i]);
            __syncthreads();

            const int half = (cntb_v + 1) >> 1;
            const int iend = qb ? cntb_v : half;
            const int istart = (qb ? half : 0) + wv * 4;
            const int c0 = lane * 16;

            auto loadrow = [&](int ii, u64& A, u64& B) {
                const int idx = nlS[(ii < iend) ? ii : (iend - 1)];
                const u8* rp = encWa8 + ((size_t)b * NP1 + idx) * HH + c0;
                A = gload64b(rp);
                B = gload64b(rp + 8);
            };
            auto rowscore = [&](u64 p0, u64 p1) -> float {
                float s = 0.f;
                #pragma unroll
                for (int j = 0; j < 8; j++)
                    s += vvS[HPHI(c0 + j)] * ftanh(e82f((u32)(p0 >> (8 * j)) & 0xFFu) + huS[HPHI(c0 + j)]);
                #pragma unroll
                for (int j = 0; j < 8; j++)
                    s += vvS[HPHI(c0 + 8 + j)] * ftanh(e82f((u32)(p1 >> (8 * j)) & 0xFFu) + huS[HPHI(c0 + 8 + j)]);
                #pragma unroll
                for (int off = 32; off; off >>= 1) s += __shfl_down(s, off);
                return s;
            };

            if (istart < iend) {
                u64 qa0, qc0, qa1, qc1, qa2, qc2, qa3, qc3;
                loadrow(istart + 0, qa0, qc0);
                loadrow(istart + 1, qa1, qc1);
                loadrow(istart + 2, qa2, qc2);
                loadrow(istart + 3, qa3, qc3);
                for (int i = istart; i < iend; i += 32) {
                    u64 pa0, pc0, pa1, pc1, pa2, pc2, pa3, pc3;
                    const int inext = i + 32;
                    if (inext < iend) {
                        loadrow(inext + 0, pa0, pc0);
                        loadrow(inext + 1, pa1, pc1);
                        loadrow(inext + 2, pa2, pc2);
                        loadrow(inext + 3, pa3, pc3);
                    } else {
                        pa0 = qa0; pc0 = qc0; pa1 = qa1; pc1 = qc1;
                        pa2 = qa2; pc2 = qc2; pa3 = qa3; pc3 = qc3;
                    }
                    float s0 = rowscore(qa0, qc0);
                    float s1 = rowscore(qa1, qc1);
                    float s2 = rowscore(qa2, qc2);
                    float s3 = rowscore(qa3, qc3);
                    if (lane == 0) {
                        gstore32((u32*)&scSg[b * NP1 + nlS[i]], __float_as_uint(s0));
                        if (i + 1 < iend)
                            gstore32((u32*)&scSg[b * NP1 + nlS[i + 1]], __float_as_uint(s1));
                        if (i + 2 < iend)
                            gstore32((u32*)&scSg[b * NP1 + nlS[i + 2]], __float_as_uint(s2));
                        if (i + 3 < iend)
                            gstore32((u32*)&scSg[b * NP1 + nlS[i + 3]], __float_as_uint(s3));
                    }
                    qa0 = pa0; qc0 = pc0; qa1 = pa1; qc1 = pc1;
                    qa2 = pa2; qc2 = pc2; qa3 = pa3; qc3 = pc3;
                }
            }
            __syncthreads();
            if (qb == 1 && t == 0) gstore32((u32*)&cflag[b << 4], (u32)(step + 1));
        }

        // ============ phase C2: finalize, wave-level reductions ============
        if (bid < 128) {
            const int b = bid;
            if (t == 0) {
                while ((int)gload32((const u32*)&cflag[b << 4]) <= step)
                    __builtin_amdgcn_s_sleep(1);
            }
            __syncthreads();

            float va = -INFINITY;
            if (t < NP1) {
                float sc = __uint_as_float(gload32((const u32*)&scSg[b * NP1 + t]));
                va = (mask[b * NP1 + t] != 0) ? -INFINITY : sc;
            }
            // wave argmax (tie -> smallest index), then 8-way scan
            float mv = va; int mi = t;
            #pragma unroll
            for (int off = 32; off; off >>= 1) {
                float ov = __shfl_down(mv, off);
                int   oi = __shfl_down(mi, off);
                if (ov > mv || (ov == mv && oi < mi)) { mv = ov; mi = oi; }
            }
            if (lane == 0) { rv[wv] = mv; ri[wv] = mi; }
            __syncthreads();
            if (t == 0) {
                float bv2 = rv[0]; int bi2 = ri[0];
                #pragma unroll
                for (int j2 = 1; j2 < 8; j2++)
                    if (rv[j2] > bv2 || (rv[j2] == bv2 && ri[j2] < bi2)) {
                        bv2 = rv[j2]; bi2 = ri[j2];
                    }
                rv[8] = bv2; ri[8] = bi2;
            }
            __syncthreads();
            const float vmax = rv[8]; const int amax = ri[8];

            // logsumexp: wave sums, then 8-way sum
            float ss = (t < NP1) ? expf(va - vmax) : 0.f;
            #pragma unroll
            for (int off = 32; off; off >>= 1) ss += __shfl_down(ss, off);
            if (lane == 0) rv[16 + wv] = ss;
            __syncthreads();
            if (t == 0) {
                float s8 = 0.f;
                #pragma unroll
                for (int j2 = 0; j2 < 8; j2++) s8 += rv[16 + j2];
                rv[25] = s8;
            }
            __syncthreads();
            const float lse = vmax + logf(rv[25]);

            if (t < NP1)
                out_lp[((size_t)b * NP1 + step) * NP1 + t] = fmaxf(va - lse, -1e30f);

            // swap-remove amax from the unmasked list (end token stays)
            if (t == 0) posS = -1;
            __syncthreads();
            if (t < cntb_v && nlS[t] == amax) posS = t;
            __syncthreads();
            if (t == 0) {
                if (amax < NN && posS >= 0) {
                    gstore32((u32*)&nlist[b * NP1 + posS], (u32)nlS[cntb_v - 1]);
                    gstore32((u32*)&cnt[b], (u32)(cntb_v - 1));
                }
                out_idx[(size_t)b * NP1 + step] = (float)amax;
                gstore32((u32*)&cur[b], (u32)amax);
                if (amax < NN) mask[b * NP1 + amax] = 1;
            }
        }
        pbar(slots, go, gen++);
    }
}

// ---------------------------------------------------------------------------
extern "C" void kernel_launch(void* const* d_in, const int* in_sizes, int n_in,
                              void* d_out, int out_size, void* d_ws, size_t ws_size,
                              hipStream_t stream) {
    const float* enc  = (const float*)d_in[0];
    const float* Wih  = (const float*)d_in[1];
    const float* Whh  = (const float*)d_in[2];
    const float* bih  = (const float*)d_in[3];
    const float* bhh  = (const float*)d_in[4];
    const float* Wa   = (const float*)d_in[5];
    const float* Ua   = (const float*)d_in[6];
    const float* v    = (const float*)d_in[7];
    const float* stok = (const float*)d_in[8];
    const float* etok = (const float*)d_in[9];
    float* out = (float*)d_out;
    float* out_idx = out + (size_t)BB * NP1 * NP1;

    size_t off = 0;
    char* base = (char*)d_ws;
    auto alloc = [&](size_t bytes) -> char* {
        char* p = base + off;
        off += (bytes + 255) & ~(size_t)255;
        return p;
    };
    u8*    encWa8 = (u8*)   alloc((size_t)BB * NP1 * HH);          // 33.7 MB
    u16*   encB   = (u16*)  alloc((size_t)(BB * NN + 2) * HH * 2); // 67.1 MB
    u16*   Wpk    = (u16*)  alloc((size_t)4096 * 2048 * 2);        // 16.8 MB
    u16*   Uab    = (u16*)  alloc((size_t)HH * HH * 2);
    float* bpk    = (float*)alloc((size_t)4096 * 4);
    float* hup    = (float*)alloc((size_t)4 * BB * HH * 4);
    float* cx     = (float*)alloc((size_t)BB * HH * 4);
    u16*   hxbA   = (u16*)  alloc((size_t)BB * HH * 2);
    u16*   hxbB   = (u16*)  alloc((size_t)BB * HH * 2);
    float* scSg   = (float*)alloc((size_t)BB * NP1 * 4);
    int*   mask   = (int*)  alloc((size_t)BB * NP1 * 4);
    int*   nlist  = (int*)  alloc((size_t)BB * NP1 * 4);
    int*   cnt    = (int*)  alloc((size_t)BB * 4);
    int*   cur    = (int*)  alloc((size_t)BB * 4);
    int*   slots  = (int*)  alloc((size_t)256 * 16 * 4);
    int*   go     = (int*)  alloc((size_t)64);
    int*   cflag  = (int*)  alloc((size_t)BB * 16 * 4);
    if (off > ws_size) return;   // distinctive failure: 0-node graph

    k_binit<<<512, 256, 0, stream>>>(cx, hxbA, mask, cur, slots, go, cflag,
                                     nlist, cnt);
    k_pack<<<4096, 256, 0, stream>>>(Wih, Whh, bih, bhh, Wpk, bpk);
    k_cvte<<<BB * NN + 2, 256, 0, stream>>>(enc, etok, stok, encB);
    k_cvtu<<<HH, 256, 0, stream>>>(Ua, Uab);
    k_encWa8<<<dim3(257, 8), 256, 0, stream>>>(enc, etok, Wa, encWa8);

    void* args[] = { (void*)&encB, (void*)&Wpk, (void*)&bpk, (void*)&Uab,
                     (void*)&encWa8, (void*)&v, (void*)&cur, (void*)&mask,
                     (void*)&hxbA, (void*)&hxbB, (void*)&cx, (void*)&hup,
                     (void*)&scSg, (void*)&cflag, (void*)&nlist, (void*)&cnt,
                     (void*)&out, (void*)&out_idx, (void*)&slots, (void*)&go };
    hipLaunchCooperativeKernel((const void*)k_persist, dim3(256), dim3(512),
                               args, 0, stream);
}